// Round 1
// baseline (2518.575 us; speedup 1.0000x reference)
//
#include <hip/hip_runtime.h>
#include <math.h>

#define N 4096
#define C 512
#define H 128

// ---------------- helpers ----------------

__device__ inline float wave_reduce_sum(float v) {
#pragma unroll
  for (int m = 32; m; m >>= 1) v += __shfl_xor(v, m);
  return v;
}

__device__ inline float lrelu(float v) { return v > 0.f ? v : 0.01f * v; }

__device__ inline void top3_insert(float v, int j, float& v0, int& j0,
                                   float& v1, int& j1, float& v2, int& j2) {
  if (v > v0) { v2 = v1; j2 = j1; v1 = v0; j1 = j0; v0 = v; j0 = j; }
  else if (v > v1) { v2 = v1; j2 = j1; v1 = v; j1 = j; }
  else if (v > v2) { v2 = v; j2 = j; }
}

// ---------------- small kernels ----------------

// colsum_c[c] = sum_i cm[i,c]*mv[i]
__global__ __launch_bounds__(256) void k_colsum_s2c(
    const float* __restrict__ cm, const float* __restrict__ mv,
    float* __restrict__ colsum_c) {
  int c = blockIdx.x * 256 + threadIdx.x;
  float acc = 0.f;
  for (int i = 0; i < N; i++) acc += cm[(size_t)i * C + c] * mv[i];
  colsum_c[c] = acc;
}

// valid1[c] = (sum_h hidden1[c,h]) != 0
__global__ __launch_bounds__(64) void k_valid1(const float* __restrict__ hid,
                                               float* __restrict__ valid1) {
  int c = blockIdx.x, t = threadIdx.x;
  float s = hid[(size_t)c * H + t] + hid[(size_t)c * H + 64 + t];
  s = wave_reduce_sum(s);
  if (t == 0) valid1[c] = (s != 0.f) ? 1.f : 0.f;
}

// row L2 norm of a [rows,128] matrix
__global__ __launch_bounds__(64) void k_rownorm128(const float* __restrict__ A,
                                                   float* __restrict__ nrm) {
  int r = blockIdx.x, t = threadIdx.x;
  float a = A[(size_t)r * H + t], b = A[(size_t)r * H + 64 + t];
  float ss = wave_reduce_sum(a * a + b * b);
  if (t == 0) nrm[r] = sqrtf(ss);
}

// per-column (over N) max and sum-exp of scores [N,C]
__global__ __launch_bounds__(256) void k_colstats(const float* __restrict__ sc,
                                                  float* __restrict__ colmax,
                                                  float* __restrict__ colsum) {
  __shared__ float red[256];
  int c = blockIdx.x, t = threadIdx.x;
  float v[16];
  float m = -3e38f;
#pragma unroll
  for (int q = 0; q < 16; q++) {
    v[q] = sc[(size_t)(q * 256 + t) * C + c];
    m = fmaxf(m, v[q]);
  }
  red[t] = m; __syncthreads();
  for (int s = 128; s; s >>= 1) { if (t < s) red[t] = fmaxf(red[t], red[t + s]); __syncthreads(); }
  m = red[0]; __syncthreads();
  float sum = 0.f;
#pragma unroll
  for (int q = 0; q < 16; q++) sum += __expf(v[q] - m);
  red[t] = sum; __syncthreads();
  for (int s = 128; s; s >>= 1) { if (t < s) red[t] += red[t + s]; __syncthreads(); }
  if (t == 0) { colmax[c] = m; colsum[c] = red[0]; }
}

// in-place row softmax of cos-sim scores with valid-column masking
__global__ __launch_bounds__(256) void k_cs_softmax(
    float* __restrict__ sc, const float* __restrict__ xnorm,
    const float* __restrict__ hnorm, const float* __restrict__ valid1) {
  __shared__ float red[256];
  int i = blockIdx.x, t = threadIdx.x;
  float xn = xnorm[i];
  float r0 = sc[(size_t)i * C + t], r1 = sc[(size_t)i * C + 256 + t];
  float d0 = xn * hnorm[t], d1 = xn * hnorm[256 + t];
  float c0 = r0 / (d0 == 0.f ? 1.f : d0);
  float c1 = r1 / (d1 == 0.f ? 1.f : d1);
  float s0 = (valid1[t] != 0.f) ? c0 : -3e38f;
  float s1 = (valid1[256 + t] != 0.f) ? c1 : -3e38f;
  red[t] = fmaxf(s0, s1); __syncthreads();
  for (int s = 128; s; s >>= 1) { if (t < s) red[t] = fmaxf(red[t], red[t + s]); __syncthreads(); }
  float m = red[0]; __syncthreads();
  float p0 = (s0 > -1e37f) ? __expf(s0 - m) : 0.f;
  float p1 = (s1 > -1e37f) ? __expf(s1 - m) : 0.f;
  red[t] = p0 + p1; __syncthreads();
  for (int s = 128; s; s >>= 1) { if (t < s) red[t] += red[t + s]; __syncthreads(); }
  float inv = 1.f / red[0];
  sc[(size_t)i * C + t] = p0 * inv;
  sc[(size_t)i * C + 256 + t] = p1 * inv;
}

// h row norms -> hhat (normalized rows) and diag value
__global__ __launch_bounds__(64) void k_hhat(const float* __restrict__ h,
                                             float* __restrict__ hhat,
                                             float* __restrict__ diagv) {
  int i = blockIdx.x, t = threadIdx.x;
  float a = h[(size_t)i * H + t], b = h[(size_t)i * H + 64 + t];
  float ss = wave_reduce_sum(a * a + b * b);
  float hn = sqrtf(ss);
  float den = hn * hn;
  float dg = (den == 0.f) ? 0.f : ss / den;
  float inv = (ss > 0.f) ? (1.f / hn) : 1.f;
  hhat[(size_t)i * H + t] = a * inv;
  hhat[(size_t)i * H + 64 + t] = b * inv;
  if (t == 0) diagv[i] = dg;
}

// finalize hidden2: add gated diagonal term, compute valid2 & inv norm, mask
__global__ __launch_bounds__(64) void k_fin_hidden2(
    const float* __restrict__ h, const float* __restrict__ diagv,
    const float* __restrict__ colsum_m, float* __restrict__ hidden2,
    float* __restrict__ valid2f, float* __restrict__ invh2n) {
  int j = blockIdx.x, t = threadIdx.x;
  float add = (colsum_m[j] != 0.f) ? diagv[j] : 0.f;
  float a = hidden2[(size_t)j * H + t] + add * h[(size_t)j * H + t];
  float b = hidden2[(size_t)j * H + 64 + t] + add * h[(size_t)j * H + 64 + t];
  float s = a + b, ss = a * a + b * b;
#pragma unroll
  for (int m = 32; m; m >>= 1) { s += __shfl_xor(s, m); ss += __shfl_xor(ss, m); }
  bool valid = (s != 0.f);
  hidden2[(size_t)j * H + t] = valid ? a : 0.f;
  hidden2[(size_t)j * H + 64 + t] = valid ? b : 0.f;
  if (t == 0) {
    valid2f[j] = valid ? 1.f : 0.f;
    invh2n[j] = (valid && ss > 0.f) ? (1.f / sqrtf(ss)) : 1.f;
  }
}

// out[i] = dot(all_info[i], W_out) + b_out
__global__ __launch_bounds__(64) void k_final(const float* __restrict__ ai,
                                              const float* __restrict__ Wout,
                                              const float* __restrict__ bout,
                                              float* __restrict__ out) {
  int i = blockIdx.x, t = threadIdx.x;
  float s = ai[(size_t)i * H + t] * Wout[t] + ai[(size_t)i * H + 64 + t] * Wout[64 + t];
  s = wave_reduce_sum(s);
  if (t == 0) out[i] = s + bout[0];
}

// ---------------- tiled GEMM ----------------
// out[M,Nn] = epi(A @ opB + bias); BT=1: B is [Nn,Kk] (use B^T); BT=0: B is [Kk,Nn]
// EPI: 0 store, 1 store lrelu, 2 out += lrelu, 3 out = aux - v
template <int BT, int EPI>
__global__ __launch_bounds__(256) void k_gemm(
    const float* __restrict__ A, const float* __restrict__ B,
    const float* __restrict__ bias, const float* __restrict__ aux,
    float* __restrict__ out, int M, int Nn, int Kk) {
  __shared__ float As[32][33], Bs[32][33];
  int tx = threadIdx.x & 15, ty = threadIdx.x >> 4;
  int bm = blockIdx.y * 32, bn = blockIdx.x * 32;
  float acc00 = 0, acc01 = 0, acc10 = 0, acc11 = 0;
  for (int kt = 0; kt < Kk; kt += 32) {
#pragma unroll
    for (int q = 0; q < 4; q++) {
      int idx = threadIdx.x + q * 256;
      int row = idx >> 5, col = idx & 31;
      As[row][col] = A[(size_t)(bm + row) * Kk + kt + col];
      if (BT) Bs[row][col] = B[(size_t)(bn + row) * Kk + kt + col];
      else    Bs[row][col] = B[(size_t)(kt + row) * Nn + bn + col];
    }
    __syncthreads();
#pragma unroll
    for (int kk = 0; kk < 32; kk++) {
      float a0 = As[ty * 2][kk], a1 = As[ty * 2 + 1][kk];
      float b0 = BT ? Bs[tx * 2][kk] : Bs[kk][tx * 2];
      float b1 = BT ? Bs[tx * 2 + 1][kk] : Bs[kk][tx * 2 + 1];
      acc00 += a0 * b0; acc01 += a0 * b1;
      acc10 += a1 * b0; acc11 += a1 * b1;
    }
    __syncthreads();
  }
  int m0 = bm + ty * 2, n0 = bn + tx * 2;
  float bb0 = bias ? bias[n0] : 0.f, bb1 = bias ? bias[n0 + 1] : 0.f;
  float v00 = acc00 + bb0, v01 = acc01 + bb1;
  float v10 = acc10 + bb0, v11 = acc11 + bb1;
  size_t o00 = (size_t)m0 * Nn + n0, o10 = (size_t)(m0 + 1) * Nn + n0;
  if (EPI == 0) {
    out[o00] = v00; out[o00 + 1] = v01; out[o10] = v10; out[o10 + 1] = v11;
  } else if (EPI == 1) {
    out[o00] = lrelu(v00); out[o00 + 1] = lrelu(v01);
    out[o10] = lrelu(v10); out[o10 + 1] = lrelu(v11);
  } else if (EPI == 2) {
    out[o00] += lrelu(v00); out[o00 + 1] += lrelu(v01);
    out[o10] += lrelu(v10); out[o10 + 1] += lrelu(v11);
  } else {
    out[o00] = aux[o00] - v00; out[o00 + 1] = aux[o00 + 1] - v01;
    out[o10] = aux[o10] - v10; out[o10 + 1] = aux[o10 + 1] - v11;
  }
}

// out[M,Nn] = sum_k a(k,m) * B[k,n], A generated on the fly.
// AMODE 1: a = cm[k,m]*mv[k] / (colsum_c[m]*cm[k,m] + 1)
// AMODE 2: a = exp(sc[k,m]-colmax[m]) / colsumexp[m]; output scaled by valid[m]
template <int AMODE>
__global__ __launch_bounds__(256) void k_gemm_at(
    const float* __restrict__ P, const float* __restrict__ mv,
    const float* __restrict__ col1, const float* __restrict__ col2,
    const float* __restrict__ B, const float* __restrict__ validm,
    float* __restrict__ out, int M, int Nn, int Kk) {
  __shared__ float As[32][33], Bs[32][33];
  int tx = threadIdx.x & 15, ty = threadIdx.x >> 4;
  int bm = blockIdx.y * 32, bn = blockIdx.x * 32;
  float acc00 = 0, acc01 = 0, acc10 = 0, acc11 = 0;
  for (int kt = 0; kt < Kk; kt += 32) {
#pragma unroll
    for (int q = 0; q < 4; q++) {
      int idx = threadIdx.x + q * 256;
      int kr = idx >> 5, mc = idx & 31;
      float raw = P[(size_t)(kt + kr) * M + bm + mc];
      float a;
      if (AMODE == 1) a = raw * mv[kt + kr] / (col1[bm + mc] * raw + 1.f);
      else            a = __expf(raw - col1[bm + mc]) / col2[bm + mc];
      As[mc][kr] = a;
      Bs[kr][mc] = B[(size_t)(kt + kr) * Nn + bn + mc];
    }
    __syncthreads();
#pragma unroll
    for (int kk = 0; kk < 32; kk++) {
      float a0 = As[ty * 2][kk], a1 = As[ty * 2 + 1][kk];
      float b0 = Bs[kk][tx * 2], b1 = Bs[kk][tx * 2 + 1];
      acc00 += a0 * b0; acc01 += a0 * b1;
      acc10 += a1 * b0; acc11 += a1 * b1;
    }
    __syncthreads();
  }
  int m0 = bm + ty * 2, n0 = bn + tx * 2;
  float sc0 = 1.f, sc1 = 1.f;
  if (AMODE == 2) { sc0 = validm[m0]; sc1 = validm[m0 + 1]; }
  out[(size_t)m0 * Nn + n0] = acc00 * sc0;
  out[(size_t)m0 * Nn + n0 + 1] = acc01 * sc0;
  out[(size_t)(m0 + 1) * Nn + n0] = acc10 * sc1;
  out[(size_t)(m0 + 1) * Nn + n0 + 1] = acc11 * sc1;
}

// ---------------- top-k candidate pass ----------------
// grid (128 j-chunks of 32, 4 row groups of 1024); 256 thr, 4 rows/thread
__global__ __launch_bounds__(256) void k_topk_cand(
    const float* __restrict__ hhat, float* __restrict__ candv,
    int* __restrict__ candi) {
  __shared__ float4 bt[32 * 32];
  int jb = blockIdx.x, rg = blockIdx.y, tid = threadIdx.x;
  int jbase = jb * 32;
  for (int q = tid; q < 1024; q += 256)
    bt[q] = ((const float4*)hhat)[jbase * 32 + q];
  __syncthreads();
  int i0 = rg * 1024 + tid * 4;
  float v0[4], v1[4], v2[4]; int j0[4], j1[4], j2[4];
#pragma unroll
  for (int r = 0; r < 4; r++) { v0[r] = v1[r] = v2[r] = -3e38f; j0[r] = j1[r] = j2[r] = 0; }
  for (int jjh = 0; jjh < 32; jjh += 16) {
    float acc[4][16];
#pragma unroll
    for (int r = 0; r < 4; r++)
#pragma unroll
      for (int jj = 0; jj < 16; jj++) acc[r][jj] = 0.f;
    for (int kc = 0; kc < 128; kc += 8) {
      float4 a0[4], a1[4];
#pragma unroll
      for (int r = 0; r < 4; r++) {
        const float4* ap = (const float4*)&hhat[(size_t)(i0 + r) * H + kc];
        a0[r] = ap[0]; a1[r] = ap[1];
      }
#pragma unroll
      for (int jj = 0; jj < 16; jj++) {
        float4 b0 = bt[(jjh + jj) * 32 + (kc >> 2)];
        float4 b1 = bt[(jjh + jj) * 32 + (kc >> 2) + 1];
#pragma unroll
        for (int r = 0; r < 4; r++) {
          acc[r][jj] += a0[r].x * b0.x + a0[r].y * b0.y + a0[r].z * b0.z + a0[r].w * b0.w
                      + a1[r].x * b1.x + a1[r].y * b1.y + a1[r].z * b1.z + a1[r].w * b1.w;
        }
      }
    }
#pragma unroll
    for (int r = 0; r < 4; r++)
#pragma unroll
      for (int jj = 0; jj < 16; jj++) {
        int j = jbase + jjh + jj;
        float v = acc[r][jj];
        if (j == i0 + r) v = 0.f;  // diagonal zeroed before top-k in reference
        top3_insert(v, j, v0[r], j0[r], v1[r], j1[r], v2[r], j2[r]);
      }
  }
#pragma unroll
  for (int r = 0; r < 4; r++) {
    int base = (i0 + r) * 384 + jb * 3;
    candv[base] = v0[r]; candv[base + 1] = v1[r]; candv[base + 2] = v2[r];
    candi[base] = j0[r]; candi[base + 1] = j1[r]; candi[base + 2] = j2[r];
  }
}

// merge 128 chunk-candidates per row -> global top3, scatter into hidden2
__global__ __launch_bounds__(256) void k_merge_scatter(
    const float* __restrict__ candv, const int* __restrict__ candi,
    const float* __restrict__ h, float* __restrict__ hidden2,
    float* __restrict__ colsum_m) {
  int i = blockIdx.x * 256 + threadIdx.x;
  float v0 = -3e38f, v1 = -3e38f, v2 = -3e38f;
  int j0 = 0, j1 = 0, j2 = 0;
  for (int c = 0; c < 384; c++) {
    float v = candv[(size_t)i * 384 + c];
    int j = candi[(size_t)i * 384 + c];
    top3_insert(v, j, v0, j0, v1, j1, v2, j2);
  }
  const float* hr = &h[(size_t)i * H];
  float vv[3] = {v0, v1, v2};
  int jj[3] = {j0, j1, j2};
#pragma unroll
  for (int t = 0; t < 3; t++) {
    atomicAdd(&colsum_m[jj[t]], vv[t]);
    float* dst = &hidden2[(size_t)jj[t] * H];
    for (int k = 0; k < H; k++) atomicAdd(&dst[k], vv[t] * hr[k]);
  }
}

// ---------------- flash pass: hs_pre = softmax(cos(h,hidden2) masked) @ hidden2
__global__ __launch_bounds__(256) void k_flash(
    const float* __restrict__ hhat, const float* __restrict__ hidden2,
    const float* __restrict__ invh2n, const float* __restrict__ valid2f,
    float* __restrict__ hs_pre) {
  __shared__ float4 bt[32 * 32];
  __shared__ float invl[32], vall[32];
  int ib = blockIdx.x, tid = threadIdx.x;
  int r = tid >> 4, c = tid & 15;
  int i = ib * 16 + r;
  const float4* qp = (const float4*)&hhat[(size_t)i * H + c * 8];
  float4 q0 = qp[0], q1 = qp[1];
  float o[8];
#pragma unroll
  for (int u = 0; u < 8; u++) o[u] = 0.f;
  float m = -3e38f, l = 0.f;
  for (int jt = 0; jt < 128; jt++) {
    __syncthreads();
    for (int q = tid; q < 1024; q += 256)
      bt[q] = ((const float4*)hidden2)[jt * 1024 + q];
    if (tid < 32) { invl[tid] = invh2n[jt * 32 + tid]; vall[tid] = valid2f[jt * 32 + tid]; }
    __syncthreads();
    for (int jj = 0; jj < 32; jj++) {
      float4 b0 = bt[jj * 32 + c * 2], b1 = bt[jj * 32 + c * 2 + 1];
      float p = q0.x * b0.x + q0.y * b0.y + q0.z * b0.z + q0.w * b0.w
              + q1.x * b1.x + q1.y * b1.y + q1.z * b1.z + q1.w * b1.w;
      p += __shfl_xor(p, 1); p += __shfl_xor(p, 2);
      p += __shfl_xor(p, 4); p += __shfl_xor(p, 8);
      float s = p * invl[jj];
      bool ok = (vall[jj] != 0.f);
      if (ok) {
        if (s > m) {
          float alpha = __expf(m - s);
          l = l * alpha + 1.f;
          o[0] = o[0] * alpha + b0.x; o[1] = o[1] * alpha + b0.y;
          o[2] = o[2] * alpha + b0.z; o[3] = o[3] * alpha + b0.w;
          o[4] = o[4] * alpha + b1.x; o[5] = o[5] * alpha + b1.y;
          o[6] = o[6] * alpha + b1.z; o[7] = o[7] * alpha + b1.w;
          m = s;
        } else {
          float pe = __expf(s - m);
          l += pe;
          o[0] += pe * b0.x; o[1] += pe * b0.y; o[2] += pe * b0.z; o[3] += pe * b0.w;
          o[4] += pe * b1.x; o[5] += pe * b1.y; o[6] += pe * b1.z; o[7] += pe * b1.w;
        }
      }
    }
  }
  float rl = 1.f / l;
  float* op = &hs_pre[(size_t)i * H + c * 8];
#pragma unroll
  for (int u = 0; u < 8; u++) op[u] = o[u] * rl;
}

// ---------------- launch ----------------

extern "C" void kernel_launch(void* const* d_in, const int* in_sizes, int n_in,
                              void* d_out, int out_size, void* d_ws, size_t ws_size,
                              hipStream_t stream) {
  (void)in_sizes; (void)n_in; (void)out_size; (void)ws_size;
  const float* x   = (const float*)d_in[0];
  const float* cm  = (const float*)d_in[1];
  const float* mv  = (const float*)d_in[2];
  const float* W_ps = (const float*)d_in[3],  *b_ps = (const float*)d_in[4];
  const float* W_psf = (const float*)d_in[5], *b_psf = (const float*)d_in[6];
  const float* W_psb = (const float*)d_in[7], *b_psb = (const float*)d_in[8];
  const float* W_hs = (const float*)d_in[9],  *b_hs = (const float*)d_in[10];
  const float* W_hsf = (const float*)d_in[11], *b_hsf = (const float*)d_in[12];
  const float* W_hsb = (const float*)d_in[13], *b_hsb = (const float*)d_in[14];
  const float* W_in = (const float*)d_in[15], *b_in = (const float*)d_in[16];
  const float* W_out = (const float*)d_in[17], *b_out = (const float*)d_in[18];
  float* out = (float*)d_out;

  float* W = (float*)d_ws;
  size_t o = 0;
  auto alloc = [&](size_t n) { float* p = W + o; o += n; return p; };
  float* colsum_c = alloc(C);
  float* colmax   = alloc(C);
  float* colsumexp= alloc(C);
  float* valid1   = alloc(C);
  float* hnorm_ps = alloc(C);
  float* xnorm    = alloc(N);
  float* diagv    = alloc(N);
  float* colsum_m = alloc(N);
  float* invh2n   = alloc(N);
  float* valid2f  = alloc(N);
  float* hidden1  = alloc((size_t)C * H);
  float* hidden_ps= alloc((size_t)C * H);
  float* scores   = alloc((size_t)N * C);   // scores1 / cs / candv (reused)
  int*   candi    = (int*)alloc((size_t)N * 128 * 3);
  float* ps_pre   = alloc((size_t)N * H);   // later hs_pre
  float* p_shared = alloc((size_t)N * H);   // later h_shared
  float* all_info = alloc((size_t)N * H);
  float* hbuf     = alloc((size_t)N * H);
  float* hhat     = alloc((size_t)N * H);
  float* hidden2  = alloc((size_t)N * H);
  float* indiv    = alloc((size_t)N * H);
  float* candv    = scores;  // alias: scores free by the time H1 runs

  hipMemsetAsync(hidden2, 0, (size_t)N * H * sizeof(float), stream);
  hipMemsetAsync(colsum_m, 0, (size_t)N * sizeof(float), stream);

  dim3 blk(256);
  // --- ps branch ---
  k_colsum_s2c<<<dim3(C / 256), blk, 0, stream>>>(cm, mv, colsum_c);
  k_gemm_at<1><<<dim3(H / 32, C / 32), blk, 0, stream>>>(
      cm, mv, colsum_c, nullptr, x, nullptr, hidden1, C, H, N);
  k_valid1<<<dim3(C), dim3(64), 0, stream>>>(hidden1, valid1);
  k_gemm<1, 0><<<dim3(C / 32, N / 32), blk, 0, stream>>>(
      x, hidden1, nullptr, nullptr, scores, N, C, H);
  k_colstats<<<dim3(C), blk, 0, stream>>>(scores, colmax, colsumexp);
  k_gemm_at<2><<<dim3(H / 32, C / 32), blk, 0, stream>>>(
      scores, nullptr, colmax, colsumexp, x, valid1, hidden_ps, C, H, N);
  k_rownorm128<<<dim3(N), dim3(64), 0, stream>>>(x, xnorm);
  k_rownorm128<<<dim3(C), dim3(64), 0, stream>>>(hidden_ps, hnorm_ps);
  k_gemm<1, 0><<<dim3(C / 32, N / 32), blk, 0, stream>>>(
      x, hidden_ps, nullptr, nullptr, scores, N, C, H);
  k_cs_softmax<<<dim3(N), blk, 0, stream>>>(scores, xnorm, hnorm_ps, valid1);
  k_gemm<0, 0><<<dim3(H / 32, N / 32), blk, 0, stream>>>(
      scores, hidden_ps, nullptr, nullptr, ps_pre, N, H, C);
  k_gemm<1, 0><<<dim3(H / 32, N / 32), blk, 0, stream>>>(
      ps_pre, W_ps, b_ps, nullptr, p_shared, N, H, H);
  k_gemm<1, 3><<<dim3(H / 32, N / 32), blk, 0, stream>>>(
      p_shared, W_psb, b_psb, x, hbuf, N, H, H);             // h = x - p_back
  k_gemm<1, 1><<<dim3(H / 32, N / 32), blk, 0, stream>>>(
      p_shared, W_psf, b_psf, nullptr, all_info, N, H, H);   // out_ps
  // --- hs branch ---
  k_hhat<<<dim3(N), dim3(64), 0, stream>>>(hbuf, hhat, diagv);
  k_topk_cand<<<dim3(128, 4), blk, 0, stream>>>(hhat, candv, candi);
  k_merge_scatter<<<dim3(16), blk, 0, stream>>>(candv, candi, hbuf, hidden2, colsum_m);
  k_fin_hidden2<<<dim3(N), dim3(64), 0, stream>>>(hbuf, diagv, colsum_m, hidden2,
                                                  valid2f, invh2n);
  k_flash<<<dim3(256), blk, 0, stream>>>(hhat, hidden2, invh2n, valid2f, ps_pre);
  k_gemm<1, 0><<<dim3(H / 32, N / 32), blk, 0, stream>>>(
      ps_pre, W_hs, b_hs, nullptr, p_shared, N, H, H);       // h_shared
  k_gemm<1, 2><<<dim3(H / 32, N / 32), blk, 0, stream>>>(
      p_shared, W_hsf, b_hsf, nullptr, all_info, N, H, H);   // += out_hs
  k_gemm<1, 3><<<dim3(H / 32, N / 32), blk, 0, stream>>>(
      p_shared, W_hsb, b_hsb, hbuf, indiv, N, H, H);         // indiv = h - h_back
  k_gemm<1, 2><<<dim3(H / 32, N / 32), blk, 0, stream>>>(
      indiv, W_in, b_in, nullptr, all_info, N, H, H);        // += out_indi
  k_final<<<dim3(N), dim3(64), 0, stream>>>(all_info, W_out, b_out, out);
}

// Round 2
// 924.448 us; speedup vs baseline: 2.7244x; 2.7244x over previous
//
#include <hip/hip_runtime.h>
#include <math.h>

#define N 4096
#define C 512
#define H 128

// ---------------- helpers ----------------

__device__ inline float wave_reduce_sum(float v) {
#pragma unroll
  for (int m = 32; m; m >>= 1) v += __shfl_xor(v, m);
  return v;
}

__device__ inline float lrelu(float v) { return v > 0.f ? v : 0.01f * v; }

__device__ inline void top3_insert(float v, int j, float& v0, int& j0,
                                   float& v1, int& j1, float& v2, int& j2) {
  if (v > v0) { v2 = v1; j2 = j1; v1 = v0; j1 = j0; v0 = v; j0 = j; }
  else if (v > v1) { v2 = v1; j2 = j1; v1 = v; j1 = j; }
  else if (v > v2) { v2 = v; j2 = j; }
}

// ---------------- small kernels ----------------

// colsum_c[c] += partial over i-chunk; grid (C/64, 16), block 64
__global__ __launch_bounds__(64) void k_colsum_s2c(
    const float* __restrict__ cm, const float* __restrict__ mv,
    float* __restrict__ colsum_c) {
  int c = blockIdx.x * 64 + threadIdx.x;
  int i0 = blockIdx.y * 256;
  float acc = 0.f;
  for (int i = i0; i < i0 + 256; i++) acc += cm[(size_t)i * C + c] * mv[i];
  atomicAdd(&colsum_c[c], acc);
}

// valid1[c] = (sum_h hidden1[c,h]) != 0
__global__ __launch_bounds__(64) void k_valid1(const float* __restrict__ hid,
                                               float* __restrict__ valid1) {
  int c = blockIdx.x, t = threadIdx.x;
  float s = hid[(size_t)c * H + t] + hid[(size_t)c * H + 64 + t];
  s = wave_reduce_sum(s);
  if (t == 0) valid1[c] = (s != 0.f) ? 1.f : 0.f;
}

// row L2 norm of a [rows,128] matrix
__global__ __launch_bounds__(64) void k_rownorm128(const float* __restrict__ A,
                                                   float* __restrict__ nrm) {
  int r = blockIdx.x, t = threadIdx.x;
  float a = A[(size_t)r * H + t], b = A[(size_t)r * H + 64 + t];
  float ss = wave_reduce_sum(a * a + b * b);
  if (t == 0) nrm[r] = sqrtf(ss);
}

// per-column (over N) max and sum-exp of scores [N,C]
__global__ __launch_bounds__(256) void k_colstats(const float* __restrict__ sc,
                                                  float* __restrict__ colmax,
                                                  float* __restrict__ colsum) {
  __shared__ float red[256];
  int c = blockIdx.x, t = threadIdx.x;
  float v[16];
  float m = -3e38f;
#pragma unroll
  for (int q = 0; q < 16; q++) {
    v[q] = sc[(size_t)(q * 256 + t) * C + c];
    m = fmaxf(m, v[q]);
  }
  red[t] = m; __syncthreads();
  for (int s = 128; s; s >>= 1) { if (t < s) red[t] = fmaxf(red[t], red[t + s]); __syncthreads(); }
  m = red[0]; __syncthreads();
  float sum = 0.f;
#pragma unroll
  for (int q = 0; q < 16; q++) sum += __expf(v[q] - m);
  red[t] = sum; __syncthreads();
  for (int s = 128; s; s >>= 1) { if (t < s) red[t] += red[t + s]; __syncthreads(); }
  if (t == 0) { colmax[c] = m; colsum[c] = red[0]; }
}

// in-place row softmax of cos-sim scores with valid-column masking
__global__ __launch_bounds__(256) void k_cs_softmax(
    float* __restrict__ sc, const float* __restrict__ xnorm,
    const float* __restrict__ hnorm, const float* __restrict__ valid1) {
  __shared__ float red[256];
  int i = blockIdx.x, t = threadIdx.x;
  float xn = xnorm[i];
  float r0 = sc[(size_t)i * C + t], r1 = sc[(size_t)i * C + 256 + t];
  float d0 = xn * hnorm[t], d1 = xn * hnorm[256 + t];
  float c0 = r0 / (d0 == 0.f ? 1.f : d0);
  float c1 = r1 / (d1 == 0.f ? 1.f : d1);
  float s0 = (valid1[t] != 0.f) ? c0 : -3e38f;
  float s1 = (valid1[256 + t] != 0.f) ? c1 : -3e38f;
  red[t] = fmaxf(s0, s1); __syncthreads();
  for (int s = 128; s; s >>= 1) { if (t < s) red[t] = fmaxf(red[t], red[t + s]); __syncthreads(); }
  float m = red[0]; __syncthreads();
  float p0 = (s0 > -1e37f) ? __expf(s0 - m) : 0.f;
  float p1 = (s1 > -1e37f) ? __expf(s1 - m) : 0.f;
  red[t] = p0 + p1; __syncthreads();
  for (int s = 128; s; s >>= 1) { if (t < s) red[t] += red[t + s]; __syncthreads(); }
  float inv = 1.f / red[0];
  sc[(size_t)i * C + t] = p0 * inv;
  sc[(size_t)i * C + 256 + t] = p1 * inv;
}

// h row norms -> hhat (normalized rows) and diag value
__global__ __launch_bounds__(64) void k_hhat(const float* __restrict__ h,
                                             float* __restrict__ hhat,
                                             float* __restrict__ diagv) {
  int i = blockIdx.x, t = threadIdx.x;
  float a = h[(size_t)i * H + t], b = h[(size_t)i * H + 64 + t];
  float ss = wave_reduce_sum(a * a + b * b);
  float hn = sqrtf(ss);
  float den = hn * hn;
  float dg = (den == 0.f) ? 0.f : ss / den;
  float inv = (ss > 0.f) ? (1.f / hn) : 1.f;
  hhat[(size_t)i * H + t] = a * inv;
  hhat[(size_t)i * H + 64 + t] = b * inv;
  if (t == 0) diagv[i] = dg;
}

// finalize hidden2: add gated diagonal, mask invalid rows, emit h2hat & valid2f
__global__ __launch_bounds__(64) void k_fin_hidden2(
    const float* __restrict__ h, const float* __restrict__ diagv,
    const float* __restrict__ colsum_m, float* __restrict__ hidden2,
    float* __restrict__ h2hat, float* __restrict__ valid2f) {
  int j = blockIdx.x, t = threadIdx.x;
  float add = (colsum_m[j] != 0.f) ? diagv[j] : 0.f;
  float a = hidden2[(size_t)j * H + t] + add * h[(size_t)j * H + t];
  float b = hidden2[(size_t)j * H + 64 + t] + add * h[(size_t)j * H + 64 + t];
  float s = a + b, ss = a * a + b * b;
#pragma unroll
  for (int m = 32; m; m >>= 1) { s += __shfl_xor(s, m); ss += __shfl_xor(ss, m); }
  bool valid = (s != 0.f);
  a = valid ? a : 0.f; b = valid ? b : 0.f;
  hidden2[(size_t)j * H + t] = a;
  hidden2[(size_t)j * H + 64 + t] = b;
  float inv = (valid && ss > 0.f) ? (1.f / sqrtf(ss)) : 1.f;
  h2hat[(size_t)j * H + t] = a * inv;
  h2hat[(size_t)j * H + 64 + t] = b * inv;
  if (t == 0) valid2f[j] = valid ? 1.f : 0.f;
}

// per-row max & 1/sumexp of S [N,N] (invalid cols already -3e38)
__global__ __launch_bounds__(256) void k_rowstats(const float* __restrict__ S,
                                                  float* __restrict__ rowmax,
                                                  float* __restrict__ rowinv) {
  __shared__ float red[256];
  int i = blockIdx.x, t = threadIdx.x;
  float4 v[4];
  float m = -3e38f;
#pragma unroll
  for (int q = 0; q < 4; q++) {
    v[q] = *(const float4*)&S[(size_t)i * N + q * 1024 + t * 4];
    m = fmaxf(m, fmaxf(fmaxf(v[q].x, v[q].y), fmaxf(v[q].z, v[q].w)));
  }
  red[t] = m; __syncthreads();
  for (int s = 128; s; s >>= 1) { if (t < s) red[t] = fmaxf(red[t], red[t + s]); __syncthreads(); }
  m = red[0]; __syncthreads();
  float sum = 0.f;
#pragma unroll
  for (int q = 0; q < 4; q++)
    sum += __expf(v[q].x - m) + __expf(v[q].y - m) + __expf(v[q].z - m) + __expf(v[q].w - m);
  red[t] = sum; __syncthreads();
  for (int s = 128; s; s >>= 1) { if (t < s) red[t] += red[t + s]; __syncthreads(); }
  if (t == 0) { rowmax[i] = m; rowinv[i] = 1.f / red[0]; }
}

// out[i] = dot(all_info[i], W_out) + b_out
__global__ __launch_bounds__(64) void k_final(const float* __restrict__ ai,
                                              const float* __restrict__ Wout,
                                              const float* __restrict__ bout,
                                              float* __restrict__ out) {
  int i = blockIdx.x, t = threadIdx.x;
  float s = ai[(size_t)i * H + t] * Wout[t] + ai[(size_t)i * H + 64 + t] * Wout[64 + t];
  s = wave_reduce_sum(s);
  if (t == 0) out[i] = s + bout[0];
}

// ---------------- big NT GEMM: out[M,Nn] = A[M,128] @ B[Nn,128]^T ----------------
// tile 128x64, 256 threads, 8x4 micro. MASK: validn[n]==0 -> store -3e38
template <int MASK>
__global__ __launch_bounds__(256) void k_gemm_nt(
    const float* __restrict__ A, const float* __restrict__ B,
    const float* __restrict__ validn, float* __restrict__ out, int Nn) {
  __shared__ float As[32][132];  // [k][m], padded (132*4 % 16 == 0)
  __shared__ float Bs[32][68];   // [k][n]
  int tid = threadIdx.x;
  int tx = tid & 15, ty = tid >> 4;
  int bm = blockIdx.y * 128, bn = blockIdx.x * 64;
  float acc[8][4];
#pragma unroll
  for (int r = 0; r < 8; r++)
#pragma unroll
    for (int c = 0; c < 4; c++) acc[r][c] = 0.f;
  for (int kt = 0; kt < 128; kt += 32) {
#pragma unroll
    for (int q = 0; q < 4; q++) {
      int f = q * 256 + tid;
      int row = f >> 3, kq = f & 7;
      float4 av = *(const float4*)&A[(size_t)(bm + row) * 128 + kt + kq * 4];
      As[kq * 4 + 0][row] = av.x; As[kq * 4 + 1][row] = av.y;
      As[kq * 4 + 2][row] = av.z; As[kq * 4 + 3][row] = av.w;
    }
#pragma unroll
    for (int q = 0; q < 2; q++) {
      int f = q * 256 + tid;
      int row = f >> 3, kq = f & 7;
      float4 bv = *(const float4*)&B[(size_t)(bn + row) * 128 + kt + kq * 4];
      Bs[kq * 4 + 0][row] = bv.x; Bs[kq * 4 + 1][row] = bv.y;
      Bs[kq * 4 + 2][row] = bv.z; Bs[kq * 4 + 3][row] = bv.w;
    }
    __syncthreads();
#pragma unroll
    for (int kk = 0; kk < 32; kk++) {
      float4 a0 = *(float4*)&As[kk][ty * 8];
      float4 a1 = *(float4*)&As[kk][ty * 8 + 4];
      float4 fb = *(float4*)&Bs[kk][tx * 4];
      float am[8] = {a0.x, a0.y, a0.z, a0.w, a1.x, a1.y, a1.z, a1.w};
      float bn_[4] = {fb.x, fb.y, fb.z, fb.w};
#pragma unroll
      for (int r = 0; r < 8; r++)
#pragma unroll
        for (int c = 0; c < 4; c++) acc[r][c] += am[r] * bn_[c];
    }
    __syncthreads();
  }
  float4 vm = MASK ? *(const float4*)&validn[bn + tx * 4] : float4{1, 1, 1, 1};
#pragma unroll
  for (int r = 0; r < 8; r++) {
    float4 v;
    v.x = acc[r][0]; v.y = acc[r][1]; v.z = acc[r][2]; v.w = acc[r][3];
    if (MASK) {
      v.x = (vm.x != 0.f) ? v.x : -3e38f;
      v.y = (vm.y != 0.f) ? v.y : -3e38f;
      v.z = (vm.z != 0.f) ? v.z : -3e38f;
      v.w = (vm.w != 0.f) ? v.w : -3e38f;
    }
    *(float4*)&out[(size_t)(bm + ty * 8 + r) * Nn + bn + tx * 4] = v;
  }
}

// ---------------- split-K KN GEMM: partial[z] = A'[M,K-chunk] @ B[K,128] -------
// A row-major [M,lda]; EXP=1: a = exp(a - rowmax[m]) * rowinv[m]
// tile 64x64, 256 threads, 4x4 micro; out partial slot z of width 128
template <int EXP>
__global__ __launch_bounds__(256) void k_gemm_kn(
    const float* __restrict__ A, int lda,
    const float* __restrict__ rowmax, const float* __restrict__ rowinv,
    const float* __restrict__ B, float* __restrict__ partial, int KC, int M) {
  __shared__ float As[32][68];  // [k][m]
  __shared__ float Bs[32][68];  // [k][n]
  int tid = threadIdx.x;
  int tx = tid & 15, ty = tid >> 4;
  int bm = blockIdx.y * 64, bn = blockIdx.x * 64;
  int k0 = blockIdx.z * KC;
  float acc[4][4];
#pragma unroll
  for (int r = 0; r < 4; r++)
#pragma unroll
    for (int c = 0; c < 4; c++) acc[r][c] = 0.f;
  for (int kt = 0; kt < KC; kt += 32) {
#pragma unroll
    for (int q = 0; q < 2; q++) {
      int f = q * 256 + tid;
      int row = f >> 3, kq = f & 7;
      float4 av = *(const float4*)&A[(size_t)(bm + row) * lda + k0 + kt + kq * 4];
      if (EXP) {
        float rm = rowmax[bm + row], ri = rowinv[bm + row];
        av.x = __expf(av.x - rm) * ri; av.y = __expf(av.y - rm) * ri;
        av.z = __expf(av.z - rm) * ri; av.w = __expf(av.w - rm) * ri;
      }
      As[kq * 4 + 0][row] = av.x; As[kq * 4 + 1][row] = av.y;
      As[kq * 4 + 2][row] = av.z; As[kq * 4 + 3][row] = av.w;
      int kr = f >> 4, nq = f & 15;
      float4 bv = *(const float4*)&B[(size_t)(k0 + kt + kr) * 128 + bn + nq * 4];
      *(float4*)&Bs[kr][nq * 4] = bv;
    }
    __syncthreads();
#pragma unroll
    for (int kk = 0; kk < 32; kk++) {
      float4 fa = *(float4*)&As[kk][ty * 4];
      float4 fb = *(float4*)&Bs[kk][tx * 4];
      float am[4] = {fa.x, fa.y, fa.z, fa.w};
      float bb[4] = {fb.x, fb.y, fb.z, fb.w};
#pragma unroll
      for (int r = 0; r < 4; r++)
#pragma unroll
        for (int c = 0; c < 4; c++) acc[r][c] += am[r] * bb[c];
    }
    __syncthreads();
  }
  float* pp = partial + (size_t)blockIdx.z * M * 128;
#pragma unroll
  for (int r = 0; r < 4; r++) {
    float4 v = {acc[r][0], acc[r][1], acc[r][2], acc[r][3]};
    *(float4*)&pp[(size_t)(bm + ty * 4 + r) * 128 + bn + tx * 4] = v;
  }
}

// ---------------- split-K GEMM with generated A^T: partial[z] = a(k,m) @ B[k,n]
// AMODE1: a = P[k,m]*mv[k] / (col1[m]*P[k,m] + 1)    (P = concept_matrix)
// AMODE2: a = exp(P[k,m]-col1[m]) / col2[m]          (P = scores)
template <int AMODE>
__global__ __launch_bounds__(256) void k_gemm_genA(
    const float* __restrict__ P, const float* __restrict__ mv,
    const float* __restrict__ col1, const float* __restrict__ col2,
    const float* __restrict__ B, float* __restrict__ partial, int KC) {
  __shared__ float Ps[32][68];  // [k][m]
  __shared__ float Bs[32][68];  // [k][n]
  int tid = threadIdx.x;
  int tx = tid & 15, ty = tid >> 4;
  int bm = blockIdx.y * 64, bn = blockIdx.x * 64;
  int k0 = blockIdx.z * KC;
  float acc[4][4];
#pragma unroll
  for (int r = 0; r < 4; r++)
#pragma unroll
    for (int c = 0; c < 4; c++) acc[r][c] = 0.f;
  for (int kt = 0; kt < KC; kt += 32) {
#pragma unroll
    for (int q = 0; q < 2; q++) {
      int f = q * 256 + tid;
      int kr = f >> 4, nq = f & 15;
      int k = k0 + kt + kr;
      float4 pv = *(const float4*)&P[(size_t)k * C + bm + nq * 4];
      float4 av;
      if (AMODE == 1) {
        float m = mv[k];
        float4 cs = *(const float4*)&col1[bm + nq * 4];
        av.x = pv.x * m / (cs.x * pv.x + 1.f);
        av.y = pv.y * m / (cs.y * pv.y + 1.f);
        av.z = pv.z * m / (cs.z * pv.z + 1.f);
        av.w = pv.w * m / (cs.w * pv.w + 1.f);
      } else {
        float4 cm_ = *(const float4*)&col1[bm + nq * 4];
        float4 cd = *(const float4*)&col2[bm + nq * 4];
        av.x = __expf(pv.x - cm_.x) / cd.x;
        av.y = __expf(pv.y - cm_.y) / cd.y;
        av.z = __expf(pv.z - cm_.z) / cd.z;
        av.w = __expf(pv.w - cm_.w) / cd.w;
      }
      *(float4*)&Ps[kr][nq * 4] = av;
      float4 bv = *(const float4*)&B[(size_t)k * 128 + bn + nq * 4];
      *(float4*)&Bs[kr][nq * 4] = bv;
    }
    __syncthreads();
#pragma unroll
    for (int kk = 0; kk < 32; kk++) {
      float4 fa = *(float4*)&Ps[kk][ty * 4];
      float4 fb = *(float4*)&Bs[kk][tx * 4];
      float am[4] = {fa.x, fa.y, fa.z, fa.w};
      float bb[4] = {fb.x, fb.y, fb.z, fb.w};
#pragma unroll
      for (int r = 0; r < 4; r++)
#pragma unroll
        for (int c = 0; c < 4; c++) acc[r][c] += am[r] * bb[c];
    }
    __syncthreads();
  }
  float* pp = partial + (size_t)blockIdx.z * C * 128;
#pragma unroll
  for (int r = 0; r < 4; r++) {
    float4 v = {acc[r][0], acc[r][1], acc[r][2], acc[r][3]};
    *(float4*)&pp[(size_t)(bm + ty * 4 + r) * 128 + bn + tx * 4] = v;
  }
}

// reduce split-K partials; optional per-row (128-wide) valid scale
__global__ __launch_bounds__(256) void k_reduce(
    const float* __restrict__ partial, float* __restrict__ out, int cnt,
    size_t slot, size_t size4, const float* __restrict__ validm) {
  size_t idx = (size_t)blockIdx.x * 256 + threadIdx.x;
  if (idx >= size4) return;
  float4 s = {0, 0, 0, 0};
  for (int c = 0; c < cnt; c++) {
    float4 v = *(const float4*)&partial[c * slot + idx * 4];
    s.x += v.x; s.y += v.y; s.z += v.z; s.w += v.w;
  }
  if (validm) {
    float sc = validm[idx >> 5];
    s.x *= sc; s.y *= sc; s.z *= sc; s.w *= sc;
  }
  *(float4*)&out[idx * 4] = s;
}

// ---------------- 32-tile GEMM for the small linears ----------------
// out[M,Nn] = epi(A @ B^T + bias); EPI: 0 store, 1 lrelu, 2 +=lrelu, 3 aux - v
template <int BT, int EPI>
__global__ __launch_bounds__(256) void k_gemm(
    const float* __restrict__ A, const float* __restrict__ B,
    const float* __restrict__ bias, const float* __restrict__ aux,
    float* __restrict__ out, int M, int Nn, int Kk) {
  __shared__ float As[32][33], Bs[32][33];
  int tx = threadIdx.x & 15, ty = threadIdx.x >> 4;
  int bm = blockIdx.y * 32, bn = blockIdx.x * 32;
  float acc00 = 0, acc01 = 0, acc10 = 0, acc11 = 0;
  for (int kt = 0; kt < Kk; kt += 32) {
#pragma unroll
    for (int q = 0; q < 4; q++) {
      int idx = threadIdx.x + q * 256;
      int row = idx >> 5, col = idx & 31;
      As[row][col] = A[(size_t)(bm + row) * Kk + kt + col];
      if (BT) Bs[row][col] = B[(size_t)(bn + row) * Kk + kt + col];
      else    Bs[row][col] = B[(size_t)(kt + row) * Nn + bn + col];
    }
    __syncthreads();
#pragma unroll
    for (int kk = 0; kk < 32; kk++) {
      float a0 = As[ty * 2][kk], a1 = As[ty * 2 + 1][kk];
      float b0 = BT ? Bs[tx * 2][kk] : Bs[kk][tx * 2];
      float b1 = BT ? Bs[tx * 2 + 1][kk] : Bs[kk][tx * 2 + 1];
      acc00 += a0 * b0; acc01 += a0 * b1;
      acc10 += a1 * b0; acc11 += a1 * b1;
    }
    __syncthreads();
  }
  int m0 = bm + ty * 2, n0 = bn + tx * 2;
  float bb0 = bias ? bias[n0] : 0.f, bb1 = bias ? bias[n0 + 1] : 0.f;
  float v00 = acc00 + bb0, v01 = acc01 + bb1;
  float v10 = acc10 + bb0, v11 = acc11 + bb1;
  size_t o00 = (size_t)m0 * Nn + n0, o10 = (size_t)(m0 + 1) * Nn + n0;
  if (EPI == 0) {
    out[o00] = v00; out[o00 + 1] = v01; out[o10] = v10; out[o10 + 1] = v11;
  } else if (EPI == 1) {
    out[o00] = lrelu(v00); out[o00 + 1] = lrelu(v01);
    out[o10] = lrelu(v10); out[o10 + 1] = lrelu(v11);
  } else if (EPI == 2) {
    out[o00] += lrelu(v00); out[o00 + 1] += lrelu(v01);
    out[o10] += lrelu(v10); out[o10 + 1] += lrelu(v11);
  } else {
    out[o00] = aux[o00] - v00; out[o00 + 1] = aux[o00 + 1] - v01;
    out[o10] = aux[o10] - v10; out[o10 + 1] = aux[o10 + 1] - v11;
  }
}

// ---------------- top-k candidate pass ----------------
// chunk-major output layout: candv[(jb*3+s)*N + i]
__global__ __launch_bounds__(256) void k_topk_cand(
    const float* __restrict__ hhat, float* __restrict__ candv,
    int* __restrict__ candi) {
  __shared__ float4 bt[32 * 32];
  int jb = blockIdx.x, rg = blockIdx.y, tid = threadIdx.x;
  int jbase = jb * 32;
  for (int q = tid; q < 1024; q += 256)
    bt[q] = ((const float4*)hhat)[jbase * 32 + q];
  __syncthreads();
  int i0 = rg * 1024 + tid * 4;
  float v0[4], v1[4], v2[4]; int j0[4], j1[4], j2[4];
#pragma unroll
  for (int r = 0; r < 4; r++) { v0[r] = v1[r] = v2[r] = -3e38f; j0[r] = j1[r] = j2[r] = 0; }
  for (int jjh = 0; jjh < 32; jjh += 16) {
    float acc[4][16];
#pragma unroll
    for (int r = 0; r < 4; r++)
#pragma unroll
      for (int jj = 0; jj < 16; jj++) acc[r][jj] = 0.f;
    for (int kc = 0; kc < 128; kc += 8) {
      float4 a0[4], a1[4];
#pragma unroll
      for (int r = 0; r < 4; r++) {
        const float4* ap = (const float4*)&hhat[(size_t)(i0 + r) * H + kc];
        a0[r] = ap[0]; a1[r] = ap[1];
      }
#pragma unroll
      for (int jj = 0; jj < 16; jj++) {
        float4 b0 = bt[(jjh + jj) * 32 + (kc >> 2)];
        float4 b1 = bt[(jjh + jj) * 32 + (kc >> 2) + 1];
#pragma unroll
        for (int r = 0; r < 4; r++) {
          acc[r][jj] += a0[r].x * b0.x + a0[r].y * b0.y + a0[r].z * b0.z + a0[r].w * b0.w
                      + a1[r].x * b1.x + a1[r].y * b1.y + a1[r].z * b1.z + a1[r].w * b1.w;
        }
      }
    }
#pragma unroll
    for (int r = 0; r < 4; r++)
#pragma unroll
      for (int jj = 0; jj < 16; jj++) {
        int j = jbase + jjh + jj;
        float v = acc[r][jj];
        if (j == i0 + r) v = 0.f;  // diagonal zeroed before top-k in reference
        top3_insert(v, j, v0[r], j0[r], v1[r], j1[r], v2[r], j2[r]);
      }
  }
#pragma unroll
  for (int r = 0; r < 4; r++) {
    size_t base = (size_t)(jb * 3) * N + (i0 + r);
    candv[base] = v0[r]; candv[base + N] = v1[r]; candv[base + 2 * N] = v2[r];
    candi[base] = j0[r]; candi[base + N] = j1[r]; candi[base + 2 * N] = j2[r];
  }
}

// merge 128 chunk-candidate sets per row (coalesced chunk-major reads)
__global__ __launch_bounds__(64) void k_merge(const float* __restrict__ candv,
                                              const int* __restrict__ candi,
                                              float* __restrict__ mtv,
                                              int* __restrict__ mtj) {
  int i = blockIdx.x * 64 + threadIdx.x;
  float v0 = -3e38f, v1 = -3e38f, v2 = -3e38f;
  int j0 = 0, j1 = 0, j2 = 0;
  for (int c = 0; c < 384; c++) {
    float v = candv[(size_t)c * N + i];
    int j = candi[(size_t)c * N + i];
    top3_insert(v, j, v0, j0, v1, j1, v2, j2);
  }
  mtv[i * 3 + 0] = v0; mtv[i * 3 + 1] = v1; mtv[i * 3 + 2] = v2;
  mtj[i * 3 + 0] = j0; mtj[i * 3 + 1] = j1; mtj[i * 3 + 2] = j2;
}

// wave-per-row scatter: hidden2[j] += v * h[i], colsum_m[j] += v
__global__ __launch_bounds__(256) void k_scatter(
    const float* __restrict__ mtv, const int* __restrict__ mtj,
    const float* __restrict__ h, float* __restrict__ hidden2,
    float* __restrict__ colsum_m) {
  int i = blockIdx.x * 4 + (threadIdx.x >> 6);
  int lane = threadIdx.x & 63;
  float h0 = h[(size_t)i * H + lane], h1 = h[(size_t)i * H + 64 + lane];
#pragma unroll
  for (int s = 0; s < 3; s++) {
    float v = mtv[i * 3 + s];
    int j = mtj[i * 3 + s];
    atomicAdd(&hidden2[(size_t)j * H + lane], v * h0);
    atomicAdd(&hidden2[(size_t)j * H + 64 + lane], v * h1);
    if (lane == s) atomicAdd(&colsum_m[j], v);
  }
}

// ---------------- launch ----------------

extern "C" void kernel_launch(void* const* d_in, const int* in_sizes, int n_in,
                              void* d_out, int out_size, void* d_ws, size_t ws_size,
                              hipStream_t stream) {
  (void)in_sizes; (void)n_in; (void)out_size; (void)ws_size;
  const float* x   = (const float*)d_in[0];
  const float* cm  = (const float*)d_in[1];
  const float* mv  = (const float*)d_in[2];
  const float* W_ps = (const float*)d_in[3],  *b_ps = (const float*)d_in[4];
  const float* W_psf = (const float*)d_in[5], *b_psf = (const float*)d_in[6];
  const float* W_psb = (const float*)d_in[7], *b_psb = (const float*)d_in[8];
  const float* W_hs = (const float*)d_in[9],  *b_hs = (const float*)d_in[10];
  const float* W_hsf = (const float*)d_in[11], *b_hsf = (const float*)d_in[12];
  const float* W_hsb = (const float*)d_in[13], *b_hsb = (const float*)d_in[14];
  const float* W_in = (const float*)d_in[15], *b_in = (const float*)d_in[16];
  const float* W_out = (const float*)d_in[17], *b_out = (const float*)d_in[18];
  float* out = (float*)d_out;

  float* W = (float*)d_ws;
  size_t o = 0;
  auto alloc = [&](size_t n) { float* p = W + o; o += n; return p; };
  float* colsum_c = alloc(C);
  float* colmax   = alloc(C);
  float* colsumexp= alloc(C);
  float* valid1   = alloc(C);
  float* hnorm_ps = alloc(C);
  float* xnorm    = alloc(N);
  float* diagv    = alloc(N);
  float* colsum_m = alloc(N);
  float* valid2f  = alloc(N);
  float* rowmax   = alloc(N);
  float* rowinv   = alloc(N);
  float* mtv      = alloc(3 * N);
  int*   mtj      = (int*)alloc(3 * N);
  float* hidden1  = alloc((size_t)C * H);
  float* hidden_ps= alloc((size_t)C * H);
  float* scores   = alloc((size_t)N * C);   // scores1 / cs / candv (reused)
  int*   candi    = (int*)alloc((size_t)N * 128 * 3);
  float* ps_pre   = alloc((size_t)N * H);   // later hs_pre
  float* p_shared = alloc((size_t)N * H);   // later h_shared
  float* all_info = alloc((size_t)N * H);
  float* hbuf     = alloc((size_t)N * H);
  float* hhat     = alloc((size_t)N * H);
  float* hidden2  = alloc((size_t)N * H);
  float* h2hat    = alloc((size_t)N * H);
  float* indiv    = alloc((size_t)N * H);
  float* partial  = alloc((size_t)8 * N * H);  // split-K partials (max use)
  float* Sbuf     = alloc((size_t)N * N);      // 64 MB score matrix
  float* candv    = scores;  // alias: cs no longer needed once hs branch runs

  hipMemsetAsync(colsum_c, 0, C * sizeof(float), stream);
  hipMemsetAsync(colsum_m, 0, N * sizeof(float), stream);
  hipMemsetAsync(hidden2, 0, (size_t)N * H * sizeof(float), stream);

  dim3 blk(256);
  // --- ps branch ---
  k_colsum_s2c<<<dim3(C / 64, 16), dim3(64), 0, stream>>>(cm, mv, colsum_c);
  k_gemm_genA<1><<<dim3(2, C / 64, 16), blk, 0, stream>>>(
      cm, mv, colsum_c, nullptr, x, partial, N / 16);
  k_reduce<<<dim3(C * H / 4 / 256), blk, 0, stream>>>(
      partial, hidden1, 16, (size_t)C * H, (size_t)C * H / 4, nullptr);
  k_valid1<<<dim3(C), dim3(64), 0, stream>>>(hidden1, valid1);
  k_gemm_nt<0><<<dim3(C / 64, N / 128), blk, 0, stream>>>(
      x, hidden1, nullptr, scores, C);
  k_colstats<<<dim3(C), blk, 0, stream>>>(scores, colmax, colsumexp);
  k_gemm_genA<2><<<dim3(2, C / 64, 16), blk, 0, stream>>>(
      scores, nullptr, colmax, colsumexp, x, partial, N / 16);
  k_reduce<<<dim3(C * H / 4 / 256), blk, 0, stream>>>(
      partial, hidden_ps, 16, (size_t)C * H, (size_t)C * H / 4, valid1);
  k_rownorm128<<<dim3(N), dim3(64), 0, stream>>>(x, xnorm);
  k_rownorm128<<<dim3(C), dim3(64), 0, stream>>>(hidden_ps, hnorm_ps);
  k_gemm_nt<0><<<dim3(C / 64, N / 128), blk, 0, stream>>>(
      x, hidden_ps, nullptr, scores, C);
  k_cs_softmax<<<dim3(N), blk, 0, stream>>>(scores, xnorm, hnorm_ps, valid1);
  k_gemm_kn<0><<<dim3(2, N / 64, 4), blk, 0, stream>>>(
      scores, C, nullptr, nullptr, hidden_ps, partial, C / 4, N);
  k_reduce<<<dim3(N * H / 4 / 256), blk, 0, stream>>>(
      partial, ps_pre, 4, (size_t)N * H, (size_t)N * H / 4, nullptr);
  k_gemm<1, 0><<<dim3(H / 32, N / 32), blk, 0, stream>>>(
      ps_pre, W_ps, b_ps, nullptr, p_shared, N, H, H);
  k_gemm<1, 3><<<dim3(H / 32, N / 32), blk, 0, stream>>>(
      p_shared, W_psb, b_psb, x, hbuf, N, H, H);             // h = x - p_back
  k_gemm<1, 1><<<dim3(H / 32, N / 32), blk, 0, stream>>>(
      p_shared, W_psf, b_psf, nullptr, all_info, N, H, H);   // out_ps
  // --- hs branch ---
  k_hhat<<<dim3(N), dim3(64), 0, stream>>>(hbuf, hhat, diagv);
  k_topk_cand<<<dim3(128, 4), blk, 0, stream>>>(hhat, candv, candi);
  k_merge<<<dim3(N / 64), dim3(64), 0, stream>>>(candv, candi, mtv, mtj);
  k_scatter<<<dim3(N / 4), blk, 0, stream>>>(mtv, mtj, hbuf, hidden2, colsum_m);
  k_fin_hidden2<<<dim3(N), dim3(64), 0, stream>>>(hbuf, diagv, colsum_m, hidden2,
                                                  h2hat, valid2f);
  k_gemm_nt<1><<<dim3(N / 64, N / 128), blk, 0, stream>>>(
      hhat, h2hat, valid2f, Sbuf, N);
  k_rowstats<<<dim3(N), blk, 0, stream>>>(Sbuf, rowmax, rowinv);
  k_gemm_kn<1><<<dim3(2, N / 64, 8), blk, 0, stream>>>(
      Sbuf, N, rowmax, rowinv, hidden2, partial, N / 8, N);
  k_reduce<<<dim3(N * H / 4 / 256), blk, 0, stream>>>(
      partial, ps_pre, 8, (size_t)N * H, (size_t)N * H / 4, nullptr);  // hs_pre
  k_gemm<1, 0><<<dim3(H / 32, N / 32), blk, 0, stream>>>(
      ps_pre, W_hs, b_hs, nullptr, p_shared, N, H, H);       // h_shared
  k_gemm<1, 2><<<dim3(H / 32, N / 32), blk, 0, stream>>>(
      p_shared, W_hsf, b_hsf, nullptr, all_info, N, H, H);   // += out_hs
  k_gemm<1, 3><<<dim3(H / 32, N / 32), blk, 0, stream>>>(
      p_shared, W_hsb, b_hsb, hbuf, indiv, N, H, H);         // indiv = h - h_back
  k_gemm<1, 2><<<dim3(H / 32, N / 32), blk, 0, stream>>>(
      indiv, W_in, b_in, nullptr, all_info, N, H, H);        // += out_indi
  k_final<<<dim3(N), dim3(64), 0, stream>>>(all_info, W_out, b_out, out);
}

// Round 3
// 848.129 us; speedup vs baseline: 2.9696x; 1.0900x over previous
//
#include <hip/hip_runtime.h>
#include <math.h>

#define N 4096
#define C 512
#define H 128

// ---------------- helpers ----------------

__device__ inline float wave_reduce_sum(float v) {
#pragma unroll
  for (int m = 32; m; m >>= 1) v += __shfl_xor(v, m);
  return v;
}

__device__ inline float lrelu(float v) { return v > 0.f ? v : 0.01f * v; }

// comparator: (v desc, j asc) — matches jax top_k tie-break (lower index wins)
__device__ inline bool better(float v, int j, float w, int k) {
  return (v > w) || (v == w && j < k);
}

__device__ inline void top3_ins(float v, int j, float& v0, int& j0,
                                float& v1, int& j1, float& v2, int& j2) {
  if (better(v, j, v0, j0)) { v2 = v1; j2 = j1; v1 = v0; j1 = j0; v0 = v; j0 = j; }
  else if (better(v, j, v1, j1)) { v2 = v1; j2 = j1; v1 = v; j1 = j; }
  else if (better(v, j, v2, j2)) { v2 = v; j2 = j; }
}

// ---------------- small kernels ----------------

__global__ __launch_bounds__(64) void k_colsum_s2c(
    const float* __restrict__ cm, const float* __restrict__ mv,
    float* __restrict__ colsum_c) {
  int c = blockIdx.x * 64 + threadIdx.x;
  int i0 = blockIdx.y * 256;
  float acc = 0.f;
  for (int i = i0; i < i0 + 256; i++) acc += cm[(size_t)i * C + c] * mv[i];
  atomicAdd(&colsum_c[c], acc);
}

__global__ __launch_bounds__(64) void k_valid1(const float* __restrict__ hid,
                                               float* __restrict__ valid1) {
  int c = blockIdx.x, t = threadIdx.x;
  float s = hid[(size_t)c * H + t] + hid[(size_t)c * H + 64 + t];
  s = wave_reduce_sum(s);
  if (t == 0) valid1[c] = (s != 0.f) ? 1.f : 0.f;
}

__global__ __launch_bounds__(64) void k_rownorm128(const float* __restrict__ A,
                                                   float* __restrict__ nrm) {
  int r = blockIdx.x, t = threadIdx.x;
  float a = A[(size_t)r * H + t], b = A[(size_t)r * H + 64 + t];
  float ss = wave_reduce_sum(a * a + b * b);
  if (t == 0) nrm[r] = sqrtf(ss);
}

__global__ __launch_bounds__(256) void k_colstats(const float* __restrict__ sc,
                                                  float* __restrict__ colmax,
                                                  float* __restrict__ colsum) {
  __shared__ float red[256];
  int c = blockIdx.x, t = threadIdx.x;
  float v[16];
  float m = -3e38f;
#pragma unroll
  for (int q = 0; q < 16; q++) {
    v[q] = sc[(size_t)(q * 256 + t) * C + c];
    m = fmaxf(m, v[q]);
  }
  red[t] = m; __syncthreads();
  for (int s = 128; s; s >>= 1) { if (t < s) red[t] = fmaxf(red[t], red[t + s]); __syncthreads(); }
  m = red[0]; __syncthreads();
  float sum = 0.f;
#pragma unroll
  for (int q = 0; q < 16; q++) sum += __expf(v[q] - m);
  red[t] = sum; __syncthreads();
  for (int s = 128; s; s >>= 1) { if (t < s) red[t] += red[t + s]; __syncthreads(); }
  if (t == 0) { colmax[c] = m; colsum[c] = red[0]; }
}

__global__ __launch_bounds__(256) void k_cs_softmax(
    float* __restrict__ sc, const float* __restrict__ xnorm,
    const float* __restrict__ hnorm, const float* __restrict__ valid1) {
  __shared__ float red[256];
  int i = blockIdx.x, t = threadIdx.x;
  float xn = xnorm[i];
  float r0 = sc[(size_t)i * C + t], r1 = sc[(size_t)i * C + 256 + t];
  float d0 = xn * hnorm[t], d1 = xn * hnorm[256 + t];
  float c0 = r0 / (d0 == 0.f ? 1.f : d0);
  float c1 = r1 / (d1 == 0.f ? 1.f : d1);
  float s0 = (valid1[t] != 0.f) ? c0 : -3e38f;
  float s1 = (valid1[256 + t] != 0.f) ? c1 : -3e38f;
  red[t] = fmaxf(s0, s1); __syncthreads();
  for (int s = 128; s; s >>= 1) { if (t < s) red[t] = fmaxf(red[t], red[t + s]); __syncthreads(); }
  float m = red[0]; __syncthreads();
  float p0 = (s0 > -1e37f) ? __expf(s0 - m) : 0.f;
  float p1 = (s1 > -1e37f) ? __expf(s1 - m) : 0.f;
  red[t] = p0 + p1; __syncthreads();
  for (int s = 128; s; s >>= 1) { if (t < s) red[t] += red[t + s]; __syncthreads(); }
  float inv = 1.f / red[0];
  sc[(size_t)i * C + t] = p0 * inv;
  sc[(size_t)i * C + 256 + t] = p1 * inv;
}

__global__ __launch_bounds__(64) void k_hhat(const float* __restrict__ h,
                                             float* __restrict__ hhat,
                                             float* __restrict__ diagv) {
  int i = blockIdx.x, t = threadIdx.x;
  float a = h[(size_t)i * H + t], b = h[(size_t)i * H + 64 + t];
  float ss = wave_reduce_sum(a * a + b * b);
  float hn = sqrtf(ss);
  float den = hn * hn;
  float dg = (den == 0.f) ? 0.f : ss / den;
  float inv = (ss > 0.f) ? (1.f / hn) : 1.f;
  hhat[(size_t)i * H + t] = a * inv;
  hhat[(size_t)i * H + 64 + t] = b * inv;
  if (t == 0) diagv[i] = dg;
}

__global__ __launch_bounds__(64) void k_fin_hidden2(
    const float* __restrict__ h, const float* __restrict__ diagv,
    const float* __restrict__ colsum_m, float* __restrict__ hidden2,
    float* __restrict__ h2hat, float* __restrict__ valid2f) {
  int j = blockIdx.x, t = threadIdx.x;
  float add = (colsum_m[j] != 0.f) ? diagv[j] : 0.f;
  float a = hidden2[(size_t)j * H + t] + add * h[(size_t)j * H + t];
  float b = hidden2[(size_t)j * H + 64 + t] + add * h[(size_t)j * H + 64 + t];
  float s = a + b, ss = a * a + b * b;
#pragma unroll
  for (int m = 32; m; m >>= 1) { s += __shfl_xor(s, m); ss += __shfl_xor(ss, m); }
  bool valid = (s != 0.f);
  a = valid ? a : 0.f; b = valid ? b : 0.f;
  hidden2[(size_t)j * H + t] = a;
  hidden2[(size_t)j * H + 64 + t] = b;
  float inv = (valid && ss > 0.f) ? (1.f / sqrtf(ss)) : 1.f;
  h2hat[(size_t)j * H + t] = a * inv;
  h2hat[(size_t)j * H + 64 + t] = b * inv;
  if (t == 0) valid2f[j] = valid ? 1.f : 0.f;
}

__global__ __launch_bounds__(256) void k_rowstats(const float* __restrict__ S,
                                                  float* __restrict__ rowmax,
                                                  float* __restrict__ rowinv) {
  __shared__ float red[256];
  int i = blockIdx.x, t = threadIdx.x;
  float4 v[4];
  float m = -3e38f;
#pragma unroll
  for (int q = 0; q < 4; q++) {
    v[q] = *(const float4*)&S[(size_t)i * N + q * 1024 + t * 4];
    m = fmaxf(m, fmaxf(fmaxf(v[q].x, v[q].y), fmaxf(v[q].z, v[q].w)));
  }
  red[t] = m; __syncthreads();
  for (int s = 128; s; s >>= 1) { if (t < s) red[t] = fmaxf(red[t], red[t + s]); __syncthreads(); }
  m = red[0]; __syncthreads();
  float sum = 0.f;
#pragma unroll
  for (int q = 0; q < 4; q++)
    sum += __expf(v[q].x - m) + __expf(v[q].y - m) + __expf(v[q].z - m) + __expf(v[q].w - m);
  red[t] = sum; __syncthreads();
  for (int s = 128; s; s >>= 1) { if (t < s) red[t] += red[t + s]; __syncthreads(); }
  if (t == 0) { rowmax[i] = m; rowinv[i] = 1.f / red[0]; }
}

__global__ __launch_bounds__(64) void k_final(const float* __restrict__ ai,
                                              const float* __restrict__ Wout,
                                              const float* __restrict__ bout,
                                              float* __restrict__ out) {
  int i = blockIdx.x, t = threadIdx.x;
  float s = ai[(size_t)i * H + t] * Wout[t] + ai[(size_t)i * H + 64 + t] * Wout[64 + t];
  s = wave_reduce_sum(s);
  if (t == 0) out[i] = s + bout[0];
}

// ---------------- big NT GEMM: out[M,Nn] = A[M,128] @ B[Nn,128]^T ----------------
// tile 128x64, 256 threads, 8x4 micro. MASK: validn[n]==0 -> store -3e38
template <int MASK>
__global__ __launch_bounds__(256) void k_gemm_nt(
    const float* __restrict__ A, const float* __restrict__ B,
    const float* __restrict__ validn, float* __restrict__ out, int Nn) {
  __shared__ float As[32][132];
  __shared__ float Bs[32][68];
  int tid = threadIdx.x;
  int tx = tid & 15, ty = tid >> 4;
  int bm = blockIdx.y * 128, bn = blockIdx.x * 64;
  float acc[8][4];
#pragma unroll
  for (int r = 0; r < 8; r++)
#pragma unroll
    for (int c = 0; c < 4; c++) acc[r][c] = 0.f;
  for (int kt = 0; kt < 128; kt += 32) {
#pragma unroll
    for (int q = 0; q < 4; q++) {
      int f = q * 256 + tid;
      int row = f >> 3, kq = f & 7;
      float4 av = *(const float4*)&A[(size_t)(bm + row) * 128 + kt + kq * 4];
      As[kq * 4 + 0][row] = av.x; As[kq * 4 + 1][row] = av.y;
      As[kq * 4 + 2][row] = av.z; As[kq * 4 + 3][row] = av.w;
    }
#pragma unroll
    for (int q = 0; q < 2; q++) {
      int f = q * 256 + tid;
      int row = f >> 3, kq = f & 7;
      float4 bv = *(const float4*)&B[(size_t)(bn + row) * 128 + kt + kq * 4];
      Bs[kq * 4 + 0][row] = bv.x; Bs[kq * 4 + 1][row] = bv.y;
      Bs[kq * 4 + 2][row] = bv.z; Bs[kq * 4 + 3][row] = bv.w;
    }
    __syncthreads();
#pragma unroll
    for (int kk = 0; kk < 32; kk++) {
      float4 a0 = *(float4*)&As[kk][ty * 8];
      float4 a1 = *(float4*)&As[kk][ty * 8 + 4];
      float4 fb = *(float4*)&Bs[kk][tx * 4];
      float am[8] = {a0.x, a0.y, a0.z, a0.w, a1.x, a1.y, a1.z, a1.w};
      float bn_[4] = {fb.x, fb.y, fb.z, fb.w};
#pragma unroll
      for (int r = 0; r < 8; r++)
#pragma unroll
        for (int c = 0; c < 4; c++) acc[r][c] += am[r] * bn_[c];
    }
    __syncthreads();
  }
  float4 vm = MASK ? *(const float4*)&validn[bn + tx * 4] : float4{1, 1, 1, 1};
#pragma unroll
  for (int r = 0; r < 8; r++) {
    float4 v;
    v.x = acc[r][0]; v.y = acc[r][1]; v.z = acc[r][2]; v.w = acc[r][3];
    if (MASK) {
      v.x = (vm.x != 0.f) ? v.x : -3e38f;
      v.y = (vm.y != 0.f) ? v.y : -3e38f;
      v.z = (vm.z != 0.f) ? v.z : -3e38f;
      v.w = (vm.w != 0.f) ? v.w : -3e38f;
    }
    *(float4*)&out[(size_t)(bm + ty * 8 + r) * Nn + bn + tx * 4] = v;
  }
}

// ---- same GEMM but epilogue = per-row top3 over the 64-col chunk (diag=0) ----
// candidates chunk-major: candv[(cb*3+s)*N + i], cb = blockIdx.x (64 chunks)
__global__ __launch_bounds__(256) void k_gemm_nt_top3(
    const float* __restrict__ A, float* __restrict__ candv,
    int* __restrict__ candi) {
  __shared__ float As[32][132];
  __shared__ float Bs[32][68];
  int tid = threadIdx.x;
  int tx = tid & 15, ty = tid >> 4;
  int bm = blockIdx.y * 128, bn = blockIdx.x * 64;
  float acc[8][4];
#pragma unroll
  for (int r = 0; r < 8; r++)
#pragma unroll
    for (int c = 0; c < 4; c++) acc[r][c] = 0.f;
  for (int kt = 0; kt < 128; kt += 32) {
#pragma unroll
    for (int q = 0; q < 4; q++) {
      int f = q * 256 + tid;
      int row = f >> 3, kq = f & 7;
      float4 av = *(const float4*)&A[(size_t)(bm + row) * 128 + kt + kq * 4];
      As[kq * 4 + 0][row] = av.x; As[kq * 4 + 1][row] = av.y;
      As[kq * 4 + 2][row] = av.z; As[kq * 4 + 3][row] = av.w;
    }
#pragma unroll
    for (int q = 0; q < 2; q++) {
      int f = q * 256 + tid;
      int row = f >> 3, kq = f & 7;
      float4 bv = *(const float4*)&A[(size_t)(bn + row) * 128 + kt + kq * 4];
      Bs[kq * 4 + 0][row] = bv.x; Bs[kq * 4 + 1][row] = bv.y;
      Bs[kq * 4 + 2][row] = bv.z; Bs[kq * 4 + 3][row] = bv.w;
    }
    __syncthreads();
#pragma unroll
    for (int kk = 0; kk < 32; kk++) {
      float4 a0 = *(float4*)&As[kk][ty * 8];
      float4 a1 = *(float4*)&As[kk][ty * 8 + 4];
      float4 fb = *(float4*)&Bs[kk][tx * 4];
      float am[8] = {a0.x, a0.y, a0.z, a0.w, a1.x, a1.y, a1.z, a1.w};
      float bn_[4] = {fb.x, fb.y, fb.z, fb.w};
#pragma unroll
      for (int r = 0; r < 8; r++)
#pragma unroll
        for (int c = 0; c < 4; c++) acc[r][c] += am[r] * bn_[c];
    }
    __syncthreads();
  }
#pragma unroll
  for (int r = 0; r < 8; r++) {
    int i = bm + ty * 8 + r;
    float v0 = -3e38f, v1 = -3e38f, v2 = -3e38f;
    int j0 = 0, j1 = 0, j2 = 0;
#pragma unroll
    for (int c = 0; c < 4; c++) {
      int j = bn + tx * 4 + c;
      float v = (j == i) ? 0.f : acc[r][c];  // reference zeroes the diagonal
      top3_ins(v, j, v0, j0, v1, j1, v2, j2);
    }
    // butterfly merge across the 16 tx lanes (same ty within the wave)
#pragma unroll
    for (int s = 1; s < 16; s <<= 1) {
      float w0 = __shfl_xor(v0, s), w1 = __shfl_xor(v1, s), w2 = __shfl_xor(v2, s);
      int k0 = __shfl_xor(j0, s), k1 = __shfl_xor(j1, s), k2 = __shfl_xor(j2, s);
      top3_ins(w0, k0, v0, j0, v1, j1, v2, j2);
      top3_ins(w1, k1, v0, j0, v1, j1, v2, j2);
      top3_ins(w2, k2, v0, j0, v1, j1, v2, j2);
    }
    if (tx == 0) {
      size_t base = (size_t)(blockIdx.x * 3) * N + i;
      candv[base] = v0; candv[base + N] = v1; candv[base + 2 * N] = v2;
      candi[base] = j0; candi[base + N] = j1; candi[base + 2 * N] = j2;
    }
  }
}

// merge 64 chunk-candidate sets per row (coalesced chunk-major reads)
__global__ __launch_bounds__(256) void k_merge(const float* __restrict__ candv,
                                               const int* __restrict__ candi,
                                               float* __restrict__ mtv,
                                               int* __restrict__ mtj) {
  int i = blockIdx.x * 256 + threadIdx.x;
  float v0 = -3e38f, v1 = -3e38f, v2 = -3e38f;
  int j0 = 0, j1 = 0, j2 = 0;
  for (int c = 0; c < 192; c++) {
    float v = candv[(size_t)c * N + i];
    int j = candi[(size_t)c * N + i];
    top3_ins(v, j, v0, j0, v1, j1, v2, j2);
  }
  mtv[i * 3 + 0] = v0; mtv[i * 3 + 1] = v1; mtv[i * 3 + 2] = v2;
  mtj[i * 3 + 0] = j0; mtj[i * 3 + 1] = j1; mtj[i * 3 + 2] = j2;
}

// wave-per-row scatter: hidden2[j] += v * h[i], colsum_m[j] += v
__global__ __launch_bounds__(256) void k_scatter(
    const float* __restrict__ mtv, const int* __restrict__ mtj,
    const float* __restrict__ h, float* __restrict__ hidden2,
    float* __restrict__ colsum_m) {
  int i = blockIdx.x * 4 + (threadIdx.x >> 6);
  int lane = threadIdx.x & 63;
  float h0 = h[(size_t)i * H + lane], h1 = h[(size_t)i * H + 64 + lane];
#pragma unroll
  for (int s = 0; s < 3; s++) {
    float v = mtv[i * 3 + s];
    int j = mtj[i * 3 + s];
    atomicAdd(&hidden2[(size_t)j * H + lane], v * h0);
    atomicAdd(&hidden2[(size_t)j * H + 64 + lane], v * h1);
    if (lane == s) atomicAdd(&colsum_m[j], v);
  }
}

// ---------------- split-K KN GEMM: partial[z] = A'[M,K-chunk] @ B[K,128] -------
template <int EXP>
__global__ __launch_bounds__(256) void k_gemm_kn(
    const float* __restrict__ A, int lda,
    const float* __restrict__ rowmax, const float* __restrict__ rowinv,
    const float* __restrict__ B, float* __restrict__ partial, int KC, int M) {
  __shared__ float As[32][68];
  __shared__ float Bs[32][68];
  int tid = threadIdx.x;
  int tx = tid & 15, ty = tid >> 4;
  int bm = blockIdx.y * 64, bn = blockIdx.x * 64;
  int k0 = blockIdx.z * KC;
  float acc[4][4];
#pragma unroll
  for (int r = 0; r < 4; r++)
#pragma unroll
    for (int c = 0; c < 4; c++) acc[r][c] = 0.f;
  for (int kt = 0; kt < KC; kt += 32) {
#pragma unroll
    for (int q = 0; q < 2; q++) {
      int f = q * 256 + tid;
      int row = f >> 3, kq = f & 7;
      float4 av = *(const float4*)&A[(size_t)(bm + row) * lda + k0 + kt + kq * 4];
      if (EXP) {
        float rm = rowmax[bm + row], ri = rowinv[bm + row];
        av.x = __expf(av.x - rm) * ri; av.y = __expf(av.y - rm) * ri;
        av.z = __expf(av.z - rm) * ri; av.w = __expf(av.w - rm) * ri;
      }
      As[kq * 4 + 0][row] = av.x; As[kq * 4 + 1][row] = av.y;
      As[kq * 4 + 2][row] = av.z; As[kq * 4 + 3][row] = av.w;
      int kr = f >> 4, nq = f & 15;
      float4 bv = *(const float4*)&B[(size_t)(k0 + kt + kr) * 128 + bn + nq * 4];
      *(float4*)&Bs[kr][nq * 4] = bv;
    }
    __syncthreads();
#pragma unroll
    for (int kk = 0; kk < 32; kk++) {
      float4 fa = *(float4*)&As[kk][ty * 4];
      float4 fb = *(float4*)&Bs[kk][tx * 4];
      float am[4] = {fa.x, fa.y, fa.z, fa.w};
      float bb[4] = {fb.x, fb.y, fb.z, fb.w};
#pragma unroll
      for (int r = 0; r < 4; r++)
#pragma unroll
        for (int c = 0; c < 4; c++) acc[r][c] += am[r] * bb[c];
    }
    __syncthreads();
  }
  float* pp = partial + (size_t)blockIdx.z * M * 128;
#pragma unroll
  for (int r = 0; r < 4; r++) {
    float4 v = {acc[r][0], acc[r][1], acc[r][2], acc[r][3]};
    *(float4*)&pp[(size_t)(bm + ty * 4 + r) * 128 + bn + tx * 4] = v;
  }
}

// ---------------- split-K GEMM with generated A^T ----------------
template <int AMODE>
__global__ __launch_bounds__(256) void k_gemm_genA(
    const float* __restrict__ P, const float* __restrict__ mv,
    const float* __restrict__ col1, const float* __restrict__ col2,
    const float* __restrict__ B, float* __restrict__ partial, int KC) {
  __shared__ float Ps[32][68];
  __shared__ float Bs[32][68];
  int tid = threadIdx.x;
  int tx = tid & 15, ty = tid >> 4;
  int bm = blockIdx.y * 64, bn = blockIdx.x * 64;
  int k0 = blockIdx.z * KC;
  float acc[4][4];
#pragma unroll
  for (int r = 0; r < 4; r++)
#pragma unroll
    for (int c = 0; c < 4; c++) acc[r][c] = 0.f;
  for (int kt = 0; kt < KC; kt += 32) {
#pragma unroll
    for (int q = 0; q < 2; q++) {
      int f = q * 256 + tid;
      int kr = f >> 4, nq = f & 15;
      int k = k0 + kt + kr;
      float4 pv = *(const float4*)&P[(size_t)k * C + bm + nq * 4];
      float4 av;
      if (AMODE == 1) {
        float m = mv[k];
        float4 cs = *(const float4*)&col1[bm + nq * 4];
        av.x = pv.x * m / (cs.x * pv.x + 1.f);
        av.y = pv.y * m / (cs.y * pv.y + 1.f);
        av.z = pv.z * m / (cs.z * pv.z + 1.f);
        av.w = pv.w * m / (cs.w * pv.w + 1.f);
      } else {
        float4 cm_ = *(const float4*)&col1[bm + nq * 4];
        float4 cd = *(const float4*)&col2[bm + nq * 4];
        av.x = __expf(pv.x - cm_.x) / cd.x;
        av.y = __expf(pv.y - cm_.y) / cd.y;
        av.z = __expf(pv.z - cm_.z) / cd.z;
        av.w = __expf(pv.w - cm_.w) / cd.w;
      }
      *(float4*)&Ps[kr][nq * 4] = av;
      float4 bv = *(const float4*)&B[(size_t)k * 128 + bn + nq * 4];
      *(float4*)&Bs[kr][nq * 4] = bv;
    }
    __syncthreads();
#pragma unroll
    for (int kk = 0; kk < 32; kk++) {
      float4 fa = *(float4*)&Ps[kk][ty * 4];
      float4 fb = *(float4*)&Bs[kk][tx * 4];
      float am[4] = {fa.x, fa.y, fa.z, fa.w};
      float bb[4] = {fb.x, fb.y, fb.z, fb.w};
#pragma unroll
      for (int r = 0; r < 4; r++)
#pragma unroll
        for (int c = 0; c < 4; c++) acc[r][c] += am[r] * bb[c];
    }
    __syncthreads();
  }
  float* pp = partial + (size_t)blockIdx.z * C * 128;
#pragma unroll
  for (int r = 0; r < 4; r++) {
    float4 v = {acc[r][0], acc[r][1], acc[r][2], acc[r][3]};
    *(float4*)&pp[(size_t)(bm + ty * 4 + r) * 128 + bn + tx * 4] = v;
  }
}

// reduce split-K partials; optional per-row (128-wide) valid scale
__global__ __launch_bounds__(256) void k_reduce(
    const float* __restrict__ partial, float* __restrict__ out, int cnt,
    size_t slot, size_t size4, const float* __restrict__ validm) {
  size_t idx = (size_t)blockIdx.x * 256 + threadIdx.x;
  if (idx >= size4) return;
  float4 s = {0, 0, 0, 0};
  for (int c = 0; c < cnt; c++) {
    float4 v = *(const float4*)&partial[c * slot + idx * 4];
    s.x += v.x; s.y += v.y; s.z += v.z; s.w += v.w;
  }
  if (validm) {
    float sc = validm[idx >> 5];
    s.x *= sc; s.y *= sc; s.z *= sc; s.w *= sc;
  }
  *(float4*)&out[idx * 4] = s;
}

// ---------------- linear: out[4096,128] = epi(A[4096,128] @ W[128,128]^T + b) --
// tile 64x64, 4x4 micro. EPI: 0 store, 1 lrelu, 2 +=lrelu, 3 aux - v
template <int EPI>
__global__ __launch_bounds__(256) void k_gemm_lin(
    const float* __restrict__ A, const float* __restrict__ Wt,
    const float* __restrict__ bias, const float* __restrict__ aux,
    float* __restrict__ out) {
  __shared__ float As[32][68];
  __shared__ float Ws[32][68];
  int tid = threadIdx.x;
  int tx = tid & 15, ty = tid >> 4;
  int bm = blockIdx.y * 64, bn = blockIdx.x * 64;
  float acc[4][4];
#pragma unroll
  for (int r = 0; r < 4; r++)
#pragma unroll
    for (int c = 0; c < 4; c++) acc[r][c] = 0.f;
  for (int kt = 0; kt < 128; kt += 32) {
#pragma unroll
    for (int q = 0; q < 2; q++) {
      int f = q * 256 + tid;
      int row = f >> 3, kq = f & 7;
      float4 av = *(const float4*)&A[(size_t)(bm + row) * 128 + kt + kq * 4];
      As[kq * 4 + 0][row] = av.x; As[kq * 4 + 1][row] = av.y;
      As[kq * 4 + 2][row] = av.z; As[kq * 4 + 3][row] = av.w;
      float4 wv = *(const float4*)&Wt[(size_t)(bn + row) * 128 + kt + kq * 4];
      Ws[kq * 4 + 0][row] = wv.x; Ws[kq * 4 + 1][row] = wv.y;
      Ws[kq * 4 + 2][row] = wv.z; Ws[kq * 4 + 3][row] = wv.w;
    }
    __syncthreads();
#pragma unroll
    for (int kk = 0; kk < 32; kk++) {
      float4 fa = *(float4*)&As[kk][ty * 4];
      float4 fb = *(float4*)&Ws[kk][tx * 4];
      float am[4] = {fa.x, fa.y, fa.z, fa.w};
      float bb[4] = {fb.x, fb.y, fb.z, fb.w};
#pragma unroll
      for (int r = 0; r < 4; r++)
#pragma unroll
        for (int c = 0; c < 4; c++) acc[r][c] += am[r] * bb[c];
    }
    __syncthreads();
  }
  float4 bb = *(const float4*)&bias[bn + tx * 4];
  float bv[4] = {bb.x, bb.y, bb.z, bb.w};
#pragma unroll
  for (int r = 0; r < 4; r++) {
    size_t off = (size_t)(bm + ty * 4 + r) * 128 + bn + tx * 4;
    float v[4];
#pragma unroll
    for (int c = 0; c < 4; c++) v[c] = acc[r][c] + bv[c];
    if (EPI == 0) {
      float4 s = {v[0], v[1], v[2], v[3]};
      *(float4*)&out[off] = s;
    } else if (EPI == 1) {
      float4 s = {lrelu(v[0]), lrelu(v[1]), lrelu(v[2]), lrelu(v[3])};
      *(float4*)&out[off] = s;
    } else if (EPI == 2) {
      float4 p = *(float4*)&out[off];
      p.x += lrelu(v[0]); p.y += lrelu(v[1]); p.z += lrelu(v[2]); p.w += lrelu(v[3]);
      *(float4*)&out[off] = p;
    } else {
      float4 a = *(const float4*)&aux[off];
      float4 s = {a.x - v[0], a.y - v[1], a.z - v[2], a.w - v[3]};
      *(float4*)&out[off] = s;
    }
  }
}

// ---------------- launch ----------------

extern "C" void kernel_launch(void* const* d_in, const int* in_sizes, int n_in,
                              void* d_out, int out_size, void* d_ws, size_t ws_size,
                              hipStream_t stream) {
  (void)in_sizes; (void)n_in; (void)out_size; (void)ws_size;
  const float* x   = (const float*)d_in[0];
  const float* cm  = (const float*)d_in[1];
  const float* mv  = (const float*)d_in[2];
  const float* W_ps = (const float*)d_in[3],  *b_ps = (const float*)d_in[4];
  const float* W_psf = (const float*)d_in[5], *b_psf = (const float*)d_in[6];
  const float* W_psb = (const float*)d_in[7], *b_psb = (const float*)d_in[8];
  const float* W_hs = (const float*)d_in[9],  *b_hs = (const float*)d_in[10];
  const float* W_hsf = (const float*)d_in[11], *b_hsf = (const float*)d_in[12];
  const float* W_hsb = (const float*)d_in[13], *b_hsb = (const float*)d_in[14];
  const float* W_in = (const float*)d_in[15], *b_in = (const float*)d_in[16];
  const float* W_out = (const float*)d_in[17], *b_out = (const float*)d_in[18];
  float* out = (float*)d_out;

  float* W = (float*)d_ws;
  size_t o = 0;
  auto alloc = [&](size_t n) { float* p = W + o; o += n; return p; };
  float* colsum_c = alloc(C);
  float* colmax   = alloc(C);
  float* colsumexp= alloc(C);
  float* valid1   = alloc(C);
  float* hnorm_ps = alloc(C);
  float* xnorm    = alloc(N);
  float* diagv    = alloc(N);
  float* colsum_m = alloc(N);
  float* valid2f  = alloc(N);
  float* rowmax   = alloc(N);
  float* rowinv   = alloc(N);
  float* mtv      = alloc(3 * N);
  int*   mtj      = (int*)alloc(3 * N);
  float* hidden1  = alloc((size_t)C * H);
  float* hidden_ps= alloc((size_t)C * H);
  float* scores   = alloc((size_t)N * C);   // scores1 / cs / candv (reused)
  int*   candi    = (int*)alloc((size_t)N * 64 * 3);
  float* ps_pre   = alloc((size_t)N * H);   // later hs_pre
  float* p_shared = alloc((size_t)N * H);   // later h_shared
  float* all_info = alloc((size_t)N * H);
  float* hbuf     = alloc((size_t)N * H);
  float* hhat     = alloc((size_t)N * H);
  float* hidden2  = alloc((size_t)N * H);
  float* h2hat    = alloc((size_t)N * H);
  float* indiv    = alloc((size_t)N * H);
  float* partial  = alloc((size_t)8 * N * H);  // split-K partials (max use)
  float* Sbuf     = alloc((size_t)N * N);      // 64 MB score matrix
  float* candv    = scores;  // alias: cs no longer needed once hs branch runs

  hipMemsetAsync(colsum_c, 0, C * sizeof(float), stream);
  hipMemsetAsync(colsum_m, 0, N * sizeof(float), stream);
  hipMemsetAsync(hidden2, 0, (size_t)N * H * sizeof(float), stream);

  dim3 blk(256);
  // --- ps branch ---
  k_colsum_s2c<<<dim3(C / 64, 16), dim3(64), 0, stream>>>(cm, mv, colsum_c);
  k_gemm_genA<1><<<dim3(2, C / 64, 16), blk, 0, stream>>>(
      cm, mv, colsum_c, nullptr, x, partial, N / 16);
  k_reduce<<<dim3(C * H / 4 / 256), blk, 0, stream>>>(
      partial, hidden1, 16, (size_t)C * H, (size_t)C * H / 4, nullptr);
  k_valid1<<<dim3(C), dim3(64), 0, stream>>>(hidden1, valid1);
  k_gemm_nt<0><<<dim3(C / 64, N / 128), blk, 0, stream>>>(
      x, hidden1, nullptr, scores, C);
  k_colstats<<<dim3(C), blk, 0, stream>>>(scores, colmax, colsumexp);
  k_gemm_genA<2><<<dim3(2, C / 64, 16), blk, 0, stream>>>(
      scores, nullptr, colmax, colsumexp, x, partial, N / 16);
  k_reduce<<<dim3(C * H / 4 / 256), blk, 0, stream>>>(
      partial, hidden_ps, 16, (size_t)C * H, (size_t)C * H / 4, valid1);
  k_rownorm128<<<dim3(N), dim3(64), 0, stream>>>(x, xnorm);
  k_rownorm128<<<dim3(C), dim3(64), 0, stream>>>(hidden_ps, hnorm_ps);
  k_gemm_nt<0><<<dim3(C / 64, N / 128), blk, 0, stream>>>(
      x, hidden_ps, nullptr, scores, C);
  k_cs_softmax<<<dim3(N), blk, 0, stream>>>(scores, xnorm, hnorm_ps, valid1);
  k_gemm_kn<0><<<dim3(2, N / 64, 4), blk, 0, stream>>>(
      scores, C, nullptr, nullptr, hidden_ps, partial, C / 4, N);
  k_reduce<<<dim3(N * H / 4 / 256), blk, 0, stream>>>(
      partial, ps_pre, 4, (size_t)N * H, (size_t)N * H / 4, nullptr);
  k_gemm_lin<0><<<dim3(2, N / 64), blk, 0, stream>>>(
      ps_pre, W_ps, b_ps, nullptr, p_shared);
  k_gemm_lin<3><<<dim3(2, N / 64), blk, 0, stream>>>(
      p_shared, W_psb, b_psb, x, hbuf);                      // h = x - p_back
  k_gemm_lin<1><<<dim3(2, N / 64), blk, 0, stream>>>(
      p_shared, W_psf, b_psf, nullptr, all_info);            // out_ps
  // --- hs branch ---
  k_hhat<<<dim3(N), dim3(64), 0, stream>>>(hbuf, hhat, diagv);
  k_gemm_nt_top3<<<dim3(N / 64, N / 128), blk, 0, stream>>>(hhat, candv, candi);
  k_merge<<<dim3(N / 256), blk, 0, stream>>>(candv, candi, mtv, mtj);
  k_scatter<<<dim3(N / 4), blk, 0, stream>>>(mtv, mtj, hbuf, hidden2, colsum_m);
  k_fin_hidden2<<<dim3(N), dim3(64), 0, stream>>>(hbuf, diagv, colsum_m, hidden2,
                                                  h2hat, valid2f);
  k_gemm_nt<1><<<dim3(N / 64, N / 128), blk, 0, stream>>>(
      hhat, h2hat, valid2f, Sbuf, N);
  k_rowstats<<<dim3(N), blk, 0, stream>>>(Sbuf, rowmax, rowinv);
  k_gemm_kn<1><<<dim3(2, N / 64, 8), blk, 0, stream>>>(
      Sbuf, N, rowmax, rowinv, hidden2, partial, N / 8, N);
  k_reduce<<<dim3(N * H / 4 / 256), blk, 0, stream>>>(
      partial, ps_pre, 8, (size_t)N * H, (size_t)N * H / 4, nullptr);  // hs_pre
  k_gemm_lin<0><<<dim3(2, N / 64), blk, 0, stream>>>(
      ps_pre, W_hs, b_hs, nullptr, p_shared);                // h_shared
  k_gemm_lin<2><<<dim3(2, N / 64), blk, 0, stream>>>(
      p_shared, W_hsf, b_hsf, nullptr, all_info);            // += out_hs
  k_gemm_lin<3><<<dim3(2, N / 64), blk, 0, stream>>>(
      p_shared, W_hsb, b_hsb, hbuf, indiv);                  // indiv = h - h_back
  k_gemm_lin<2><<<dim3(2, N / 64), blk, 0, stream>>>(
      indiv, W_in, b_in, nullptr, all_info);                 // += out_indi
  k_final<<<dim3(N), dim3(64), 0, stream>>>(all_info, W_out, b_out, out);
}

// Round 4
// 778.254 us; speedup vs baseline: 3.2362x; 1.0898x over previous
//
#include <hip/hip_runtime.h>
#include <math.h>

#define N 4096
#define C 512
#define H 128

// ---------------- helpers ----------------

__device__ inline float wave_reduce_sum(float v) {
#pragma unroll
  for (int m = 32; m; m >>= 1) v += __shfl_xor(v, m);
  return v;
}

__device__ inline float lrelu(float v) { return v > 0.f ? v : 0.01f * v; }

// comparator: (v desc, j asc) — matches jax top_k tie-break (lower index wins)
__device__ inline bool better(float v, int j, float w, int k) {
  return (v > w) || (v == w && j < k);
}

__device__ inline void top3_ins(float v, int j, float& v0, int& j0,
                                float& v1, int& j1, float& v2, int& j2) {
  if (better(v, j, v0, j0)) { v2 = v1; j2 = j1; v1 = v0; j1 = j0; v0 = v; j0 = j; }
  else if (better(v, j, v1, j1)) { v2 = v1; j2 = j1; v1 = v; j1 = j; }
  else if (better(v, j, v2, j2)) { v2 = v; j2 = j; }
}

// ---------------- small kernels ----------------

__global__ __launch_bounds__(64) void k_colsum_s2c(
    const float* __restrict__ cm, const float* __restrict__ mv,
    float* __restrict__ colsum_c) {
  int c = blockIdx.x * 64 + threadIdx.x;
  int i0 = blockIdx.y * 256;
  float acc = 0.f;
  for (int i = i0; i < i0 + 256; i++) acc += cm[(size_t)i * C + c] * mv[i];
  atomicAdd(&colsum_c[c], acc);
}

__global__ __launch_bounds__(64) void k_valid1(const float* __restrict__ hid,
                                               float* __restrict__ valid1) {
  int c = blockIdx.x, t = threadIdx.x;
  float s = hid[(size_t)c * H + t] + hid[(size_t)c * H + 64 + t];
  s = wave_reduce_sum(s);
  if (t == 0) valid1[c] = (s != 0.f) ? 1.f : 0.f;
}

__global__ __launch_bounds__(64) void k_rownorm128(const float* __restrict__ A,
                                                   float* __restrict__ nrm) {
  int r = blockIdx.x, t = threadIdx.x;
  float a = A[(size_t)r * H + t], b = A[(size_t)r * H + 64 + t];
  float ss = wave_reduce_sum(a * a + b * b);
  if (t == 0) nrm[r] = sqrtf(ss);
}

__global__ __launch_bounds__(256) void k_colstats(const float* __restrict__ sc,
                                                  float* __restrict__ colmax,
                                                  float* __restrict__ colsum) {
  __shared__ float red[256];
  int c = blockIdx.x, t = threadIdx.x;
  float v[16];
  float m = -3e38f;
#pragma unroll
  for (int q = 0; q < 16; q++) {
    v[q] = sc[(size_t)(q * 256 + t) * C + c];
    m = fmaxf(m, v[q]);
  }
  red[t] = m; __syncthreads();
  for (int s = 128; s; s >>= 1) { if (t < s) red[t] = fmaxf(red[t], red[t + s]); __syncthreads(); }
  m = red[0]; __syncthreads();
  float sum = 0.f;
#pragma unroll
  for (int q = 0; q < 16; q++) sum += __expf(v[q] - m);
  red[t] = sum; __syncthreads();
  for (int s = 128; s; s >>= 1) { if (t < s) red[t] += red[t + s]; __syncthreads(); }
  if (t == 0) { colmax[c] = m; colsum[c] = red[0]; }
}

__global__ __launch_bounds__(256) void k_cs_softmax(
    float* __restrict__ sc, const float* __restrict__ xnorm,
    const float* __restrict__ hnorm, const float* __restrict__ valid1) {
  __shared__ float red[256];
  int i = blockIdx.x, t = threadIdx.x;
  float xn = xnorm[i];
  float r0 = sc[(size_t)i * C + t], r1 = sc[(size_t)i * C + 256 + t];
  float d0 = xn * hnorm[t], d1 = xn * hnorm[256 + t];
  float c0 = r0 / (d0 == 0.f ? 1.f : d0);
  float c1 = r1 / (d1 == 0.f ? 1.f : d1);
  float s0 = (valid1[t] != 0.f) ? c0 : -3e38f;
  float s1 = (valid1[256 + t] != 0.f) ? c1 : -3e38f;
  red[t] = fmaxf(s0, s1); __syncthreads();
  for (int s = 128; s; s >>= 1) { if (t < s) red[t] = fmaxf(red[t], red[t + s]); __syncthreads(); }
  float m = red[0]; __syncthreads();
  float p0 = (s0 > -1e37f) ? __expf(s0 - m) : 0.f;
  float p1 = (s1 > -1e37f) ? __expf(s1 - m) : 0.f;
  red[t] = p0 + p1; __syncthreads();
  for (int s = 128; s; s >>= 1) { if (t < s) red[t] += red[t + s]; __syncthreads(); }
  float inv = 1.f / red[0];
  sc[(size_t)i * C + t] = p0 * inv;
  sc[(size_t)i * C + 256 + t] = p1 * inv;
}

__global__ __launch_bounds__(64) void k_hhat(const float* __restrict__ h,
                                             float* __restrict__ hhat,
                                             float* __restrict__ diagv) {
  int i = blockIdx.x, t = threadIdx.x;
  float a = h[(size_t)i * H + t], b = h[(size_t)i * H + 64 + t];
  float ss = wave_reduce_sum(a * a + b * b);
  float hn = sqrtf(ss);
  float den = hn * hn;
  float dg = (den == 0.f) ? 0.f : ss / den;
  float inv = (ss > 0.f) ? (1.f / hn) : 1.f;
  hhat[(size_t)i * H + t] = a * inv;
  hhat[(size_t)i * H + 64 + t] = b * inv;
  if (t == 0) diagv[i] = dg;
}

__global__ __launch_bounds__(64) void k_fin_hidden2(
    const float* __restrict__ h, const float* __restrict__ diagv,
    const float* __restrict__ colsum_m, float* __restrict__ hidden2,
    float* __restrict__ h2hat, float* __restrict__ valid2f) {
  int j = blockIdx.x, t = threadIdx.x;
  float add = (colsum_m[j] != 0.f) ? diagv[j] : 0.f;
  float a = hidden2[(size_t)j * H + t] + add * h[(size_t)j * H + t];
  float b = hidden2[(size_t)j * H + 64 + t] + add * h[(size_t)j * H + 64 + t];
  float s = a + b, ss = a * a + b * b;
#pragma unroll
  for (int m = 32; m; m >>= 1) { s += __shfl_xor(s, m); ss += __shfl_xor(ss, m); }
  bool valid = (s != 0.f);
  a = valid ? a : 0.f; b = valid ? b : 0.f;
  hidden2[(size_t)j * H + t] = a;
  hidden2[(size_t)j * H + 64 + t] = b;
  float inv = (valid && ss > 0.f) ? (1.f / sqrtf(ss)) : 1.f;
  h2hat[(size_t)j * H + t] = a * inv;
  h2hat[(size_t)j * H + 64 + t] = b * inv;
  if (t == 0) valid2f[j] = valid ? 1.f : 0.f;
}

__global__ __launch_bounds__(256) void k_rowstats(const float* __restrict__ S,
                                                  float* __restrict__ rowmax,
                                                  float* __restrict__ rowinv) {
  __shared__ float red[256];
  int i = blockIdx.x, t = threadIdx.x;
  float4 v[4];
  float m = -3e38f;
#pragma unroll
  for (int q = 0; q < 4; q++) {
    v[q] = *(const float4*)&S[(size_t)i * N + q * 1024 + t * 4];
    m = fmaxf(m, fmaxf(fmaxf(v[q].x, v[q].y), fmaxf(v[q].z, v[q].w)));
  }
  red[t] = m; __syncthreads();
  for (int s = 128; s; s >>= 1) { if (t < s) red[t] = fmaxf(red[t], red[t + s]); __syncthreads(); }
  m = red[0]; __syncthreads();
  float sum = 0.f;
#pragma unroll
  for (int q = 0; q < 4; q++)
    sum += __expf(v[q].x - m) + __expf(v[q].y - m) + __expf(v[q].z - m) + __expf(v[q].w - m);
  red[t] = sum; __syncthreads();
  for (int s = 128; s; s >>= 1) { if (t < s) red[t] += red[t + s]; __syncthreads(); }
  if (t == 0) { rowmax[i] = m; rowinv[i] = 1.f / red[0]; }
}

__global__ __launch_bounds__(64) void k_final(const float* __restrict__ ai,
                                              const float* __restrict__ Wout,
                                              const float* __restrict__ bout,
                                              float* __restrict__ out) {
  int i = blockIdx.x, t = threadIdx.x;
  float s = ai[(size_t)i * H + t] * Wout[t] + ai[(size_t)i * H + 64 + t] * Wout[64 + t];
  s = wave_reduce_sum(s);
  if (t == 0) out[i] = s + bout[0];
}

// ---------------- 128x128-tile NT GEMM, 8x8 micro: out = A[M,128] @ B[Nn,128]^T
// EPI 0: plain store; 1: masked store (-3e38 where validn==0); 2: top3 epilogue
template <int EPI>
__global__ __launch_bounds__(256, 4) void k_nt128(
    const float* __restrict__ A, const float* __restrict__ B,
    const float* __restrict__ validn, float* __restrict__ out,
    int* __restrict__ candi, int Nn) {
  __shared__ float As[32][132];
  __shared__ float Bs[32][132];
  int tid = threadIdx.x;
  int tx = tid & 15, ty = tid >> 4;
  int bm = blockIdx.y * 128, bn = blockIdx.x * 128;
  float acc[8][8];
#pragma unroll
  for (int r = 0; r < 8; r++)
#pragma unroll
    for (int c = 0; c < 8; c++) acc[r][c] = 0.f;
  for (int kt = 0; kt < 128; kt += 32) {
#pragma unroll
    for (int q = 0; q < 4; q++) {
      int f = q * 256 + tid;
      int row = f >> 3, kq = f & 7;
      float4 av = *(const float4*)&A[(size_t)(bm + row) * 128 + kt + kq * 4];
      As[kq * 4 + 0][row] = av.x; As[kq * 4 + 1][row] = av.y;
      As[kq * 4 + 2][row] = av.z; As[kq * 4 + 3][row] = av.w;
      float4 bv = *(const float4*)&B[(size_t)(bn + row) * 128 + kt + kq * 4];
      Bs[kq * 4 + 0][row] = bv.x; Bs[kq * 4 + 1][row] = bv.y;
      Bs[kq * 4 + 2][row] = bv.z; Bs[kq * 4 + 3][row] = bv.w;
    }
    __syncthreads();
#pragma unroll 8
    for (int kk = 0; kk < 32; kk++) {
      float4 a0 = *(float4*)&As[kk][ty * 8];
      float4 a1 = *(float4*)&As[kk][ty * 8 + 4];
      float4 b0 = *(float4*)&Bs[kk][tx * 8];
      float4 b1 = *(float4*)&Bs[kk][tx * 8 + 4];
      float am[8] = {a0.x, a0.y, a0.z, a0.w, a1.x, a1.y, a1.z, a1.w};
      float bb[8] = {b0.x, b0.y, b0.z, b0.w, b1.x, b1.y, b1.z, b1.w};
#pragma unroll
      for (int r = 0; r < 8; r++)
#pragma unroll
        for (int c = 0; c < 8; c++) acc[r][c] += am[r] * bb[c];
    }
    __syncthreads();
  }
  if (EPI == 0) {
#pragma unroll
    for (int r = 0; r < 8; r++) {
      size_t off = (size_t)(bm + ty * 8 + r) * Nn + bn + tx * 8;
      float4 v0 = {acc[r][0], acc[r][1], acc[r][2], acc[r][3]};
      float4 v1 = {acc[r][4], acc[r][5], acc[r][6], acc[r][7]};
      *(float4*)&out[off] = v0;
      *(float4*)&out[off + 4] = v1;
    }
  } else if (EPI == 1) {
    float4 m0 = *(const float4*)&validn[bn + tx * 8];
    float4 m1 = *(const float4*)&validn[bn + tx * 8 + 4];
    float vm[8] = {m0.x, m0.y, m0.z, m0.w, m1.x, m1.y, m1.z, m1.w};
#pragma unroll
    for (int r = 0; r < 8; r++) {
      size_t off = (size_t)(bm + ty * 8 + r) * Nn + bn + tx * 8;
      float v[8];
#pragma unroll
      for (int c = 0; c < 8; c++) v[c] = (vm[c] != 0.f) ? acc[r][c] : -3e38f;
      float4 v0 = {v[0], v[1], v[2], v[3]};
      float4 v1 = {v[4], v[5], v[6], v[7]};
      *(float4*)&out[off] = v0;
      *(float4*)&out[off + 4] = v1;
    }
  } else {
#pragma unroll
    for (int r = 0; r < 8; r++) {
      int i = bm + ty * 8 + r;
      float v0 = -3e38f, v1 = -3e38f, v2 = -3e38f;
      int j0 = 0, j1 = 0, j2 = 0;
#pragma unroll
      for (int c = 0; c < 8; c++) {
        int j = bn + tx * 8 + c;
        float v = (j == i) ? 0.f : acc[r][c];  // diagonal zeroed pre-top-k
        top3_ins(v, j, v0, j0, v1, j1, v2, j2);
      }
#pragma unroll
      for (int s = 1; s < 16; s <<= 1) {
        float w0 = __shfl_xor(v0, s), w1 = __shfl_xor(v1, s), w2 = __shfl_xor(v2, s);
        int q0 = __shfl_xor(j0, s), q1 = __shfl_xor(j1, s), q2 = __shfl_xor(j2, s);
        top3_ins(w0, q0, v0, j0, v1, j1, v2, j2);
        top3_ins(w1, q1, v0, j0, v1, j1, v2, j2);
        top3_ins(w2, q2, v0, j0, v1, j1, v2, j2);
      }
      if (tx == 0) {
        size_t base = (size_t)(blockIdx.x * 3) * N + i;
        out[base] = v0; out[base + N] = v1; out[base + 2 * N] = v2;
        candi[base] = j0; candi[base + N] = j1; candi[base + 2 * N] = j2;
      }
    }
  }
}

// ---------------- 64x128-tile split-K KN GEMM, 128 threads, 8x8 micro ---------
// partial[z] = A'[bm:bm+64, k0:k0+KC] @ B[k0:k0+KC, 0:128]
// EXP=1: a' = exp(a - rowmax[m]) * rowinv[m]
template <int EXP>
__global__ __launch_bounds__(128, 3) void k_kn(
    const float* __restrict__ A, int lda,
    const float* __restrict__ rowmax, const float* __restrict__ rowinv,
    const float* __restrict__ B, float* __restrict__ partial, int KC) {
  __shared__ float As[32][68];
  __shared__ float Bs[32][132];
  int tid = threadIdx.x;
  int tx = tid & 15, ty = tid >> 4;
  int bm = blockIdx.y * 64;
  int k0 = blockIdx.z * KC;
  float rm[4], ri[4];
  if (EXP) {
#pragma unroll
    for (int q = 0; q < 4; q++) {
      int row = q * 16 + (tid >> 3);
      rm[q] = rowmax[bm + row]; ri[q] = rowinv[bm + row];
    }
  }
  float acc[8][8];
#pragma unroll
  for (int r = 0; r < 8; r++)
#pragma unroll
    for (int c = 0; c < 8; c++) acc[r][c] = 0.f;
  for (int kt = 0; kt < KC; kt += 32) {
#pragma unroll
    for (int q = 0; q < 4; q++) {
      int f = q * 128 + tid;
      int row = f >> 3, kq = f & 7;
      float4 av = *(const float4*)&A[(size_t)(bm + row) * lda + k0 + kt + kq * 4];
      if (EXP) {
        av.x = __expf(av.x - rm[q]) * ri[q];
        av.y = __expf(av.y - rm[q]) * ri[q];
        av.z = __expf(av.z - rm[q]) * ri[q];
        av.w = __expf(av.w - rm[q]) * ri[q];
      }
      As[kq * 4 + 0][row] = av.x; As[kq * 4 + 1][row] = av.y;
      As[kq * 4 + 2][row] = av.z; As[kq * 4 + 3][row] = av.w;
    }
#pragma unroll
    for (int q = 0; q < 8; q++) {
      int f = q * 128 + tid;
      int kr = f >> 5, nq = f & 31;
      float4 bv = *(const float4*)&B[(size_t)(k0 + kt + kr) * 128 + nq * 4];
      *(float4*)&Bs[kr][nq * 4] = bv;
    }
    __syncthreads();
#pragma unroll 8
    for (int kk = 0; kk < 32; kk++) {
      float4 a0 = *(float4*)&As[kk][ty * 8];
      float4 a1 = *(float4*)&As[kk][ty * 8 + 4];
      float4 b0 = *(float4*)&Bs[kk][tx * 8];
      float4 b1 = *(float4*)&Bs[kk][tx * 8 + 4];
      float am[8] = {a0.x, a0.y, a0.z, a0.w, a1.x, a1.y, a1.z, a1.w};
      float bb[8] = {b0.x, b0.y, b0.z, b0.w, b1.x, b1.y, b1.z, b1.w};
#pragma unroll
      for (int r = 0; r < 8; r++)
#pragma unroll
        for (int c = 0; c < 8; c++) acc[r][c] += am[r] * bb[c];
    }
    __syncthreads();
  }
  float* pp = partial + (size_t)blockIdx.z * N * 128;
#pragma unroll
  for (int r = 0; r < 8; r++) {
    size_t off = (size_t)(bm + ty * 8 + r) * 128 + tx * 8;
    float4 v0 = {acc[r][0], acc[r][1], acc[r][2], acc[r][3]};
    float4 v1 = {acc[r][4], acc[r][5], acc[r][6], acc[r][7]};
    *(float4*)&pp[off] = v0;
    *(float4*)&pp[off + 4] = v1;
  }
}

// ---------------- split-K GEMM with generated A^T (ps staging GEMMs) ----------
template <int AMODE>
__global__ __launch_bounds__(256) void k_gemm_genA(
    const float* __restrict__ P, const float* __restrict__ mv,
    const float* __restrict__ col1, const float* __restrict__ col2,
    const float* __restrict__ B, float* __restrict__ partial, int KC) {
  __shared__ float Ps[32][68];
  __shared__ float Bs[32][68];
  int tid = threadIdx.x;
  int tx = tid & 15, ty = tid >> 4;
  int bm = blockIdx.y * 64, bn = blockIdx.x * 64;
  int k0 = blockIdx.z * KC;
  float acc[4][4];
#pragma unroll
  for (int r = 0; r < 4; r++)
#pragma unroll
    for (int c = 0; c < 4; c++) acc[r][c] = 0.f;
  for (int kt = 0; kt < KC; kt += 32) {
#pragma unroll
    for (int q = 0; q < 2; q++) {
      int f = q * 256 + tid;
      int kr = f >> 4, nq = f & 15;
      int k = k0 + kt + kr;
      float4 pv = *(const float4*)&P[(size_t)k * C + bm + nq * 4];
      float4 av;
      if (AMODE == 1) {
        float m = mv[k];
        float4 cs = *(const float4*)&col1[bm + nq * 4];
        av.x = pv.x * m / (cs.x * pv.x + 1.f);
        av.y = pv.y * m / (cs.y * pv.y + 1.f);
        av.z = pv.z * m / (cs.z * pv.z + 1.f);
        av.w = pv.w * m / (cs.w * pv.w + 1.f);
      } else {
        float4 cm_ = *(const float4*)&col1[bm + nq * 4];
        float4 cd = *(const float4*)&col2[bm + nq * 4];
        av.x = __expf(pv.x - cm_.x) / cd.x;
        av.y = __expf(pv.y - cm_.y) / cd.y;
        av.z = __expf(pv.z - cm_.z) / cd.z;
        av.w = __expf(pv.w - cm_.w) / cd.w;
      }
      *(float4*)&Ps[kr][nq * 4] = av;
      float4 bv = *(const float4*)&B[(size_t)k * 128 + bn + nq * 4];
      *(float4*)&Bs[kr][nq * 4] = bv;
    }
    __syncthreads();
#pragma unroll
    for (int kk = 0; kk < 32; kk++) {
      float4 fa = *(float4*)&Ps[kk][ty * 4];
      float4 fb = *(float4*)&Bs[kk][tx * 4];
      float am[4] = {fa.x, fa.y, fa.z, fa.w};
      float bb[4] = {fb.x, fb.y, fb.z, fb.w};
#pragma unroll
      for (int r = 0; r < 4; r++)
#pragma unroll
        for (int c = 0; c < 4; c++) acc[r][c] += am[r] * bb[c];
    }
    __syncthreads();
  }
  float* pp = partial + (size_t)blockIdx.z * C * 128;
#pragma unroll
  for (int r = 0; r < 4; r++) {
    float4 v = {acc[r][0], acc[r][1], acc[r][2], acc[r][3]};
    *(float4*)&pp[(size_t)(bm + ty * 4 + r) * 128 + bn + tx * 4] = v;
  }
}

// reduce split-K partials; optional per-row (128-wide) valid scale
__global__ __launch_bounds__(256) void k_reduce(
    const float* __restrict__ partial, float* __restrict__ out, int cnt,
    size_t slot, size_t size4, const float* __restrict__ validm) {
  size_t idx = (size_t)blockIdx.x * 256 + threadIdx.x;
  if (idx >= size4) return;
  float4 s = {0, 0, 0, 0};
  for (int c = 0; c < cnt; c++) {
    float4 v = *(const float4*)&partial[c * slot + idx * 4];
    s.x += v.x; s.y += v.y; s.z += v.z; s.w += v.w;
  }
  if (validm) {
    float sc = validm[idx >> 5];
    s.x *= sc; s.y *= sc; s.z *= sc; s.w *= sc;
  }
  *(float4*)&out[idx * 4] = s;
}

// ---------------- linear: out[4096,128] = epi(A @ W^T + b) ----------------
template <int EPI>
__global__ __launch_bounds__(256) void k_gemm_lin(
    const float* __restrict__ A, const float* __restrict__ Wt,
    const float* __restrict__ bias, const float* __restrict__ aux,
    float* __restrict__ out) {
  __shared__ float As[32][68];
  __shared__ float Ws[32][68];
  int tid = threadIdx.x;
  int tx = tid & 15, ty = tid >> 4;
  int bm = blockIdx.y * 64, bn = blockIdx.x * 64;
  float acc[4][4];
#pragma unroll
  for (int r = 0; r < 4; r++)
#pragma unroll
    for (int c = 0; c < 4; c++) acc[r][c] = 0.f;
  for (int kt = 0; kt < 128; kt += 32) {
#pragma unroll
    for (int q = 0; q < 2; q++) {
      int f = q * 256 + tid;
      int row = f >> 3, kq = f & 7;
      float4 av = *(const float4*)&A[(size_t)(bm + row) * 128 + kt + kq * 4];
      As[kq * 4 + 0][row] = av.x; As[kq * 4 + 1][row] = av.y;
      As[kq * 4 + 2][row] = av.z; As[kq * 4 + 3][row] = av.w;
      float4 wv = *(const float4*)&Wt[(size_t)(bn + row) * 128 + kt + kq * 4];
      Ws[kq * 4 + 0][row] = wv.x; Ws[kq * 4 + 1][row] = wv.y;
      Ws[kq * 4 + 2][row] = wv.z; Ws[kq * 4 + 3][row] = wv.w;
    }
    __syncthreads();
#pragma unroll
    for (int kk = 0; kk < 32; kk++) {
      float4 fa = *(float4*)&As[kk][ty * 4];
      float4 fb = *(float4*)&Ws[kk][tx * 4];
      float am[4] = {fa.x, fa.y, fa.z, fa.w};
      float bb[4] = {fb.x, fb.y, fb.z, fb.w};
#pragma unroll
      for (int r = 0; r < 4; r++)
#pragma unroll
        for (int c = 0; c < 4; c++) acc[r][c] += am[r] * bb[c];
    }
    __syncthreads();
  }
  float4 bb = *(const float4*)&bias[bn + tx * 4];
  float bv[4] = {bb.x, bb.y, bb.z, bb.w};
#pragma unroll
  for (int r = 0; r < 4; r++) {
    size_t off = (size_t)(bm + ty * 4 + r) * 128 + bn + tx * 4;
    float v[4];
#pragma unroll
    for (int c = 0; c < 4; c++) v[c] = acc[r][c] + bv[c];
    if (EPI == 0) {
      float4 s = {v[0], v[1], v[2], v[3]};
      *(float4*)&out[off] = s;
    } else if (EPI == 1) {
      float4 s = {lrelu(v[0]), lrelu(v[1]), lrelu(v[2]), lrelu(v[3])};
      *(float4*)&out[off] = s;
    } else if (EPI == 2) {
      float4 p = *(float4*)&out[off];
      p.x += lrelu(v[0]); p.y += lrelu(v[1]); p.z += lrelu(v[2]); p.w += lrelu(v[3]);
      *(float4*)&out[off] = p;
    } else {
      float4 a = *(const float4*)&aux[off];
      float4 s = {a.x - v[0], a.y - v[1], a.z - v[2], a.w - v[3]};
      *(float4*)&out[off] = s;
    }
  }
}

// merge 32 chunk-candidate sets per row (coalesced chunk-major reads)
__global__ __launch_bounds__(256) void k_merge(const float* __restrict__ candv,
                                               const int* __restrict__ candi,
                                               float* __restrict__ mtv,
                                               int* __restrict__ mtj) {
  int i = blockIdx.x * 256 + threadIdx.x;
  float v0 = -3e38f, v1 = -3e38f, v2 = -3e38f;
  int j0 = 0, j1 = 0, j2 = 0;
  for (int c = 0; c < 96; c++) {
    float v = candv[(size_t)c * N + i];
    int j = candi[(size_t)c * N + i];
    top3_ins(v, j, v0, j0, v1, j1, v2, j2);
  }
  mtv[i * 3 + 0] = v0; mtv[i * 3 + 1] = v1; mtv[i * 3 + 2] = v2;
  mtj[i * 3 + 0] = j0; mtj[i * 3 + 1] = j1; mtj[i * 3 + 2] = j2;
}

// wave-per-row scatter: hidden2[j] += v * h[i], colsum_m[j] += v
__global__ __launch_bounds__(256) void k_scatter(
    const float* __restrict__ mtv, const int* __restrict__ mtj,
    const float* __restrict__ h, float* __restrict__ hidden2,
    float* __restrict__ colsum_m) {
  int i = blockIdx.x * 4 + (threadIdx.x >> 6);
  int lane = threadIdx.x & 63;
  float h0 = h[(size_t)i * H + lane], h1 = h[(size_t)i * H + 64 + lane];
#pragma unroll
  for (int s = 0; s < 3; s++) {
    float v = mtv[i * 3 + s];
    int j = mtj[i * 3 + s];
    atomicAdd(&hidden2[(size_t)j * H + lane], v * h0);
    atomicAdd(&hidden2[(size_t)j * H + 64 + lane], v * h1);
    if (lane == s) atomicAdd(&colsum_m[j], v);
  }
}

// ---------------- launch ----------------

extern "C" void kernel_launch(void* const* d_in, const int* in_sizes, int n_in,
                              void* d_out, int out_size, void* d_ws, size_t ws_size,
                              hipStream_t stream) {
  (void)in_sizes; (void)n_in; (void)out_size;
  const float* x   = (const float*)d_in[0];
  const float* cm  = (const float*)d_in[1];
  const float* mv  = (const float*)d_in[2];
  const float* W_ps = (const float*)d_in[3],  *b_ps = (const float*)d_in[4];
  const float* W_psf = (const float*)d_in[5], *b_psf = (const float*)d_in[6];
  const float* W_psb = (const float*)d_in[7], *b_psb = (const float*)d_in[8];
  const float* W_hs = (const float*)d_in[9],  *b_hs = (const float*)d_in[10];
  const float* W_hsf = (const float*)d_in[11], *b_hsf = (const float*)d_in[12];
  const float* W_hsb = (const float*)d_in[13], *b_hsb = (const float*)d_in[14];
  const float* W_in = (const float*)d_in[15], *b_in = (const float*)d_in[16];
  const float* W_out = (const float*)d_in[17], *b_out = (const float*)d_in[18];
  float* out = (float*)d_out;

  float* W = (float*)d_ws;
  size_t o = 0;
  auto alloc = [&](size_t n) { float* p = W + o; o += n; return p; };
  float* colsum_c = alloc(C);
  float* colmax   = alloc(C);
  float* colsumexp= alloc(C);
  float* valid1   = alloc(C);
  float* hnorm_ps = alloc(C);
  float* xnorm    = alloc(N);
  float* diagv    = alloc(N);
  float* colsum_m = alloc(N);
  float* valid2f  = alloc(N);
  float* rowmax   = alloc(N);
  float* rowinv   = alloc(N);
  float* mtv      = alloc(3 * N);
  int*   mtj      = (int*)alloc(3 * N);
  float* hidden1  = alloc((size_t)C * H);
  float* hidden_ps= alloc((size_t)C * H);
  float* scores   = alloc((size_t)N * C);   // scores1 / cs / candv (reused)
  int*   candi    = (int*)alloc((size_t)N * 32 * 3);
  float* ps_pre   = alloc((size_t)N * H);   // later hs_pre
  float* p_shared = alloc((size_t)N * H);   // later h_shared
  float* all_info = alloc((size_t)N * H);
  float* hbuf     = alloc((size_t)N * H);   // h; later indiv (in-place)
  float* hhat     = alloc((size_t)N * H);
  float* hidden2  = alloc((size_t)N * H);
  float* h2hat    = alloc((size_t)N * H);
  float* Sbuf     = alloc((size_t)N * N);   // 64 MB score matrix
  float* partial  = W + o;                  // split-K partials: all remaining ws
  size_t rem = ws_size / 4 - o;
  int Z = (rem >= (size_t)16 * N * H) ? 16 : 8;  // hs split-K factor
  int KC = 4096 / Z;
  float* candv    = scores;  // alias: cs free once hs branch runs

  hipMemsetAsync(colsum_c, 0, C * sizeof(float), stream);
  hipMemsetAsync(colsum_m, 0, N * sizeof(float), stream);
  hipMemsetAsync(hidden2, 0, (size_t)N * H * sizeof(float), stream);

  dim3 blk(256);
  // --- ps branch ---
  k_colsum_s2c<<<dim3(C / 64, 16), dim3(64), 0, stream>>>(cm, mv, colsum_c);
  k_gemm_genA<1><<<dim3(2, C / 64, 16), blk, 0, stream>>>(
      cm, mv, colsum_c, nullptr, x, partial, N / 16);
  k_reduce<<<dim3(C * H / 4 / 256), blk, 0, stream>>>(
      partial, hidden1, 16, (size_t)C * H, (size_t)C * H / 4, nullptr);
  k_valid1<<<dim3(C), dim3(64), 0, stream>>>(hidden1, valid1);
  k_nt128<0><<<dim3(C / 128, N / 128), blk, 0, stream>>>(
      x, hidden1, nullptr, scores, nullptr, C);
  k_colstats<<<dim3(C), blk, 0, stream>>>(scores, colmax, colsumexp);
  k_gemm_genA<2><<<dim3(2, C / 64, 16), blk, 0, stream>>>(
      scores, nullptr, colmax, colsumexp, x, partial, N / 16);
  k_reduce<<<dim3(C * H / 4 / 256), blk, 0, stream>>>(
      partial, hidden_ps, 16, (size_t)C * H, (size_t)C * H / 4, valid1);
  k_rownorm128<<<dim3(N), dim3(64), 0, stream>>>(x, xnorm);
  k_rownorm128<<<dim3(C), dim3(64), 0, stream>>>(hidden_ps, hnorm_ps);
  k_nt128<0><<<dim3(C / 128, N / 128), blk, 0, stream>>>(
      x, hidden_ps, nullptr, scores, nullptr, C);
  k_cs_softmax<<<dim3(N), blk, 0, stream>>>(scores, xnorm, hnorm_ps, valid1);
  k_kn<0><<<dim3(1, N / 64, 4), dim3(128), 0, stream>>>(
      scores, C, nullptr, nullptr, hidden_ps, partial, C / 4);
  k_reduce<<<dim3(N * H / 4 / 256), blk, 0, stream>>>(
      partial, ps_pre, 4, (size_t)N * H, (size_t)N * H / 4, nullptr);
  k_gemm_lin<0><<<dim3(2, N / 64), blk, 0, stream>>>(
      ps_pre, W_ps, b_ps, nullptr, p_shared);
  k_gemm_lin<3><<<dim3(2, N / 64), blk, 0, stream>>>(
      p_shared, W_psb, b_psb, x, hbuf);                      // h = x - p_back
  k_gemm_lin<1><<<dim3(2, N / 64), blk, 0, stream>>>(
      p_shared, W_psf, b_psf, nullptr, all_info);            // out_ps
  // --- hs branch ---
  k_hhat<<<dim3(N), dim3(64), 0, stream>>>(hbuf, hhat, diagv);
  k_nt128<2><<<dim3(N / 128, N / 128), blk, 0, stream>>>(
      hhat, hhat, nullptr, candv, candi, N);
  k_merge<<<dim3(N / 256), blk, 0, stream>>>(candv, candi, mtv, mtj);
  k_scatter<<<dim3(N / 4), blk, 0, stream>>>(mtv, mtj, hbuf, hidden2, colsum_m);
  k_fin_hidden2<<<dim3(N), dim3(64), 0, stream>>>(hbuf, diagv, colsum_m, hidden2,
                                                  h2hat, valid2f);
  k_nt128<1><<<dim3(N / 128, N / 128), blk, 0, stream>>>(
      hhat, h2hat, valid2f, Sbuf, nullptr, N);
  k_rowstats<<<dim3(N), blk, 0, stream>>>(Sbuf, rowmax, rowinv);
  k_kn<1><<<dim3(1, N / 64, Z), dim3(128), 0, stream>>>(
      Sbuf, N, rowmax, rowinv, hidden2, partial, KC);
  k_reduce<<<dim3(N * H / 4 / 256), blk, 0, stream>>>(
      partial, ps_pre, Z, (size_t)N * H, (size_t)N * H / 4, nullptr);  // hs_pre
  k_gemm_lin<0><<<dim3(2, N / 64), blk, 0, stream>>>(
      ps_pre, W_hs, b_hs, nullptr, p_shared);                // h_shared
  k_gemm_lin<2><<<dim3(2, N / 64), blk, 0, stream>>>(
      p_shared, W_hsf, b_hsf, nullptr, all_info);            // += out_hs
  k_gemm_lin<3><<<dim3(2, N / 64), blk, 0, stream>>>(
      p_shared, W_hsb, b_hsb, hbuf, hbuf);                   // indiv = h - h_back (in-place)
  k_gemm_lin<2><<<dim3(2, N / 64), blk, 0, stream>>>(
      hbuf, W_in, b_in, nullptr, all_info);                  // += out_indi
  k_final<<<dim3(N), dim3(64), 0, stream>>>(all_info, W_out, b_out, out);
}

// Round 5
// 501.106 us; speedup vs baseline: 5.0260x; 1.5531x over previous
//
#include <hip/hip_runtime.h>
#include <math.h>

#define N 4096
#define C 512
#define H 128

typedef __attribute__((ext_vector_type(8))) short bf16x8;
typedef __attribute__((ext_vector_type(4))) float f32x4;

// ---------------- helpers ----------------

__device__ inline float wave_reduce_sum(float v) {
#pragma unroll
  for (int m = 32; m; m >>= 1) v += __shfl_xor(v, m);
  return v;
}

__device__ inline float lrelu(float v) { return v > 0.f ? v : 0.01f * v; }

// comparator: (v desc, j asc) — matches jax top_k tie-break
__device__ inline bool better(float v, int j, float w, int k) {
  return (v > w) || (v == w && j < k);
}

__device__ inline void top3_ins(float v, int j, float& v0, int& j0,
                                float& v1, int& j1, float& v2, int& j2) {
  if (better(v, j, v0, j0)) { v2 = v1; j2 = j1; v1 = v0; j1 = j0; v0 = v; j0 = j; }
  else if (better(v, j, v1, j1)) { v2 = v1; j2 = j1; v1 = v; j1 = j; }
  else if (better(v, j, v2, j2)) { v2 = v; j2 = j; }
}

// sorted-5 insert (registers only; fully branch-unrolled)
__device__ inline void ins5(float s, int j, float v[5], int jx[5]) {
  if (!better(s, j, v[4], jx[4])) return;
  if (better(s, j, v[0], jx[0])) {
    v[4]=v[3]; jx[4]=jx[3]; v[3]=v[2]; jx[3]=jx[2]; v[2]=v[1]; jx[2]=jx[1];
    v[1]=v[0]; jx[1]=jx[0]; v[0]=s; jx[0]=j;
  } else if (better(s, j, v[1], jx[1])) {
    v[4]=v[3]; jx[4]=jx[3]; v[3]=v[2]; jx[3]=jx[2]; v[2]=v[1]; jx[2]=jx[1];
    v[1]=s; jx[1]=j;
  } else if (better(s, j, v[2], jx[2])) {
    v[4]=v[3]; jx[4]=jx[3]; v[3]=v[2]; jx[3]=jx[2]; v[2]=s; jx[2]=j;
  } else if (better(s, j, v[3], jx[3])) {
    v[4]=v[3]; jx[4]=jx[3]; v[3]=s; jx[3]=j;
  } else {
    v[4]=s; jx[4]=j;
  }
}

__device__ inline unsigned short f2bf(float f) {
  unsigned u = __float_as_uint(f);
  unsigned r = u + 0x7fffu + ((u >> 16) & 1u);
  return (unsigned short)(r >> 16);
}
__device__ inline float bf2f(unsigned short h) {
  return __uint_as_float(((unsigned)h) << 16);
}

// ---------------- split fp32 -> bf16 hi/lo ----------------
__global__ __launch_bounds__(256) void k_split(const float* __restrict__ in,
                                               unsigned short* __restrict__ hi,
                                               unsigned short* __restrict__ lo) {
  int idx = (blockIdx.x * 256 + threadIdx.x) * 4;
  float4 v = *(const float4*)&in[idx];
  float vv[4] = {v.x, v.y, v.z, v.w};
  unsigned short h[4], l[4];
#pragma unroll
  for (int c = 0; c < 4; c++) {
    h[c] = f2bf(vv[c]);
    l[c] = f2bf(vv[c] - bf2f(h[c]));
  }
  uint2 ph = {(unsigned)h[0] | ((unsigned)h[1] << 16),
              (unsigned)h[2] | ((unsigned)h[3] << 16)};
  uint2 pl = {(unsigned)l[0] | ((unsigned)l[1] << 16),
              (unsigned)l[2] | ((unsigned)l[3] << 16)};
  *(uint2*)&hi[idx] = ph;
  *(uint2*)&lo[idx] = pl;
}

// ---------------- small kernels ----------------

__global__ __launch_bounds__(64) void k_colsum_s2c(
    const float* __restrict__ cm, const float* __restrict__ mv,
    float* __restrict__ colsum_c) {
  int c = blockIdx.x * 64 + threadIdx.x;
  int i0 = blockIdx.y * 256;
  float acc = 0.f;
  for (int i = i0; i < i0 + 256; i++) acc += cm[(size_t)i * C + c] * mv[i];
  atomicAdd(&colsum_c[c], acc);
}

__global__ __launch_bounds__(64) void k_valid1(const float* __restrict__ hid,
                                               float* __restrict__ valid1) {
  int c = blockIdx.x, t = threadIdx.x;
  float s = hid[(size_t)c * H + t] + hid[(size_t)c * H + 64 + t];
  s = wave_reduce_sum(s);
  if (t == 0) valid1[c] = (s != 0.f) ? 1.f : 0.f;
}

__global__ __launch_bounds__(64) void k_rownorm128(const float* __restrict__ A,
                                                   float* __restrict__ nrm) {
  int r = blockIdx.x, t = threadIdx.x;
  float a = A[(size_t)r * H + t], b = A[(size_t)r * H + 64 + t];
  float ss = wave_reduce_sum(a * a + b * b);
  if (t == 0) nrm[r] = sqrtf(ss);
}

__global__ __launch_bounds__(256) void k_colstats(const float* __restrict__ sc,
                                                  float* __restrict__ colmax,
                                                  float* __restrict__ colsum) {
  __shared__ float red[256];
  int c = blockIdx.x, t = threadIdx.x;
  float v[16];
  float m = -3e38f;
#pragma unroll
  for (int q = 0; q < 16; q++) {
    v[q] = sc[(size_t)(q * 256 + t) * C + c];
    m = fmaxf(m, v[q]);
  }
  red[t] = m; __syncthreads();
  for (int s = 128; s; s >>= 1) { if (t < s) red[t] = fmaxf(red[t], red[t + s]); __syncthreads(); }
  m = red[0]; __syncthreads();
  float sum = 0.f;
#pragma unroll
  for (int q = 0; q < 16; q++) sum += __expf(v[q] - m);
  red[t] = sum; __syncthreads();
  for (int s = 128; s; s >>= 1) { if (t < s) red[t] += red[t + s]; __syncthreads(); }
  if (t == 0) { colmax[c] = m; colsum[c] = red[0]; }
}

__global__ __launch_bounds__(256) void k_cs_softmax(
    float* __restrict__ sc, const float* __restrict__ xnorm,
    const float* __restrict__ hnorm, const float* __restrict__ valid1) {
  __shared__ float red[256];
  int i = blockIdx.x, t = threadIdx.x;
  float xn = xnorm[i];
  float r0 = sc[(size_t)i * C + t], r1 = sc[(size_t)i * C + 256 + t];
  float d0 = xn * hnorm[t], d1 = xn * hnorm[256 + t];
  float c0 = r0 / (d0 == 0.f ? 1.f : d0);
  float c1 = r1 / (d1 == 0.f ? 1.f : d1);
  float s0 = (valid1[t] != 0.f) ? c0 : -3e38f;
  float s1 = (valid1[256 + t] != 0.f) ? c1 : -3e38f;
  red[t] = fmaxf(s0, s1); __syncthreads();
  for (int s = 128; s; s >>= 1) { if (t < s) red[t] = fmaxf(red[t], red[t + s]); __syncthreads(); }
  float m = red[0]; __syncthreads();
  float p0 = (s0 > -1e37f) ? __expf(s0 - m) : 0.f;
  float p1 = (s1 > -1e37f) ? __expf(s1 - m) : 0.f;
  red[t] = p0 + p1; __syncthreads();
  for (int s = 128; s; s >>= 1) { if (t < s) red[t] += red[t + s]; __syncthreads(); }
  float inv = 1.f / red[0];
  sc[(size_t)i * C + t] = p0 * inv;
  sc[(size_t)i * C + 256 + t] = p1 * inv;
}

__global__ __launch_bounds__(64) void k_hhat(const float* __restrict__ h,
                                             float* __restrict__ hhat,
                                             float* __restrict__ diagv) {
  int i = blockIdx.x, t = threadIdx.x;
  float a = h[(size_t)i * H + t], b = h[(size_t)i * H + 64 + t];
  float ss = wave_reduce_sum(a * a + b * b);
  float hn = sqrtf(ss);
  float den = hn * hn;
  float dg = (den == 0.f) ? 0.f : ss / den;
  float inv = (ss > 0.f) ? (1.f / hn) : 1.f;
  hhat[(size_t)i * H + t] = a * inv;
  hhat[(size_t)i * H + 64 + t] = b * inv;
  if (t == 0) diagv[i] = dg;
}

__global__ __launch_bounds__(64) void k_fin_hidden2(
    const float* __restrict__ h, const float* __restrict__ diagv,
    const float* __restrict__ colsum_m, float* __restrict__ hidden2,
    float* __restrict__ h2hat, float* __restrict__ valid2f) {
  int j = blockIdx.x, t = threadIdx.x;
  float add = (colsum_m[j] != 0.f) ? diagv[j] : 0.f;
  float a = hidden2[(size_t)j * H + t] + add * h[(size_t)j * H + t];
  float b = hidden2[(size_t)j * H + 64 + t] + add * h[(size_t)j * H + 64 + t];
  float s = a + b, ss = a * a + b * b;
#pragma unroll
  for (int m = 32; m; m >>= 1) { s += __shfl_xor(s, m); ss += __shfl_xor(ss, m); }
  bool valid = (s != 0.f);
  a = valid ? a : 0.f; b = valid ? b : 0.f;
  hidden2[(size_t)j * H + t] = a;
  hidden2[(size_t)j * H + 64 + t] = b;
  float inv = (valid && ss > 0.f) ? (1.f / sqrtf(ss)) : 1.f;
  h2hat[(size_t)j * H + t] = a * inv;
  h2hat[(size_t)j * H + 64 + t] = b * inv;
  if (t == 0) valid2f[j] = valid ? 1.f : 0.f;
}

__global__ __launch_bounds__(256) void k_rowstats(const float* __restrict__ S,
                                                  float* __restrict__ rowmax,
                                                  float* __restrict__ rowinv) {
  __shared__ float red[256];
  int i = blockIdx.x, t = threadIdx.x;
  float4 v[4];
  float m = -3e38f;
#pragma unroll
  for (int q = 0; q < 4; q++) {
    v[q] = *(const float4*)&S[(size_t)i * N + q * 1024 + t * 4];
    m = fmaxf(m, fmaxf(fmaxf(v[q].x, v[q].y), fmaxf(v[q].z, v[q].w)));
  }
  red[t] = m; __syncthreads();
  for (int s = 128; s; s >>= 1) { if (t < s) red[t] = fmaxf(red[t], red[t + s]); __syncthreads(); }
  m = red[0]; __syncthreads();
  float sum = 0.f;
#pragma unroll
  for (int q = 0; q < 4; q++)
    sum += __expf(v[q].x - m) + __expf(v[q].y - m) + __expf(v[q].z - m) + __expf(v[q].w - m);
  red[t] = sum; __syncthreads();
  for (int s = 128; s; s >>= 1) { if (t < s) red[t] += red[t + s]; __syncthreads(); }
  if (t == 0) { rowmax[i] = m; rowinv[i] = 1.f / red[0]; }
}

__global__ __launch_bounds__(64) void k_final(const float* __restrict__ ai,
                                              const float* __restrict__ Wout,
                                              const float* __restrict__ bout,
                                              float* __restrict__ out) {
  int i = blockIdx.x, t = threadIdx.x;
  float s = ai[(size_t)i * H + t] * Wout[t] + ai[(size_t)i * H + 64 + t] * Wout[64 + t];
  s = wave_reduce_sum(s);
  if (t == 0) out[i] = s + bout[0];
}

// ---------------- bf16x3 MFMA NT GEMM: out = A[M,128] @ B[Nn,128]^T ----------
// 128x128 tile, 4 waves, each wave 64x64 (4x4 tiles of 16x16x32 MFMA).
// EPI 0: store; 1: masked store (-3e38 where validn==0); 2: diag-zeroed store
template <int EPI>
__global__ __launch_bounds__(256) void k_mfma_nt(
    const unsigned short* __restrict__ Ahi, const unsigned short* __restrict__ Alo,
    const unsigned short* __restrict__ Bhi, const unsigned short* __restrict__ Blo,
    const float* __restrict__ validn, float* __restrict__ out, int Nn) {
  __shared__ __align__(16) unsigned short sAh[128 * 32];
  __shared__ __align__(16) unsigned short sAl[128 * 32];
  __shared__ __align__(16) unsigned short sBh[128 * 32];
  __shared__ __align__(16) unsigned short sBl[128 * 32];
  int tid = threadIdx.x;
  int bm = blockIdx.y * 128, bn = blockIdx.x * 128;
  int lane = tid & 63, w = tid >> 6;
  int wm = (w & 1) * 64, wn = (w >> 1) * 64;
  int l15 = lane & 15, quad = lane >> 4;
  f32x4 zero = {0.f, 0.f, 0.f, 0.f};
  f32x4 acc[4][4];
#pragma unroll
  for (int mt = 0; mt < 4; mt++)
#pragma unroll
    for (int nt = 0; nt < 4; nt++) acc[mt][nt] = zero;

  for (int kt = 0; kt < 128; kt += 32) {
#pragma unroll
    for (int q = 0; q < 2; q++) {
      int f = tid * 2 + q;           // 512 16B-chunks
      int row = f >> 2, ch = f & 3;  // 128 rows x 4 chunks
      size_t ga = (size_t)(bm + row) * 128 + kt + ch * 8;
      size_t gb = (size_t)(bn + row) * 128 + kt + ch * 8;
      int ls = row * 32 + ch * 8;
      *(uint4*)&sAh[ls] = *(const uint4*)&Ahi[ga];
      *(uint4*)&sAl[ls] = *(const uint4*)&Alo[ga];
      *(uint4*)&sBh[ls] = *(const uint4*)&Bhi[gb];
      *(uint4*)&sBl[ls] = *(const uint4*)&Blo[gb];
    }
    __syncthreads();
    bf16x8 ah[4], al[4], bh[4], bl[4];
#pragma unroll
    for (int t = 0; t < 4; t++) {
      int ar = (wm + t * 16 + l15) * 32 + quad * 8;
      ah[t] = *(const bf16x8*)&sAh[ar];
      al[t] = *(const bf16x8*)&sAl[ar];
      int br = (wn + t * 16 + l15) * 32 + quad * 8;
      bh[t] = *(const bf16x8*)&sBh[br];
      bl[t] = *(const bf16x8*)&sBl[br];
    }
#pragma unroll
    for (int mt = 0; mt < 4; mt++)
#pragma unroll
      for (int nt = 0; nt < 4; nt++) {
        acc[mt][nt] = __builtin_amdgcn_mfma_f32_16x16x32_bf16(ah[mt], bh[nt], acc[mt][nt], 0, 0, 0);
        acc[mt][nt] = __builtin_amdgcn_mfma_f32_16x16x32_bf16(ah[mt], bl[nt], acc[mt][nt], 0, 0, 0);
        acc[mt][nt] = __builtin_amdgcn_mfma_f32_16x16x32_bf16(al[mt], bh[nt], acc[mt][nt], 0, 0, 0);
      }
    __syncthreads();
  }
  float vm[4];
  if (EPI == 1) {
#pragma unroll
    for (int nt = 0; nt < 4; nt++) vm[nt] = validn[bn + wn + nt * 16 + l15];
  }
#pragma unroll
  for (int mt = 0; mt < 4; mt++) {
#pragma unroll
    for (int nt = 0; nt < 4; nt++) {
      int col = bn + wn + nt * 16 + l15;
#pragma unroll
      for (int rg = 0; rg < 4; rg++) {
        int row = bm + wm + mt * 16 + quad * 4 + rg;
        float v = acc[mt][nt][rg];
        if (EPI == 1) v = (vm[nt] != 0.f) ? v : -3e38f;
        if (EPI == 2 && row == col) v = 0.f;
        out[(size_t)row * Nn + col] = v;
      }
    }
  }
}

// ---------------- row top-k: approx top-5 from S, exact fp32 rescore ----------
__global__ __launch_bounds__(256) void k_rowtop(
    const float* __restrict__ S, const float* __restrict__ hhat,
    float* __restrict__ mtv, int* __restrict__ mtj) {
  int i = blockIdx.x * 4 + (threadIdx.x >> 6);
  int lane = threadIdx.x & 63;
  const float* row = &S[(size_t)i * N];
  float v[5] = {-3e38f, -3e38f, -3e38f, -3e38f, -3e38f};
  int jx[5] = {0x7fffffff, 0x7fffffff, 0x7fffffff, 0x7fffffff, 0x7fffffff};
  for (int t = 0; t < 64; t++) {
    int j = t * 64 + lane;
    ins5(row[j], j, v, jx);
  }
#pragma unroll
  for (int d = 1; d < 64; d <<= 1) {
    float fv[5]; int fj[5];
#pragma unroll
    for (int c = 0; c < 5; c++) { fv[c] = __shfl_xor(v[c], d); fj[c] = __shfl_xor(jx[c], d); }
#pragma unroll
    for (int c = 0; c < 5; c++) ins5(fv[c], fj[c], v, jx);
  }
  // exact fp32 rescore of the 5 candidates (all lanes hold identical lists)
  const float* hi = &hhat[(size_t)i * H];
  float b0 = -3e38f, b1 = -3e38f, b2 = -3e38f;
  int q0 = 0, q1 = 0, q2 = 0;
#pragma unroll
  for (int c = 0; c < 5; c++) {
    int j = jx[c];
    float s;
    if (j == i) {
      s = 0.f;  // reference zeroes the diagonal before top_k
    } else {
      const float* hj = &hhat[(size_t)j * H];
      float p = hi[lane] * hj[lane] + hi[lane + 64] * hj[lane + 64];
      s = wave_reduce_sum(p);
    }
    top3_ins(s, j, b0, q0, b1, q1, b2, q2);
  }
  if (lane == 0) {
    mtv[i * 3 + 0] = b0; mtv[i * 3 + 1] = b1; mtv[i * 3 + 2] = b2;
    mtj[i * 3 + 0] = q0; mtj[i * 3 + 1] = q1; mtj[i * 3 + 2] = q2;
  }
}

// wave-per-row scatter: hidden2[j] += v * h[i], colsum_m[j] += v
__global__ __launch_bounds__(256) void k_scatter(
    const float* __restrict__ mtv, const int* __restrict__ mtj,
    const float* __restrict__ h, float* __restrict__ hidden2,
    float* __restrict__ colsum_m) {
  int i = blockIdx.x * 4 + (threadIdx.x >> 6);
  int lane = threadIdx.x & 63;
  float h0 = h[(size_t)i * H + lane], h1 = h[(size_t)i * H + 64 + lane];
#pragma unroll
  for (int s = 0; s < 3; s++) {
    float v = mtv[i * 3 + s];
    int j = mtj[i * 3 + s];
    atomicAdd(&hidden2[(size_t)j * H + lane], v * h0);
    atomicAdd(&hidden2[(size_t)j * H + 64 + lane], v * h1);
    if (lane == s) atomicAdd(&colsum_m[j], v);
  }
}

// ---------------- 64x128-tile split-K KN GEMM, 128 threads, 8x8 micro ---------
template <int EXP>
__global__ __launch_bounds__(128, 3) void k_kn(
    const float* __restrict__ A, int lda,
    const float* __restrict__ rowmax, const float* __restrict__ rowinv,
    const float* __restrict__ B, float* __restrict__ partial, int KC) {
  __shared__ float As[32][68];
  __shared__ float Bs[32][132];
  int tid = threadIdx.x;
  int tx = tid & 15, ty = tid >> 4;
  int bm = blockIdx.y * 64;
  int k0 = blockIdx.z * KC;
  float rm[4], ri[4];
  if (EXP) {
#pragma unroll
    for (int q = 0; q < 4; q++) {
      int row = q * 16 + (tid >> 3);
      rm[q] = rowmax[bm + row]; ri[q] = rowinv[bm + row];
    }
  }
  float acc[8][8];
#pragma unroll
  for (int r = 0; r < 8; r++)
#pragma unroll
    for (int c = 0; c < 8; c++) acc[r][c] = 0.f;
  for (int kt = 0; kt < KC; kt += 32) {
#pragma unroll
    for (int q = 0; q < 4; q++) {
      int f = q * 128 + tid;
      int row = f >> 3, kq = f & 7;
      float4 av = *(const float4*)&A[(size_t)(bm + row) * lda + k0 + kt + kq * 4];
      if (EXP) {
        av.x = __expf(av.x - rm[q]) * ri[q];
        av.y = __expf(av.y - rm[q]) * ri[q];
        av.z = __expf(av.z - rm[q]) * ri[q];
        av.w = __expf(av.w - rm[q]) * ri[q];
      }
      As[kq * 4 + 0][row] = av.x; As[kq * 4 + 1][row] = av.y;
      As[kq * 4 + 2][row] = av.z; As[kq * 4 + 3][row] = av.w;
    }
#pragma unroll
    for (int q = 0; q < 8; q++) {
      int f = q * 128 + tid;
      int kr = f >> 5, nq = f & 31;
      float4 bv = *(const float4*)&B[(size_t)(k0 + kt + kr) * 128 + nq * 4];
      *(float4*)&Bs[kr][nq * 4] = bv;
    }
    __syncthreads();
#pragma unroll 8
    for (int kk = 0; kk < 32; kk++) {
      float4 a0 = *(float4*)&As[kk][ty * 8];
      float4 a1 = *(float4*)&As[kk][ty * 8 + 4];
      float4 b0 = *(float4*)&Bs[kk][tx * 8];
      float4 b1 = *(float4*)&Bs[kk][tx * 8 + 4];
      float am[8] = {a0.x, a0.y, a0.z, a0.w, a1.x, a1.y, a1.z, a1.w};
      float bb[8] = {b0.x, b0.y, b0.z, b0.w, b1.x, b1.y, b1.z, b1.w};
#pragma unroll
      for (int r = 0; r < 8; r++)
#pragma unroll
        for (int c = 0; c < 8; c++) acc[r][c] += am[r] * bb[c];
    }
    __syncthreads();
  }
  float* pp = partial + (size_t)blockIdx.z * N * 128;
#pragma unroll
  for (int r = 0; r < 8; r++) {
    size_t off = (size_t)(bm + ty * 8 + r) * 128 + tx * 8;
    float4 v0 = {acc[r][0], acc[r][1], acc[r][2], acc[r][3]};
    float4 v1 = {acc[r][4], acc[r][5], acc[r][6], acc[r][7]};
    *(float4*)&pp[off] = v0;
    *(float4*)&pp[off + 4] = v1;
  }
}

// ---------------- split-K GEMM with generated A^T (ps staging GEMMs) ----------
template <int AMODE>
__global__ __launch_bounds__(256) void k_gemm_genA(
    const float* __restrict__ P, const float* __restrict__ mv,
    const float* __restrict__ col1, const float* __restrict__ col2,
    const float* __restrict__ B, float* __restrict__ partial, int KC) {
  __shared__ float Ps[32][68];
  __shared__ float Bs[32][68];
  int tid = threadIdx.x;
  int tx = tid & 15, ty = tid >> 4;
  int bm = blockIdx.y * 64, bn = blockIdx.x * 64;
  int k0 = blockIdx.z * KC;
  float acc[4][4];
#pragma unroll
  for (int r = 0; r < 4; r++)
#pragma unroll
    for (int c = 0; c < 4; c++) acc[r][c] = 0.f;
  for (int kt = 0; kt < KC; kt += 32) {
#pragma unroll
    for (int q = 0; q < 2; q++) {
      int f = q * 256 + tid;
      int kr = f >> 4, nq = f & 15;
      int k = k0 + kt + kr;
      float4 pv = *(const float4*)&P[(size_t)k * C + bm + nq * 4];
      float4 av;
      if (AMODE == 1) {
        float m = mv[k];
        float4 cs = *(const float4*)&col1[bm + nq * 4];
        av.x = pv.x * m / (cs.x * pv.x + 1.f);
        av.y = pv.y * m / (cs.y * pv.y + 1.f);
        av.z = pv.z * m / (cs.z * pv.z + 1.f);
        av.w = pv.w * m / (cs.w * pv.w + 1.f);
      } else {
        float4 cm_ = *(const float4*)&col1[bm + nq * 4];
        float4 cd = *(const float4*)&col2[bm + nq * 4];
        av.x = __expf(pv.x - cm_.x) / cd.x;
        av.y = __expf(pv.y - cm_.y) / cd.y;
        av.z = __expf(pv.z - cm_.z) / cd.z;
        av.w = __expf(pv.w - cm_.w) / cd.w;
      }
      *(float4*)&Ps[kr][nq * 4] = av;
      float4 bv = *(const float4*)&B[(size_t)k * 128 + bn + nq * 4];
      *(float4*)&Bs[kr][nq * 4] = bv;
    }
    __syncthreads();
#pragma unroll
    for (int kk = 0; kk < 32; kk++) {
      float4 fa = *(float4*)&Ps[kk][ty * 4];
      float4 fb = *(float4*)&Bs[kk][tx * 4];
      float am[4] = {fa.x, fa.y, fa.z, fa.w};
      float bb[4] = {fb.x, fb.y, fb.z, fb.w};
#pragma unroll
      for (int r = 0; r < 4; r++)
#pragma unroll
        for (int c = 0; c < 4; c++) acc[r][c] += am[r] * bb[c];
    }
    __syncthreads();
  }
  float* pp = partial + (size_t)blockIdx.z * C * 128;
#pragma unroll
  for (int r = 0; r < 4; r++) {
    float4 v = {acc[r][0], acc[r][1], acc[r][2], acc[r][3]};
    *(float4*)&pp[(size_t)(bm + ty * 4 + r) * 128 + bn + tx * 4] = v;
  }
}

// reduce split-K partials; optional per-row (128-wide) valid scale
__global__ __launch_bounds__(256) void k_reduce(
    const float* __restrict__ partial, float* __restrict__ out, int cnt,
    size_t slot, size_t size4, const float* __restrict__ validm) {
  size_t idx = (size_t)blockIdx.x * 256 + threadIdx.x;
  if (idx >= size4) return;
  float4 s = {0, 0, 0, 0};
  for (int c = 0; c < cnt; c++) {
    float4 v = *(const float4*)&partial[c * slot + idx * 4];
    s.x += v.x; s.y += v.y; s.z += v.z; s.w += v.w;
  }
  if (validm) {
    float sc = validm[idx >> 5];
    s.x *= sc; s.y *= sc; s.z *= sc; s.w *= sc;
  }
  *(float4*)&out[idx * 4] = s;
}

// ---------------- linear: out[4096,128] = epi(A @ W^T + b) ----------------
template <int EPI>
__global__ __launch_bounds__(256) void k_gemm_lin(
    const float* __restrict__ A, const float* __restrict__ Wt,
    const float* __restrict__ bias, const float* __restrict__ aux,
    float* __restrict__ out) {
  __shared__ float As[32][68];
  __shared__ float Ws[32][68];
  int tid = threadIdx.x;
  int tx = tid & 15, ty = tid >> 4;
  int bm = blockIdx.y * 64, bn = blockIdx.x * 64;
  float acc[4][4];
#pragma unroll
  for (int r = 0; r < 4; r++)
#pragma unroll
    for (int c = 0; c < 4; c++) acc[r][c] = 0.f;
  for (int kt = 0; kt < 128; kt += 32) {
#pragma unroll
    for (int q = 0; q < 2; q++) {
      int f = q * 256 + tid;
      int row = f >> 3, kq = f & 7;
      float4 av = *(const float4*)&A[(size_t)(bm + row) * 128 + kt + kq * 4];
      As[kq * 4 + 0][row] = av.x; As[kq * 4 + 1][row] = av.y;
      As[kq * 4 + 2][row] = av.z; As[kq * 4 + 3][row] = av.w;
      float4 wv = *(const float4*)&Wt[(size_t)(bn + row) * 128 + kt + kq * 4];
      Ws[kq * 4 + 0][row] = wv.x; Ws[kq * 4 + 1][row] = wv.y;
      Ws[kq * 4 + 2][row] = wv.z; Ws[kq * 4 + 3][row] = wv.w;
    }
    __syncthreads();
#pragma unroll
    for (int kk = 0; kk < 32; kk++) {
      float4 fa = *(float4*)&As[kk][ty * 4];
      float4 fb = *(float4*)&Ws[kk][tx * 4];
      float am[4] = {fa.x, fa.y, fa.z, fa.w};
      float bb[4] = {fb.x, fb.y, fb.z, fb.w};
#pragma unroll
      for (int r = 0; r < 4; r++)
#pragma unroll
        for (int c = 0; c < 4; c++) acc[r][c] += am[r] * bb[c];
    }
    __syncthreads();
  }
  float4 bb = *(const float4*)&bias[bn + tx * 4];
  float bv[4] = {bb.x, bb.y, bb.z, bb.w};
#pragma unroll
  for (int r = 0; r < 4; r++) {
    size_t off = (size_t)(bm + ty * 4 + r) * 128 + bn + tx * 4;
    float v[4];
#pragma unroll
    for (int c = 0; c < 4; c++) v[c] = acc[r][c] + bv[c];
    if (EPI == 0) {
      float4 s = {v[0], v[1], v[2], v[3]};
      *(float4*)&out[off] = s;
    } else if (EPI == 1) {
      float4 s = {lrelu(v[0]), lrelu(v[1]), lrelu(v[2]), lrelu(v[3])};
      *(float4*)&out[off] = s;
    } else if (EPI == 2) {
      float4 p = *(float4*)&out[off];
      p.x += lrelu(v[0]); p.y += lrelu(v[1]); p.z += lrelu(v[2]); p.w += lrelu(v[3]);
      *(float4*)&out[off] = p;
    } else {
      float4 a = *(const float4*)&aux[off];
      float4 s = {a.x - v[0], a.y - v[1], a.z - v[2], a.w - v[3]};
      *(float4*)&out[off] = s;
    }
  }
}

// ---------------- launch ----------------

extern "C" void kernel_launch(void* const* d_in, const int* in_sizes, int n_in,
                              void* d_out, int out_size, void* d_ws, size_t ws_size,
                              hipStream_t stream) {
  (void)in_sizes; (void)n_in; (void)out_size;
  const float* x   = (const float*)d_in[0];
  const float* cm  = (const float*)d_in[1];
  const float* mv  = (const float*)d_in[2];
  const float* W_ps = (const float*)d_in[3],  *b_ps = (const float*)d_in[4];
  const float* W_psf = (const float*)d_in[5], *b_psf = (const float*)d_in[6];
  const float* W_psb = (const float*)d_in[7], *b_psb = (const float*)d_in[8];
  const float* W_hs = (const float*)d_in[9],  *b_hs = (const float*)d_in[10];
  const float* W_hsf = (const float*)d_in[11], *b_hsf = (const float*)d_in[12];
  const float* W_hsb = (const float*)d_in[13], *b_hsb = (const float*)d_in[14];
  const float* W_in = (const float*)d_in[15], *b_in = (const float*)d_in[16];
  const float* W_out = (const float*)d_in[17], *b_out = (const float*)d_in[18];
  float* out = (float*)d_out;

  float* W = (float*)d_ws;
  size_t o = 0;
  auto alloc = [&](size_t n) { float* p = W + o; o += n; return p; };
  float* colsum_c = alloc(C);
  float* colmax   = alloc(C);
  float* colsumexp= alloc(C);
  float* valid1   = alloc(C);
  float* hnorm_ps = alloc(C);
  float* xnorm    = alloc(N);
  float* diagv    = alloc(N);
  float* colsum_m = alloc(N);
  float* valid2f  = alloc(N);
  float* rowmax   = alloc(N);
  float* rowinv   = alloc(N);
  float* mtv      = alloc(3 * N);
  int*   mtj      = (int*)alloc(3 * N);
  float* hidden1  = alloc((size_t)C * H);
  float* hidden_ps= alloc((size_t)C * H);
  float* scores   = alloc((size_t)N * C);
  float* ps_pre   = alloc((size_t)N * H);   // later hs_pre
  float* p_shared = alloc((size_t)N * H);   // later h_shared
  float* all_info = alloc((size_t)N * H);
  float* hbuf     = alloc((size_t)N * H);   // h; later indiv (in-place)
  float* hhat     = alloc((size_t)N * H);
  float* hidden2  = alloc((size_t)N * H);
  float* h2hat    = alloc((size_t)N * H);
  // bf16 split buffers (ushort; counts are even -> 16B aligned)
  unsigned short* xhi   = (unsigned short*)alloc((size_t)N * H / 2);
  unsigned short* xlo   = (unsigned short*)alloc((size_t)N * H / 2);
  unsigned short* hhathi= (unsigned short*)alloc((size_t)N * H / 2);
  unsigned short* hhatlo= (unsigned short*)alloc((size_t)N * H / 2);
  unsigned short* h2hi  = (unsigned short*)alloc((size_t)N * H / 2);
  unsigned short* h2lo  = (unsigned short*)alloc((size_t)N * H / 2);
  unsigned short* h1hi  = (unsigned short*)alloc((size_t)C * H / 2);
  unsigned short* h1lo  = (unsigned short*)alloc((size_t)C * H / 2);
  unsigned short* hpshi = (unsigned short*)alloc((size_t)C * H / 2);
  unsigned short* hpslo = (unsigned short*)alloc((size_t)C * H / 2);
  float* Sbuf     = alloc((size_t)N * N);   // 64 MB score matrix (reused 2x)
  float* partial  = W + o;                  // split-K partials: remaining ws
  size_t rem = ws_size / 4 - o;
  int Z = (rem >= (size_t)16 * N * H) ? 16 : 8;
  int KC = 4096 / Z;

  hipMemsetAsync(colsum_c, 0, C * sizeof(float), stream);
  hipMemsetAsync(colsum_m, 0, N * sizeof(float), stream);
  hipMemsetAsync(hidden2, 0, (size_t)N * H * sizeof(float), stream);

  dim3 blk(256);
  // --- ps branch ---
  k_split<<<dim3(N * H / 1024), blk, 0, stream>>>(x, xhi, xlo);
  k_colsum_s2c<<<dim3(C / 64, 16), dim3(64), 0, stream>>>(cm, mv, colsum_c);
  k_gemm_genA<1><<<dim3(2, C / 64, 16), blk, 0, stream>>>(
      cm, mv, colsum_c, nullptr, x, partial, N / 16);
  k_reduce<<<dim3(C * H / 4 / 256), blk, 0, stream>>>(
      partial, hidden1, 16, (size_t)C * H, (size_t)C * H / 4, nullptr);
  k_valid1<<<dim3(C), dim3(64), 0, stream>>>(hidden1, valid1);
  k_split<<<dim3(C * H / 1024), blk, 0, stream>>>(hidden1, h1hi, h1lo);
  k_mfma_nt<0><<<dim3(C / 128, N / 128), blk, 0, stream>>>(
      xhi, xlo, h1hi, h1lo, nullptr, scores, C);
  k_colstats<<<dim3(C), blk, 0, stream>>>(scores, colmax, colsumexp);
  k_gemm_genA<2><<<dim3(2, C / 64, 16), blk, 0, stream>>>(
      scores, nullptr, colmax, colsumexp, x, partial, N / 16);
  k_reduce<<<dim3(C * H / 4 / 256), blk, 0, stream>>>(
      partial, hidden_ps, 16, (size_t)C * H, (size_t)C * H / 4, valid1);
  k_rownorm128<<<dim3(N), dim3(64), 0, stream>>>(x, xnorm);
  k_rownorm128<<<dim3(C), dim3(64), 0, stream>>>(hidden_ps, hnorm_ps);
  k_split<<<dim3(C * H / 1024), blk, 0, stream>>>(hidden_ps, hpshi, hpslo);
  k_mfma_nt<0><<<dim3(C / 128, N / 128), blk, 0, stream>>>(
      xhi, xlo, hpshi, hpslo, nullptr, scores, C);
  k_cs_softmax<<<dim3(N), blk, 0, stream>>>(scores, xnorm, hnorm_ps, valid1);
  k_kn<0><<<dim3(1, N / 64, 4), dim3(128), 0, stream>>>(
      scores, C, nullptr, nullptr, hidden_ps, partial, C / 4);
  k_reduce<<<dim3(N * H / 4 / 256), blk, 0, stream>>>(
      partial, ps_pre, 4, (size_t)N * H, (size_t)N * H / 4, nullptr);
  k_gemm_lin<0><<<dim3(2, N / 64), blk, 0, stream>>>(
      ps_pre, W_ps, b_ps, nullptr, p_shared);
  k_gemm_lin<3><<<dim3(2, N / 64), blk, 0, stream>>>(
      p_shared, W_psb, b_psb, x, hbuf);                      // h = x - p_back
  k_gemm_lin<1><<<dim3(2, N / 64), blk, 0, stream>>>(
      p_shared, W_psf, b_psf, nullptr, all_info);            // out_ps
  // --- hs branch ---
  k_hhat<<<dim3(N), dim3(64), 0, stream>>>(hbuf, hhat, diagv);
  k_split<<<dim3(N * H / 1024), blk, 0, stream>>>(hhat, hhathi, hhatlo);
  k_mfma_nt<2><<<dim3(N / 128, N / 128), blk, 0, stream>>>(
      hhathi, hhatlo, hhathi, hhatlo, nullptr, Sbuf, N);     // hhat.hhat^T, diag=0
  k_rowtop<<<dim3(N / 4), blk, 0, stream>>>(Sbuf, hhat, mtv, mtj);
  k_scatter<<<dim3(N / 4), blk, 0, stream>>>(mtv, mtj, hbuf, hidden2, colsum_m);
  k_fin_hidden2<<<dim3(N), dim3(64), 0, stream>>>(hbuf, diagv, colsum_m, hidden2,
                                                  h2hat, valid2f);
  k_split<<<dim3(N * H / 1024), blk, 0, stream>>>(h2hat, h2hi, h2lo);
  k_mfma_nt<1><<<dim3(N / 128, N / 128), blk, 0, stream>>>(
      hhathi, hhatlo, h2hi, h2lo, valid2f, Sbuf, N);         // S, masked
  k_rowstats<<<dim3(N), blk, 0, stream>>>(Sbuf, rowmax, rowinv);
  k_kn<1><<<dim3(1, N / 64, Z), dim3(128), 0, stream>>>(
      Sbuf, N, rowmax, rowinv, hidden2, partial, KC);
  k_reduce<<<dim3(N * H / 4 / 256), blk, 0, stream>>>(
      partial, ps_pre, Z, (size_t)N * H, (size_t)N * H / 4, nullptr);  // hs_pre
  k_gemm_lin<0><<<dim3(2, N / 64), blk, 0, stream>>>(
      ps_pre, W_hs, b_hs, nullptr, p_shared);                // h_shared
  k_gemm_lin<2><<<dim3(2, N / 64), blk, 0, stream>>>(
      p_shared, W_hsf, b_hsf, nullptr, all_info);            // += out_hs
  k_gemm_lin<3><<<dim3(2, N / 64), blk, 0, stream>>>(
      p_shared, W_hsb, b_hsb, hbuf, hbuf);                   // indiv = h - h_back
  k_gemm_lin<2><<<dim3(2, N / 64), blk, 0, stream>>>(
      hbuf, W_in, b_in, nullptr, all_info);                  // += out_indi
  k_final<<<dim3(N), dim3(64), 0, stream>>>(all_info, W_out, b_out, out);
}

// Round 7
// 461.514 us; speedup vs baseline: 5.4572x; 1.0858x over previous
//
#include <hip/hip_runtime.h>
#include <math.h>

#define N 4096
#define C 512
#define H 128
#define PAD 40  // ushort row pitch for MFMA LDS tiles (80 B: 16B-aligned, 2-way banks)

typedef __attribute__((ext_vector_type(8))) short bf16x8;
typedef __attribute__((ext_vector_type(4))) float f32x4;

// ---------------- helpers ----------------

__device__ inline float wave_reduce_sum(float v) {
#pragma unroll
  for (int m = 32; m; m >>= 1) v += __shfl_xor(v, m);
  return v;
}

__device__ inline float lrelu(float v) { return v > 0.f ? v : 0.01f * v; }

__device__ inline bool better(float v, int j, float w, int k) {
  return (v > w) || (v == w && j < k);
}

__device__ inline void top3_ins(float v, int j, float& v0, int& j0,
                                float& v1, int& j1, float& v2, int& j2) {
  if (better(v, j, v0, j0)) { v2 = v1; j2 = j1; v1 = v0; j1 = j0; v0 = v; j0 = j; }
  else if (better(v, j, v1, j1)) { v2 = v1; j2 = j1; v1 = v; j1 = j; }
  else if (better(v, j, v2, j2)) { v2 = v; j2 = j; }
}

__device__ inline void ins5(float s, int j, float v[5], int jx[5]) {
  if (!better(s, j, v[4], jx[4])) return;
  if (better(s, j, v[0], jx[0])) {
    v[4]=v[3]; jx[4]=jx[3]; v[3]=v[2]; jx[3]=jx[2]; v[2]=v[1]; jx[2]=jx[1];
    v[1]=v[0]; jx[1]=jx[0]; v[0]=s; jx[0]=j;
  } else if (better(s, j, v[1], jx[1])) {
    v[4]=v[3]; jx[4]=jx[3]; v[3]=v[2]; jx[3]=jx[2]; v[2]=v[1]; jx[2]=jx[1];
    v[1]=s; jx[1]=j;
  } else if (better(s, j, v[2], jx[2])) {
    v[4]=v[3]; jx[4]=jx[3]; v[3]=v[2]; jx[3]=jx[2]; v[2]=s; jx[2]=j;
  } else if (better(s, j, v[3], jx[3])) {
    v[4]=v[3]; jx[4]=jx[3]; v[3]=s; jx[3]=j;
  } else {
    v[4]=s; jx[4]=j;
  }
}

__device__ inline unsigned short f2bf(float f) {
  unsigned u = __float_as_uint(f);
  unsigned r = u + 0x7fffu + ((u >> 16) & 1u);
  return (unsigned short)(r >> 16);
}
__device__ inline float bf2f(unsigned short h) {
  return __uint_as_float(((unsigned)h) << 16);
}

// ---------------- split fp32 -> bf16 hi/lo ----------------
__global__ __launch_bounds__(256) void k_split(const float* __restrict__ in,
                                               unsigned short* __restrict__ hi,
                                               unsigned short* __restrict__ lo) {
  int idx = (blockIdx.x * 256 + threadIdx.x) * 4;
  float4 v = *(const float4*)&in[idx];
  float vv[4] = {v.x, v.y, v.z, v.w};
  unsigned short h[4], l[4];
#pragma unroll
  for (int c = 0; c < 4; c++) {
    h[c] = f2bf(vv[c]);
    l[c] = f2bf(vv[c] - bf2f(h[c]));
  }
  uint2 ph = {(unsigned)h[0] | ((unsigned)h[1] << 16),
              (unsigned)h[2] | ((unsigned)h[3] << 16)};
  uint2 pl = {(unsigned)l[0] | ((unsigned)l[1] << 16),
              (unsigned)l[2] | ((unsigned)l[3] << 16)};
  *(uint2*)&hi[idx] = ph;
  *(uint2*)&lo[idx] = pl;
}

// transpose + split: in [R,128] fp32 -> thi/tlo [128,R] ushort
__global__ __launch_bounds__(256) void k_tsplit(const float* __restrict__ in,
                                                unsigned short* __restrict__ thi,
                                                unsigned short* __restrict__ tlo,
                                                int R) {
  __shared__ float tile[32][132];
  int r0 = blockIdx.x * 32, tid = threadIdx.x;
#pragma unroll
  for (int q = 0; q < 4; q++) {
    int f = q * 256 + tid;
    int row = f >> 5, ch = f & 31;  // 32 rows x 32 float4-chunks (R6 bug: was >>3/&7)
    *(float4*)&tile[row][ch * 4] = *(const float4*)&in[(size_t)(r0 + row) * 128 + ch * 4];
  }
  __syncthreads();
  int c = tid & 127, half = tid >> 7;
  unsigned short hh[16], ll[16];
#pragma unroll
  for (int rr = 0; rr < 16; rr++) {
    float v = tile[half * 16 + rr][c];
    hh[rr] = f2bf(v);
    ll[rr] = f2bf(v - bf2f(hh[rr]));
  }
  size_t off = (size_t)c * R + r0 + half * 16;
  uint4 ph0 = {(unsigned)hh[0] | ((unsigned)hh[1] << 16), (unsigned)hh[2] | ((unsigned)hh[3] << 16),
               (unsigned)hh[4] | ((unsigned)hh[5] << 16), (unsigned)hh[6] | ((unsigned)hh[7] << 16)};
  uint4 ph1 = {(unsigned)hh[8] | ((unsigned)hh[9] << 16), (unsigned)hh[10] | ((unsigned)hh[11] << 16),
               (unsigned)hh[12] | ((unsigned)hh[13] << 16), (unsigned)hh[14] | ((unsigned)hh[15] << 16)};
  uint4 pl0 = {(unsigned)ll[0] | ((unsigned)ll[1] << 16), (unsigned)ll[2] | ((unsigned)ll[3] << 16),
               (unsigned)ll[4] | ((unsigned)ll[5] << 16), (unsigned)ll[6] | ((unsigned)ll[7] << 16)};
  uint4 pl1 = {(unsigned)ll[8] | ((unsigned)ll[9] << 16), (unsigned)ll[10] | ((unsigned)ll[11] << 16),
               (unsigned)ll[12] | ((unsigned)ll[13] << 16), (unsigned)ll[14] | ((unsigned)ll[15] << 16)};
  *(uint4*)&thi[off] = ph0; *(uint4*)&thi[off + 8] = ph1;
  *(uint4*)&tlo[off] = pl0; *(uint4*)&tlo[off + 8] = pl1;
}

// ---------------- small kernels ----------------

__global__ __launch_bounds__(64) void k_colsum_s2c(
    const float* __restrict__ cm, const float* __restrict__ mv,
    float* __restrict__ colsum_c) {
  int c = blockIdx.x * 64 + threadIdx.x;
  int i0 = blockIdx.y * 256;
  float acc = 0.f;
  for (int i = i0; i < i0 + 256; i++) acc += cm[(size_t)i * C + c] * mv[i];
  atomicAdd(&colsum_c[c], acc);
}

__global__ __launch_bounds__(64) void k_valid1(const float* __restrict__ hid,
                                               float* __restrict__ valid1) {
  int c = blockIdx.x, t = threadIdx.x;
  float s = hid[(size_t)c * H + t] + hid[(size_t)c * H + 64 + t];
  s = wave_reduce_sum(s);
  if (t == 0) valid1[c] = (s != 0.f) ? 1.f : 0.f;
}

__global__ __launch_bounds__(64) void k_rownorm128(const float* __restrict__ A,
                                                   float* __restrict__ nrm) {
  int r = blockIdx.x, t = threadIdx.x;
  float a = A[(size_t)r * H + t], b = A[(size_t)r * H + 64 + t];
  float ss = wave_reduce_sum(a * a + b * b);
  if (t == 0) nrm[r] = sqrtf(ss);
}

__global__ __launch_bounds__(256) void k_colstats(const float* __restrict__ sc,
                                                  float* __restrict__ colmax,
                                                  float* __restrict__ colsum) {
  __shared__ float red[256];
  int c = blockIdx.x, t = threadIdx.x;
  float v[16];
  float m = -3e38f;
#pragma unroll
  for (int q = 0; q < 16; q++) {
    v[q] = sc[(size_t)(q * 256 + t) * C + c];
    m = fmaxf(m, v[q]);
  }
  red[t] = m; __syncthreads();
  for (int s = 128; s; s >>= 1) { if (t < s) red[t] = fmaxf(red[t], red[t + s]); __syncthreads(); }
  m = red[0]; __syncthreads();
  float sum = 0.f;
#pragma unroll
  for (int q = 0; q < 16; q++) sum += __expf(v[q] - m);
  red[t] = sum; __syncthreads();
  for (int s = 128; s; s >>= 1) { if (t < s) red[t] += red[t + s]; __syncthreads(); }
  if (t == 0) { colmax[c] = m; colsum[c] = red[0]; }
}

// row softmax of cos-sim -> bf16 hi/lo pairs
__global__ __launch_bounds__(256) void k_cs_softmax(
    const float* __restrict__ sc, const float* __restrict__ xnorm,
    const float* __restrict__ hnorm, const float* __restrict__ valid1,
    unsigned short* __restrict__ cshi, unsigned short* __restrict__ cslo) {
  __shared__ float red[256];
  int i = blockIdx.x, t = threadIdx.x;
  float xn = xnorm[i];
  float r0 = sc[(size_t)i * C + t], r1 = sc[(size_t)i * C + 256 + t];
  float d0 = xn * hnorm[t], d1 = xn * hnorm[256 + t];
  float c0 = r0 / (d0 == 0.f ? 1.f : d0);
  float c1 = r1 / (d1 == 0.f ? 1.f : d1);
  float s0 = (valid1[t] != 0.f) ? c0 : -3e38f;
  float s1 = (valid1[256 + t] != 0.f) ? c1 : -3e38f;
  red[t] = fmaxf(s0, s1); __syncthreads();
  for (int s = 128; s; s >>= 1) { if (t < s) red[t] = fmaxf(red[t], red[t + s]); __syncthreads(); }
  float m = red[0]; __syncthreads();
  float p0 = (s0 > -1e37f) ? __expf(s0 - m) : 0.f;
  float p1 = (s1 > -1e37f) ? __expf(s1 - m) : 0.f;
  red[t] = p0 + p1; __syncthreads();
  for (int s = 128; s; s >>= 1) { if (t < s) red[t] += red[t + s]; __syncthreads(); }
  float inv = 1.f / red[0];
  float a = p0 * inv, b = p1 * inv;
  unsigned short ha = f2bf(a), hb = f2bf(b);
  cshi[(size_t)i * C + t] = ha;
  cslo[(size_t)i * C + t] = f2bf(a - bf2f(ha));
  cshi[(size_t)i * C + 256 + t] = hb;
  cslo[(size_t)i * C + 256 + t] = f2bf(b - bf2f(hb));
}

__global__ __launch_bounds__(64) void k_hhat(const float* __restrict__ h,
                                             float* __restrict__ hhat,
                                             float* __restrict__ diagv) {
  int i = blockIdx.x, t = threadIdx.x;
  float a = h[(size_t)i * H + t], b = h[(size_t)i * H + 64 + t];
  float ss = wave_reduce_sum(a * a + b * b);
  float hn = sqrtf(ss);
  float den = hn * hn;
  float dg = (den == 0.f) ? 0.f : ss / den;
  float inv = (ss > 0.f) ? (1.f / hn) : 1.f;
  hhat[(size_t)i * H + t] = a * inv;
  hhat[(size_t)i * H + 64 + t] = b * inv;
  if (t == 0) diagv[i] = dg;
}

__global__ __launch_bounds__(64) void k_fin_hidden2(
    const float* __restrict__ h, const float* __restrict__ diagv,
    const float* __restrict__ colsum_m, float* __restrict__ hidden2,
    float* __restrict__ h2hat, float* __restrict__ valid2f) {
  int j = blockIdx.x, t = threadIdx.x;
  float add = (colsum_m[j] != 0.f) ? diagv[j] : 0.f;
  float a = hidden2[(size_t)j * H + t] + add * h[(size_t)j * H + t];
  float b = hidden2[(size_t)j * H + 64 + t] + add * h[(size_t)j * H + 64 + t];
  float s = a + b, ss = a * a + b * b;
#pragma unroll
  for (int m = 32; m; m >>= 1) { s += __shfl_xor(s, m); ss += __shfl_xor(ss, m); }
  bool valid = (s != 0.f);
  a = valid ? a : 0.f; b = valid ? b : 0.f;
  hidden2[(size_t)j * H + t] = a;
  hidden2[(size_t)j * H + 64 + t] = b;
  float inv = (valid && ss > 0.f) ? (1.f / sqrtf(ss)) : 1.f;
  h2hat[(size_t)j * H + t] = a * inv;
  h2hat[(size_t)j * H + 64 + t] = b * inv;
  if (t == 0) valid2f[j] = valid ? 1.f : 0.f;
}

__global__ __launch_bounds__(256) void k_recip(const float* __restrict__ in,
                                               float* __restrict__ outv) {
  int i = blockIdx.x * 256 + threadIdx.x;
  outv[i] = 1.f / in[i];
}

__global__ __launch_bounds__(64) void k_final(const float* __restrict__ ai,
                                              const float* __restrict__ Wout,
                                              const float* __restrict__ bout,
                                              float* __restrict__ out) {
  int i = blockIdx.x, t = threadIdx.x;
  float s = ai[(size_t)i * H + t] * Wout[t] + ai[(size_t)i * H + 64 + t] * Wout[64 + t];
  s = wave_reduce_sum(s);
  if (t == 0) out[i] = s + bout[0];
}

// ---------------- bf16x3 MFMA NT GEMM: A[M,128] @ B[Nn,128]^T ----------------
// EPI 0: fp32 store; 2: diag-zeroed fp32 store; 3: E=exp(s-1) masked -> bf16
// pairs (ehi/elo) + per-row sum atomics into lsum
template <int EPI>
__global__ __launch_bounds__(256) void k_mfma_nt(
    const unsigned short* __restrict__ Ahi, const unsigned short* __restrict__ Alo,
    const unsigned short* __restrict__ Bhi, const unsigned short* __restrict__ Blo,
    const float* __restrict__ validn, float* __restrict__ out,
    unsigned short* __restrict__ ehi, unsigned short* __restrict__ elo,
    float* __restrict__ lsum, int Nn) {
  __shared__ __align__(16) unsigned short sAh[128 * PAD];
  __shared__ __align__(16) unsigned short sAl[128 * PAD];
  __shared__ __align__(16) unsigned short sBh[128 * PAD];
  __shared__ __align__(16) unsigned short sBl[128 * PAD];
  int tid = threadIdx.x;
  int bm = blockIdx.y * 128, bn = blockIdx.x * 128;
  int lane = tid & 63, w = tid >> 6;
  int wm = (w & 1) * 64, wn = (w >> 1) * 64;
  int l15 = lane & 15, quad = lane >> 4;
  f32x4 zero = {0.f, 0.f, 0.f, 0.f};
  f32x4 acc[4][4];
#pragma unroll
  for (int mt = 0; mt < 4; mt++)
#pragma unroll
    for (int nt = 0; nt < 4; nt++) acc[mt][nt] = zero;

  for (int kt = 0; kt < 128; kt += 32) {
#pragma unroll
    for (int q = 0; q < 2; q++) {
      int f = tid * 2 + q;
      int row = f >> 2, ch = f & 3;
      size_t ga = (size_t)(bm + row) * 128 + kt + ch * 8;
      size_t gb = (size_t)(bn + row) * 128 + kt + ch * 8;
      int ls = row * PAD + ch * 8;
      *(uint4*)&sAh[ls] = *(const uint4*)&Ahi[ga];
      *(uint4*)&sAl[ls] = *(const uint4*)&Alo[ga];
      *(uint4*)&sBh[ls] = *(const uint4*)&Bhi[gb];
      *(uint4*)&sBl[ls] = *(const uint4*)&Blo[gb];
    }
    __syncthreads();
    bf16x8 ah[4], al[4], bh[4], bl[4];
#pragma unroll
    for (int t = 0; t < 4; t++) {
      int ar = (wm + t * 16 + l15) * PAD + quad * 8;
      ah[t] = *(const bf16x8*)&sAh[ar];
      al[t] = *(const bf16x8*)&sAl[ar];
      int br = (wn + t * 16 + l15) * PAD + quad * 8;
      bh[t] = *(const bf16x8*)&sBh[br];
      bl[t] = *(const bf16x8*)&sBl[br];
    }
#pragma unroll
    for (int mt = 0; mt < 4; mt++)
#pragma unroll
      for (int nt = 0; nt < 4; nt++) {
        acc[mt][nt] = __builtin_amdgcn_mfma_f32_16x16x32_bf16(ah[mt], bh[nt], acc[mt][nt], 0, 0, 0);
        acc[mt][nt] = __builtin_amdgcn_mfma_f32_16x16x32_bf16(ah[mt], bl[nt], acc[mt][nt], 0, 0, 0);
        acc[mt][nt] = __builtin_amdgcn_mfma_f32_16x16x32_bf16(al[mt], bh[nt], acc[mt][nt], 0, 0, 0);
      }
    __syncthreads();
  }
  if (EPI == 3) {
    float vm[4];
#pragma unroll
    for (int nt = 0; nt < 4; nt++) vm[nt] = validn[bn + wn + nt * 16 + l15];
#pragma unroll
    for (int mt = 0; mt < 4; mt++) {
#pragma unroll
      for (int rg = 0; rg < 4; rg++) {
        int row = bm + wm + mt * 16 + quad * 4 + rg;
        float rsum = 0.f;
#pragma unroll
        for (int nt = 0; nt < 4; nt++) {
          int col = bn + wn + nt * 16 + l15;
          float e = (vm[nt] != 0.f) ? __expf(acc[mt][nt][rg] - 1.f) : 0.f;
          rsum += e;
          unsigned short h = f2bf(e);
          ehi[(size_t)row * N + col] = h;
          elo[(size_t)row * N + col] = f2bf(e - bf2f(h));
        }
#pragma unroll
        for (int d = 1; d < 16; d <<= 1) rsum += __shfl_xor(rsum, d);
        if (l15 == 0) atomicAdd(&lsum[row], rsum);
      }
    }
  } else {
#pragma unroll
    for (int mt = 0; mt < 4; mt++) {
#pragma unroll
      for (int nt = 0; nt < 4; nt++) {
        int col = bn + wn + nt * 16 + l15;
#pragma unroll
        for (int rg = 0; rg < 4; rg++) {
          int row = bm + wm + mt * 16 + quad * 4 + rg;
          float v = acc[mt][nt][rg];
          if (EPI == 2 && row == col) v = 0.f;
          out[(size_t)row * Nn + col] = v;
        }
      }
    }
  }
}

// ---------------- bf16x3 MFMA KN GEMM (split-K): partial[z] = A @ B ----------
// A pairs [4096, lda] row-major; Bt pairs [128, lda] (B transposed)
__global__ __launch_bounds__(256) void k_mfma_kn(
    const unsigned short* __restrict__ Ahi, const unsigned short* __restrict__ Alo,
    const unsigned short* __restrict__ Bthi, const unsigned short* __restrict__ Btlo,
    float* __restrict__ partial, int lda, int KC) {
  __shared__ __align__(16) unsigned short sAh[128 * PAD];
  __shared__ __align__(16) unsigned short sAl[128 * PAD];
  __shared__ __align__(16) unsigned short sBh[128 * PAD];
  __shared__ __align__(16) unsigned short sBl[128 * PAD];
  int tid = threadIdx.x;
  int bm = blockIdx.y * 128;
  int k0 = blockIdx.z * KC;
  int lane = tid & 63, w = tid >> 6;
  int wm = (w & 1) * 64, wn = (w >> 1) * 64;
  int l15 = lane & 15, quad = lane >> 4;
  f32x4 zero = {0.f, 0.f, 0.f, 0.f};
  f32x4 acc[4][4];
#pragma unroll
  for (int mt = 0; mt < 4; mt++)
#pragma unroll
    for (int nt = 0; nt < 4; nt++) acc[mt][nt] = zero;

  for (int kt = 0; kt < KC; kt += 32) {
#pragma unroll
    for (int q = 0; q < 2; q++) {
      int f = tid * 2 + q;
      int row = f >> 2, ch = f & 3;
      size_t ga = (size_t)(bm + row) * lda + k0 + kt + ch * 8;
      size_t gb = (size_t)row * lda + k0 + kt + ch * 8;
      int ls = row * PAD + ch * 8;
      *(uint4*)&sAh[ls] = *(const uint4*)&Ahi[ga];
      *(uint4*)&sAl[ls] = *(const uint4*)&Alo[ga];
      *(uint4*)&sBh[ls] = *(const uint4*)&Bthi[gb];
      *(uint4*)&sBl[ls] = *(const uint4*)&Btlo[gb];
    }
    __syncthreads();
    bf16x8 ah[4], al[4], bh[4], bl[4];
#pragma unroll
    for (int t = 0; t < 4; t++) {
      int ar = (wm + t * 16 + l15) * PAD + quad * 8;
      ah[t] = *(const bf16x8*)&sAh[ar];
      al[t] = *(const bf16x8*)&sAl[ar];
      int br = (wn + t * 16 + l15) * PAD + quad * 8;
      bh[t] = *(const bf16x8*)&sBh[br];
      bl[t] = *(const bf16x8*)&sBl[br];
    }
#pragma unroll
    for (int mt = 0; mt < 4; mt++)
#pragma unroll
      for (int nt = 0; nt < 4; nt++) {
        acc[mt][nt] = __builtin_amdgcn_mfma_f32_16x16x32_bf16(ah[mt], bh[nt], acc[mt][nt], 0, 0, 0);
        acc[mt][nt] = __builtin_amdgcn_mfma_f32_16x16x32_bf16(ah[mt], bl[nt], acc[mt][nt], 0, 0, 0);
        acc[mt][nt] = __builtin_amdgcn_mfma_f32_16x16x32_bf16(al[mt], bh[nt], acc[mt][nt], 0, 0, 0);
      }
    __syncthreads();
  }
  float* pp = partial + (size_t)blockIdx.z * N * 128;
#pragma unroll
  for (int mt = 0; mt < 4; mt++)
#pragma unroll
    for (int nt = 0; nt < 4; nt++) {
      int col = wn + nt * 16 + l15;
#pragma unroll
      for (int rg = 0; rg < 4; rg++) {
        int row = bm + wm + mt * 16 + quad * 4 + rg;
        pp[(size_t)row * 128 + col] = acc[mt][nt][rg];
      }
    }
}

// ---------------- bf16x3 MFMA linear: out = epi(A[4096,128] @ W[128,128]^T + b)
// EPI: 0 store, 1 lrelu, 2 += lrelu, 3 aux - v
template <int EPI>
__global__ __launch_bounds__(256) void k_mfma_lin(
    const float* __restrict__ A, const float* __restrict__ Wt,
    const float* __restrict__ bias, const float* __restrict__ aux,
    float* __restrict__ out) {
  __shared__ __align__(16) unsigned short sAh[128 * PAD];
  __shared__ __align__(16) unsigned short sAl[128 * PAD];
  __shared__ __align__(16) unsigned short sWh[128 * PAD];
  __shared__ __align__(16) unsigned short sWl[128 * PAD];
  int tid = threadIdx.x;
  int bm = blockIdx.y * 128;
  int lane = tid & 63, w = tid >> 6;
  int wm = (w & 1) * 64, wn = (w >> 1) * 64;
  int l15 = lane & 15, quad = lane >> 4;
  f32x4 zero = {0.f, 0.f, 0.f, 0.f};
  f32x4 acc[4][4];
#pragma unroll
  for (int mt = 0; mt < 4; mt++)
#pragma unroll
    for (int nt = 0; nt < 4; nt++) acc[mt][nt] = zero;

  for (int kt = 0; kt < 128; kt += 32) {
#pragma unroll
    for (int q = 0; q < 4; q++) {
      int f = q * 256 + tid;
      int row = f >> 3, ch = f & 7;
      float4 av = *(const float4*)&A[(size_t)(bm + row) * 128 + kt + ch * 4];
      float4 wv = *(const float4*)&Wt[(size_t)row * 128 + kt + ch * 4];
      float aa[4] = {av.x, av.y, av.z, av.w};
      float ww[4] = {wv.x, wv.y, wv.z, wv.w};
      unsigned short ahs[4], als[4], whs[4], wls[4];
#pragma unroll
      for (int c = 0; c < 4; c++) {
        ahs[c] = f2bf(aa[c]); als[c] = f2bf(aa[c] - bf2f(ahs[c]));
        whs[c] = f2bf(ww[c]); wls[c] = f2bf(ww[c] - bf2f(whs[c]));
      }
      int ls = row * PAD + ch * 4;
      uint2 pah = {(unsigned)ahs[0] | ((unsigned)ahs[1] << 16), (unsigned)ahs[2] | ((unsigned)ahs[3] << 16)};
      uint2 pal = {(unsigned)als[0] | ((unsigned)als[1] << 16), (unsigned)als[2] | ((unsigned)als[3] << 16)};
      uint2 pwh = {(unsigned)whs[0] | ((unsigned)whs[1] << 16), (unsigned)whs[2] | ((unsigned)whs[3] << 16)};
      uint2 pwl = {(unsigned)wls[0] | ((unsigned)wls[1] << 16), (unsigned)wls[2] | ((unsigned)wls[3] << 16)};
      *(uint2*)&sAh[ls] = pah; *(uint2*)&sAl[ls] = pal;
      *(uint2*)&sWh[ls] = pwh; *(uint2*)&sWl[ls] = pwl;
    }
    __syncthreads();
    bf16x8 ah[4], al[4], bh[4], bl[4];
#pragma unroll
    for (int t = 0; t < 4; t++) {
      int ar = (wm + t * 16 + l15) * PAD + quad * 8;
      ah[t] = *(const bf16x8*)&sAh[ar];
      al[t] = *(const bf16x8*)&sAl[ar];
      int br = (wn + t * 16 + l15) * PAD + quad * 8;
      bh[t] = *(const bf16x8*)&sWh[br];
      bl[t] = *(const bf16x8*)&sWl[br];
    }
#pragma unroll
    for (int mt = 0; mt < 4; mt++)
#pragma unroll
      for (int nt = 0; nt < 4; nt++) {
        acc[mt][nt] = __builtin_amdgcn_mfma_f32_16x16x32_bf16(ah[mt], bh[nt], acc[mt][nt], 0, 0, 0);
        acc[mt][nt] = __builtin_amdgcn_mfma_f32_16x16x32_bf16(ah[mt], bl[nt], acc[mt][nt], 0, 0, 0);
        acc[mt][nt] = __builtin_amdgcn_mfma_f32_16x16x32_bf16(al[mt], bh[nt], acc[mt][nt], 0, 0, 0);
      }
    __syncthreads();
  }
  float bv[4];
#pragma unroll
  for (int nt = 0; nt < 4; nt++) bv[nt] = bias[wn + nt * 16 + l15];
#pragma unroll
  for (int mt = 0; mt < 4; mt++)
#pragma unroll
    for (int nt = 0; nt < 4; nt++) {
      int col = wn + nt * 16 + l15;
#pragma unroll
      for (int rg = 0; rg < 4; rg++) {
        int row = bm + wm + mt * 16 + quad * 4 + rg;
        size_t off = (size_t)row * 128 + col;
        float v = acc[mt][nt][rg] + bv[nt];
        if (EPI == 0) out[off] = v;
        else if (EPI == 1) out[off] = lrelu(v);
        else if (EPI == 2) out[off] += lrelu(v);
        else out[off] = aux[off] - v;
      }
    }
}

// ---------------- row top-k: approx top-5 from S, exact fp32 rescore ----------
__global__ __launch_bounds__(256) void k_rowtop(
    const float* __restrict__ S, const float* __restrict__ hhat,
    float* __restrict__ mtv, int* __restrict__ mtj) {
  int i = blockIdx.x * 4 + (threadIdx.x >> 6);
  int lane = threadIdx.x & 63;
  const float* row = &S[(size_t)i * N];
  float v[5] = {-3e38f, -3e38f, -3e38f, -3e38f, -3e38f};
  int jx[5] = {0x7fffffff, 0x7fffffff, 0x7fffffff, 0x7fffffff, 0x7fffffff};
  for (int t = 0; t < 64; t++) {
    int j = t * 64 + lane;
    ins5(row[j], j, v, jx);
  }
#pragma unroll
  for (int d = 1; d < 64; d <<= 1) {
    float fv[5]; int fj[5];
#pragma unroll
    for (int c = 0; c < 5; c++) { fv[c] = __shfl_xor(v[c], d); fj[c] = __shfl_xor(jx[c], d); }
#pragma unroll
    for (int c = 0; c < 5; c++) ins5(fv[c], fj[c], v, jx);
  }
  const float* hi = &hhat[(size_t)i * H];
  float b0 = -3e38f, b1 = -3e38f, b2 = -3e38f;
  int q0 = 0, q1 = 0, q2 = 0;
#pragma unroll
  for (int c = 0; c < 5; c++) {
    int j = jx[c];
    float s;
    if (j == i) {
      s = 0.f;
    } else {
      const float* hj = &hhat[(size_t)j * H];
      float p = hi[lane] * hj[lane] + hi[lane + 64] * hj[lane + 64];
      s = wave_reduce_sum(p);
    }
    top3_ins(s, j, b0, q0, b1, q1, b2, q2);
  }
  if (lane == 0) {
    mtv[i * 3 + 0] = b0; mtv[i * 3 + 1] = b1; mtv[i * 3 + 2] = b2;
    mtj[i * 3 + 0] = q0; mtj[i * 3 + 1] = q1; mtj[i * 3 + 2] = q2;
  }
}

__global__ __launch_bounds__(256) void k_scatter(
    const float* __restrict__ mtv, const int* __restrict__ mtj,
    const float* __restrict__ h, float* __restrict__ hidden2,
    float* __restrict__ colsum_m) {
  int i = blockIdx.x * 4 + (threadIdx.x >> 6);
  int lane = threadIdx.x & 63;
  float h0 = h[(size_t)i * H + lane], h1 = h[(size_t)i * H + 64 + lane];
#pragma unroll
  for (int s = 0; s < 3; s++) {
    float v = mtv[i * 3 + s];
    int j = mtj[i * 3 + s];
    atomicAdd(&hidden2[(size_t)j * H + lane], v * h0);
    atomicAdd(&hidden2[(size_t)j * H + 64 + lane], v * h1);
    if (lane == s) atomicAdd(&colsum_m[j], v);
  }
}

// ---------------- split-K GEMM with generated A^T (ps staging GEMMs) ----------
template <int AMODE>
__global__ __launch_bounds__(256) void k_gemm_genA(
    const float* __restrict__ P, const float* __restrict__ mv,
    const float* __restrict__ col1, const float* __restrict__ col2,
    const float* __restrict__ B, float* __restrict__ partial, int KC) {
  __shared__ float Ps[32][68];
  __shared__ float Bs[32][68];
  int tid = threadIdx.x;
  int tx = tid & 15, ty = tid >> 4;
  int bm = blockIdx.y * 64, bn = blockIdx.x * 64;
  int k0 = blockIdx.z * KC;
  float acc[4][4];
#pragma unroll
  for (int r = 0; r < 4; r++)
#pragma unroll
    for (int c = 0; c < 4; c++) acc[r][c] = 0.f;
  for (int kt = 0; kt < KC; kt += 32) {
#pragma unroll
    for (int q = 0; q < 2; q++) {
      int f = q * 256 + tid;
      int kr = f >> 4, nq = f & 15;
      int k = k0 + kt + kr;
      float4 pv = *(const float4*)&P[(size_t)k * C + bm + nq * 4];
      float4 av;
      if (AMODE == 1) {
        float m = mv[k];
        float4 cs = *(const float4*)&col1[bm + nq * 4];
        av.x = pv.x * m / (cs.x * pv.x + 1.f);
        av.y = pv.y * m / (cs.y * pv.y + 1.f);
        av.z = pv.z * m / (cs.z * pv.z + 1.f);
        av.w = pv.w * m / (cs.w * pv.w + 1.f);
      } else {
        float4 cm_ = *(const float4*)&col1[bm + nq * 4];
        float4 cd = *(const float4*)&col2[bm + nq * 4];
        av.x = __expf(pv.x - cm_.x) / cd.x;
        av.y = __expf(pv.y - cm_.y) / cd.y;
        av.z = __expf(pv.z - cm_.z) / cd.z;
        av.w = __expf(pv.w - cm_.w) / cd.w;
      }
      *(float4*)&Ps[kr][nq * 4] = av;
      float4 bv = *(const float4*)&B[(size_t)k * 128 + bn + nq * 4];
      *(float4*)&Bs[kr][nq * 4] = bv;
    }
    __syncthreads();
#pragma unroll
    for (int kk = 0; kk < 32; kk++) {
      float4 fa = *(float4*)&Ps[kk][ty * 4];
      float4 fb = *(float4*)&Bs[kk][tx * 4];
      float am[4] = {fa.x, fa.y, fa.z, fa.w};
      float bb[4] = {fb.x, fb.y, fb.z, fb.w};
#pragma unroll
      for (int r = 0; r < 4; r++)
#pragma unroll
        for (int c = 0; c < 4; c++) acc[r][c] += am[r] * bb[c];
    }
    __syncthreads();
  }
  float* pp = partial + (size_t)blockIdx.z * C * 128;
#pragma unroll
  for (int r = 0; r < 4; r++) {
    float4 v = {acc[r][0], acc[r][1], acc[r][2], acc[r][3]};
    *(float4*)&pp[(size_t)(bm + ty * 4 + r) * 128 + bn + tx * 4] = v;
  }
}

// reduce split-K partials; optional per-row (128-wide) scale
__global__ __launch_bounds__(256) void k_reduce(
    const float* __restrict__ partial, float* __restrict__ out, int cnt,
    size_t slot, size_t size4, const float* __restrict__ scalem) {
  size_t idx = (size_t)blockIdx.x * 256 + threadIdx.x;
  if (idx >= size4) return;
  float4 s = {0, 0, 0, 0};
  for (int c = 0; c < cnt; c++) {
    float4 v = *(const float4*)&partial[c * slot + idx * 4];
    s.x += v.x; s.y += v.y; s.z += v.z; s.w += v.w;
  }
  if (scalem) {
    float sc = scalem[idx >> 5];
    s.x *= sc; s.y *= sc; s.z *= sc; s.w *= sc;
  }
  *(float4*)&out[idx * 4] = s;
}

// ---------------- launch ----------------

extern "C" void kernel_launch(void* const* d_in, const int* in_sizes, int n_in,
                              void* d_out, int out_size, void* d_ws, size_t ws_size,
                              hipStream_t stream) {
  (void)in_sizes; (void)n_in; (void)out_size;
  const float* x   = (const float*)d_in[0];
  const float* cm  = (const float*)d_in[1];
  const float* mv  = (const float*)d_in[2];
  const float* W_ps = (const float*)d_in[3],  *b_ps = (const float*)d_in[4];
  const float* W_psf = (const float*)d_in[5], *b_psf = (const float*)d_in[6];
  const float* W_psb = (const float*)d_in[7], *b_psb = (const float*)d_in[8];
  const float* W_hs = (const float*)d_in[9],  *b_hs = (const float*)d_in[10];
  const float* W_hsf = (const float*)d_in[11], *b_hsf = (const float*)d_in[12];
  const float* W_hsb = (const float*)d_in[13], *b_hsb = (const float*)d_in[14];
  const float* W_in = (const float*)d_in[15], *b_in = (const float*)d_in[16];
  const float* W_out = (const float*)d_in[17], *b_out = (const float*)d_in[18];
  float* out = (float*)d_out;

  float* W = (float*)d_ws;
  size_t o = 0;
  auto alloc = [&](size_t n) { float* p = W + o; o += n; return p; };
  float* colsum_c = alloc(C);
  float* colmax   = alloc(C);
  float* colsumexp= alloc(C);
  float* valid1   = alloc(C);
  float* hnorm_ps = alloc(C);
  float* xnorm    = alloc(N);
  float* diagv    = alloc(N);
  float* colsum_m = alloc(N);
  float* valid2f  = alloc(N);
  float* lsum     = alloc(N);
  float* linv     = alloc(N);
  float* mtv      = alloc(3 * N);
  int*   mtj      = (int*)alloc(3 * N);
  float* hidden1  = alloc((size_t)C * H);
  float* hidden_ps= alloc((size_t)C * H);
  float* scores   = alloc((size_t)N * C);
  float* ps_pre   = alloc((size_t)N * H);   // later hs_pre
  float* p_shared = alloc((size_t)N * H);   // later h_shared
  float* all_info = alloc((size_t)N * H);
  float* hbuf     = alloc((size_t)N * H);   // h; later indiv (in-place)
  float* hhat     = alloc((size_t)N * H);
  float* hidden2  = alloc((size_t)N * H);
  float* h2hat    = alloc((size_t)N * H);
  unsigned short* xhi    = (unsigned short*)alloc((size_t)N * H / 2);
  unsigned short* xlo    = (unsigned short*)alloc((size_t)N * H / 2);
  unsigned short* hhathi = (unsigned short*)alloc((size_t)N * H / 2);
  unsigned short* hhatlo = (unsigned short*)alloc((size_t)N * H / 2);
  unsigned short* h2hi   = (unsigned short*)alloc((size_t)N * H / 2);
  unsigned short* h2lo   = (unsigned short*)alloc((size_t)N * H / 2);
  unsigned short* h1hi   = (unsigned short*)alloc((size_t)C * H / 2);
  unsigned short* h1lo   = (unsigned short*)alloc((size_t)C * H / 2);
  unsigned short* hpshi  = (unsigned short*)alloc((size_t)C * H / 2);
  unsigned short* hpslo  = (unsigned short*)alloc((size_t)C * H / 2);
  unsigned short* cshi   = (unsigned short*)alloc((size_t)N * C / 2);
  unsigned short* cslo   = (unsigned short*)alloc((size_t)N * C / 2);
  unsigned short* hpst_hi= (unsigned short*)alloc((size_t)H * C / 2);
  unsigned short* hpst_lo= (unsigned short*)alloc((size_t)H * C / 2);
  unsigned short* h2t_hi = (unsigned short*)alloc((size_t)H * N / 2);
  unsigned short* h2t_lo = (unsigned short*)alloc((size_t)H * N / 2);
  float* Sbuf     = alloc((size_t)N * N);   // 64 MB; reused as E pairs
  unsigned short* Ehi = (unsigned short*)Sbuf;
  unsigned short* Elo = Ehi + (size_t)N * N;
  float* partial  = W + o;
  size_t rem = ws_size / 4 - o;
  int Z = (rem >= (size_t)16 * N * H) ? 16 : 8;
  int KC = 4096 / Z;

  hipMemsetAsync(colsum_c, 0, C * sizeof(float), stream);
  hipMemsetAsync(colsum_m, 0, N * sizeof(float), stream);
  hipMemsetAsync(lsum, 0, N * sizeof(float), stream);
  hipMemsetAsync(hidden2, 0, (size_t)N * H * sizeof(float), stream);

  dim3 blk(256);
  // --- ps branch ---
  k_split<<<dim3(N * H / 1024), blk, 0, stream>>>(x, xhi, xlo);
  k_colsum_s2c<<<dim3(C / 64, 16), dim3(64), 0, stream>>>(cm, mv, colsum_c);
  k_gemm_genA<1><<<dim3(2, C / 64, 16), blk, 0, stream>>>(
      cm, mv, colsum_c, nullptr, x, partial, N / 16);
  k_reduce<<<dim3(C * H / 4 / 256), blk, 0, stream>>>(
      partial, hidden1, 16, (size_t)C * H, (size_t)C * H / 4, nullptr);
  k_valid1<<<dim3(C), dim3(64), 0, stream>>>(hidden1, valid1);
  k_split<<<dim3(C * H / 1024), blk, 0, stream>>>(hidden1, h1hi, h1lo);
  k_mfma_nt<0><<<dim3(C / 128, N / 128), blk, 0, stream>>>(
      xhi, xlo, h1hi, h1lo, nullptr, scores, nullptr, nullptr, nullptr, C);
  k_colstats<<<dim3(C), blk, 0, stream>>>(scores, colmax, colsumexp);
  k_gemm_genA<2><<<dim3(2, C / 64, 16), blk, 0, stream>>>(
      scores, nullptr, colmax, colsumexp, x, partial, N / 16);
  k_reduce<<<dim3(C * H / 4 / 256), blk, 0, stream>>>(
      partial, hidden_ps, 16, (size_t)C * H, (size_t)C * H / 4, valid1);
  k_rownorm128<<<dim3(N), dim3(64), 0, stream>>>(x, xnorm);
  k_rownorm128<<<dim3(C), dim3(64), 0, stream>>>(hidden_ps, hnorm_ps);
  k_split<<<dim3(C * H / 1024), blk, 0, stream>>>(hidden_ps, hpshi, hpslo);
  k_mfma_nt<0><<<dim3(C / 128, N / 128), blk, 0, stream>>>(
      xhi, xlo, hpshi, hpslo, nullptr, scores, nullptr, nullptr, nullptr, C);
  k_cs_softmax<<<dim3(N), blk, 0, stream>>>(scores, xnorm, hnorm_ps, valid1,
                                            cshi, cslo);
  k_tsplit<<<dim3(C / 32), blk, 0, stream>>>(hidden_ps, hpst_hi, hpst_lo, C);
  k_mfma_kn<<<dim3(1, N / 128, 4), blk, 0, stream>>>(
      cshi, cslo, hpst_hi, hpst_lo, partial, C, C / 4);
  k_reduce<<<dim3(N * H / 4 / 256), blk, 0, stream>>>(
      partial, ps_pre, 4, (size_t)N * H, (size_t)N * H / 4, nullptr);
  k_mfma_lin<0><<<dim3(1, N / 128), blk, 0, stream>>>(
      ps_pre, W_ps, b_ps, nullptr, p_shared);
  k_mfma_lin<3><<<dim3(1, N / 128), blk, 0, stream>>>(
      p_shared, W_psb, b_psb, x, hbuf);                      // h = x - p_back
  k_mfma_lin<1><<<dim3(1, N / 128), blk, 0, stream>>>(
      p_shared, W_psf, b_psf, nullptr, all_info);            // out_ps
  // --- hs branch ---
  k_hhat<<<dim3(N), dim3(64), 0, stream>>>(hbuf, hhat, diagv);
  k_split<<<dim3(N * H / 1024), blk, 0, stream>>>(hhat, hhathi, hhatlo);
  k_mfma_nt<2><<<dim3(N / 128, N / 128), blk, 0, stream>>>(
      hhathi, hhatlo, hhathi, hhatlo, nullptr, Sbuf, nullptr, nullptr, nullptr, N);
  k_rowtop<<<dim3(N / 4), blk, 0, stream>>>(Sbuf, hhat, mtv, mtj);
  k_scatter<<<dim3(N / 4), blk, 0, stream>>>(mtv, mtj, hbuf, hidden2, colsum_m);
  k_fin_hidden2<<<dim3(N), dim3(64), 0, stream>>>(hbuf, diagv, colsum_m, hidden2,
                                                  h2hat, valid2f);
  k_split<<<dim3(N * H / 1024), blk, 0, stream>>>(h2hat, h2hi, h2lo);
  k_mfma_nt<3><<<dim3(N / 128, N / 128), blk, 0, stream>>>(
      hhathi, hhatlo, h2hi, h2lo, valid2f, nullptr, Ehi, Elo, lsum, N);
  k_recip<<<dim3(N / 256), blk, 0, stream>>>(lsum, linv);
  k_tsplit<<<dim3(N / 32), blk, 0, stream>>>(hidden2, h2t_hi, h2t_lo, N);
  k_mfma_kn<<<dim3(1, N / 128, Z), blk, 0, stream>>>(
      Ehi, Elo, h2t_hi, h2t_lo, partial, N, KC);
  k_reduce<<<dim3(N * H / 4 / 256), blk, 0, stream>>>(
      partial, ps_pre, Z, (size_t)N * H, (size_t)N * H / 4, linv);  // hs_pre
  k_mfma_lin<0><<<dim3(1, N / 128), blk, 0, stream>>>(
      ps_pre, W_hs, b_hs, nullptr, p_shared);                // h_shared
  k_mfma_lin<2><<<dim3(1, N / 128), blk, 0, stream>>>(
      p_shared, W_hsf, b_hsf, nullptr, all_info);            // += out_hs
  k_mfma_lin<3><<<dim3(1, N / 128), blk, 0, stream>>>(
      p_shared, W_hsb, b_hsb, hbuf, hbuf);                   // indiv = h - h_back
  k_mfma_lin<2><<<dim3(1, N / 128), blk, 0, stream>>>(
      hbuf, W_in, b_in, nullptr, all_info);                  // += out_indi
  k_final<<<dim3(N), dim3(64), 0, stream>>>(all_info, W_out, b_out, out);
}

// Round 8
// 436.813 us; speedup vs baseline: 5.7658x; 1.0565x over previous
//
#include <hip/hip_runtime.h>
#include <hip/hip_fp16.h>
#include <math.h>

#define N 4096
#define C 512
#define H 128
#define PAD 40  // ushort row pitch for MFMA LDS tiles (80 B: 16B-aligned, 2-way banks)

typedef __attribute__((ext_vector_type(8))) short bf16x8;
typedef __attribute__((ext_vector_type(4))) float f32x4;

// ---------------- helpers ----------------

__device__ inline float wave_reduce_sum(float v) {
#pragma unroll
  for (int m = 32; m; m >>= 1) v += __shfl_xor(v, m);
  return v;
}

__device__ inline float lrelu(float v) { return v > 0.f ? v : 0.01f * v; }

__device__ inline bool better(float v, int j, float w, int k) {
  return (v > w) || (v == w && j < k);
}

__device__ inline void top3_ins(float v, int j, float& v0, int& j0,
                                float& v1, int& j1, float& v2, int& j2) {
  if (better(v, j, v0, j0)) { v2 = v1; j2 = j1; v1 = v0; j1 = j0; v0 = v; j0 = j; }
  else if (better(v, j, v1, j1)) { v2 = v1; j2 = j1; v1 = v; j1 = j; }
  else if (better(v, j, v2, j2)) { v2 = v; j2 = j; }
}

__device__ inline void ins5(float s, int j, float v[5], int jx[5]) {
  if (!better(s, j, v[4], jx[4])) return;
  if (better(s, j, v[0], jx[0])) {
    v[4]=v[3]; jx[4]=jx[3]; v[3]=v[2]; jx[3]=jx[2]; v[2]=v[1]; jx[2]=jx[1];
    v[1]=v[0]; jx[1]=jx[0]; v[0]=s; jx[0]=j;
  } else if (better(s, j, v[1], jx[1])) {
    v[4]=v[3]; jx[4]=jx[3]; v[3]=v[2]; jx[3]=jx[2]; v[2]=v[1]; jx[2]=jx[1];
    v[1]=s; jx[1]=j;
  } else if (better(s, j, v[2], jx[2])) {
    v[4]=v[3]; jx[4]=jx[3]; v[3]=v[2]; jx[3]=jx[2]; v[2]=s; jx[2]=j;
  } else if (better(s, j, v[3], jx[3])) {
    v[4]=v[3]; jx[4]=jx[3]; v[3]=s; jx[3]=j;
  } else {
    v[4]=s; jx[4]=j;
  }
}

__device__ inline unsigned short f2bf(float f) {
  unsigned u = __float_as_uint(f);
  unsigned r = u + 0x7fffu + ((u >> 16) & 1u);
  return (unsigned short)(r >> 16);
}
__device__ inline float bf2f(unsigned short h) {
  return __uint_as_float(((unsigned)h) << 16);
}

// ---------------- split fp32 -> bf16 hi/lo ----------------
__global__ __launch_bounds__(256) void k_split(const float* __restrict__ in,
                                               unsigned short* __restrict__ hi,
                                               unsigned short* __restrict__ lo) {
  int idx = (blockIdx.x * 256 + threadIdx.x) * 4;
  float4 v = *(const float4*)&in[idx];
  float vv[4] = {v.x, v.y, v.z, v.w};
  unsigned short h[4], l[4];
#pragma unroll
  for (int c = 0; c < 4; c++) {
    h[c] = f2bf(vv[c]);
    l[c] = f2bf(vv[c] - bf2f(h[c]));
  }
  uint2 ph = {(unsigned)h[0] | ((unsigned)h[1] << 16),
              (unsigned)h[2] | ((unsigned)h[3] << 16)};
  uint2 pl = {(unsigned)l[0] | ((unsigned)l[1] << 16),
              (unsigned)l[2] | ((unsigned)l[3] << 16)};
  *(uint2*)&hi[idx] = ph;
  *(uint2*)&lo[idx] = pl;
}

// transpose + split: in [R,128] fp32 -> thi/tlo [128,R] ushort
__global__ __launch_bounds__(256) void k_tsplit(const float* __restrict__ in,
                                                unsigned short* __restrict__ thi,
                                                unsigned short* __restrict__ tlo,
                                                int R) {
  __shared__ float tile[32][132];
  int r0 = blockIdx.x * 32, tid = threadIdx.x;
#pragma unroll
  for (int q = 0; q < 4; q++) {
    int f = q * 256 + tid;
    int row = f >> 5, ch = f & 31;  // 32 rows x 32 float4-chunks
    *(float4*)&tile[row][ch * 4] = *(const float4*)&in[(size_t)(r0 + row) * 128 + ch * 4];
  }
  __syncthreads();
  int c = tid & 127, half = tid >> 7;
  unsigned short hh[16], ll[16];
#pragma unroll
  for (int rr = 0; rr < 16; rr++) {
    float v = tile[half * 16 + rr][c];
    hh[rr] = f2bf(v);
    ll[rr] = f2bf(v - bf2f(hh[rr]));
  }
  size_t off = (size_t)c * R + r0 + half * 16;
  uint4 ph0 = {(unsigned)hh[0] | ((unsigned)hh[1] << 16), (unsigned)hh[2] | ((unsigned)hh[3] << 16),
               (unsigned)hh[4] | ((unsigned)hh[5] << 16), (unsigned)hh[6] | ((unsigned)hh[7] << 16)};
  uint4 ph1 = {(unsigned)hh[8] | ((unsigned)hh[9] << 16), (unsigned)hh[10] | ((unsigned)hh[11] << 16),
               (unsigned)hh[12] | ((unsigned)hh[13] << 16), (unsigned)hh[14] | ((unsigned)hh[15] << 16)};
  uint4 pl0 = {(unsigned)ll[0] | ((unsigned)ll[1] << 16), (unsigned)ll[2] | ((unsigned)ll[3] << 16),
               (unsigned)ll[4] | ((unsigned)ll[5] << 16), (unsigned)ll[6] | ((unsigned)ll[7] << 16)};
  uint4 pl1 = {(unsigned)ll[8] | ((unsigned)ll[9] << 16), (unsigned)ll[10] | ((unsigned)ll[11] << 16),
               (unsigned)ll[12] | ((unsigned)ll[13] << 16), (unsigned)ll[14] | ((unsigned)ll[15] << 16)};
  *(uint4*)&thi[off] = ph0; *(uint4*)&thi[off + 8] = ph1;
  *(uint4*)&tlo[off] = pl0; *(uint4*)&tlo[off + 8] = pl1;
}

// ---------------- small kernels ----------------

__global__ __launch_bounds__(64) void k_colsum_s2c(
    const float* __restrict__ cm, const float* __restrict__ mv,
    float* __restrict__ colsum_c) {
  int c = blockIdx.x * 64 + threadIdx.x;
  int i0 = blockIdx.y * 256;
  float acc = 0.f;
  for (int i = i0; i < i0 + 256; i++) acc += cm[(size_t)i * C + c] * mv[i];
  atomicAdd(&colsum_c[c], acc);
}

__global__ __launch_bounds__(64) void k_valid1(const float* __restrict__ hid,
                                               float* __restrict__ valid1) {
  int c = blockIdx.x, t = threadIdx.x;
  float s = hid[(size_t)c * H + t] + hid[(size_t)c * H + 64 + t];
  s = wave_reduce_sum(s);
  if (t == 0) valid1[c] = (s != 0.f) ? 1.f : 0.f;
}

__global__ __launch_bounds__(64) void k_rownorm128(const float* __restrict__ A,
                                                   float* __restrict__ nrm) {
  int r = blockIdx.x, t = threadIdx.x;
  float a = A[(size_t)r * H + t], b = A[(size_t)r * H + 64 + t];
  float ss = wave_reduce_sum(a * a + b * b);
  if (t == 0) nrm[r] = sqrtf(ss);
}

__global__ __launch_bounds__(256) void k_colstats(const float* __restrict__ sc,
                                                  float* __restrict__ colmax,
                                                  float* __restrict__ colsum) {
  __shared__ float red[256];
  int c = blockIdx.x, t = threadIdx.x;
  float v[16];
  float m = -3e38f;
#pragma unroll
  for (int q = 0; q < 16; q++) {
    v[q] = sc[(size_t)(q * 256 + t) * C + c];
    m = fmaxf(m, v[q]);
  }
  red[t] = m; __syncthreads();
  for (int s = 128; s; s >>= 1) { if (t < s) red[t] = fmaxf(red[t], red[t + s]); __syncthreads(); }
  m = red[0]; __syncthreads();
  float sum = 0.f;
#pragma unroll
  for (int q = 0; q < 16; q++) sum += __expf(v[q] - m);
  red[t] = sum; __syncthreads();
  for (int s = 128; s; s >>= 1) { if (t < s) red[t] += red[t + s]; __syncthreads(); }
  if (t == 0) { colmax[c] = m; colsum[c] = red[0]; }
}

// row softmax of cos-sim -> bf16 hi/lo pairs
__global__ __launch_bounds__(256) void k_cs_softmax(
    const float* __restrict__ sc, const float* __restrict__ xnorm,
    const float* __restrict__ hnorm, const float* __restrict__ valid1,
    unsigned short* __restrict__ cshi, unsigned short* __restrict__ cslo) {
  __shared__ float red[256];
  int i = blockIdx.x, t = threadIdx.x;
  float xn = xnorm[i];
  float r0 = sc[(size_t)i * C + t], r1 = sc[(size_t)i * C + 256 + t];
  float d0 = xn * hnorm[t], d1 = xn * hnorm[256 + t];
  float c0 = r0 / (d0 == 0.f ? 1.f : d0);
  float c1 = r1 / (d1 == 0.f ? 1.f : d1);
  float s0 = (valid1[t] != 0.f) ? c0 : -3e38f;
  float s1 = (valid1[256 + t] != 0.f) ? c1 : -3e38f;
  red[t] = fmaxf(s0, s1); __syncthreads();
  for (int s = 128; s; s >>= 1) { if (t < s) red[t] = fmaxf(red[t], red[t + s]); __syncthreads(); }
  float m = red[0]; __syncthreads();
  float p0 = (s0 > -1e37f) ? __expf(s0 - m) : 0.f;
  float p1 = (s1 > -1e37f) ? __expf(s1 - m) : 0.f;
  red[t] = p0 + p1; __syncthreads();
  for (int s = 128; s; s >>= 1) { if (t < s) red[t] += red[t + s]; __syncthreads(); }
  float inv = 1.f / red[0];
  float a = p0 * inv, b = p1 * inv;
  unsigned short ha = f2bf(a), hb = f2bf(b);
  cshi[(size_t)i * C + t] = ha;
  cslo[(size_t)i * C + t] = f2bf(a - bf2f(ha));
  cshi[(size_t)i * C + 256 + t] = hb;
  cslo[(size_t)i * C + 256 + t] = f2bf(b - bf2f(hb));
}

__global__ __launch_bounds__(64) void k_hhat(const float* __restrict__ h,
                                             float* __restrict__ hhat,
                                             float* __restrict__ diagv) {
  int i = blockIdx.x, t = threadIdx.x;
  float a = h[(size_t)i * H + t], b = h[(size_t)i * H + 64 + t];
  float ss = wave_reduce_sum(a * a + b * b);
  float hn = sqrtf(ss);
  float den = hn * hn;
  float dg = (den == 0.f) ? 0.f : ss / den;
  float inv = (ss > 0.f) ? (1.f / hn) : 1.f;
  hhat[(size_t)i * H + t] = a * inv;
  hhat[(size_t)i * H + 64 + t] = b * inv;
  if (t == 0) diagv[i] = dg;
}

__global__ __launch_bounds__(64) void k_fin_hidden2(
    const float* __restrict__ h, const float* __restrict__ diagv,
    const float* __restrict__ colsum_m, float* __restrict__ hidden2,
    float* __restrict__ h2hat, float* __restrict__ valid2f) {
  int j = blockIdx.x, t = threadIdx.x;
  float add = (colsum_m[j] != 0.f) ? diagv[j] : 0.f;
  float a = hidden2[(size_t)j * H + t] + add * h[(size_t)j * H + t];
  float b = hidden2[(size_t)j * H + 64 + t] + add * h[(size_t)j * H + 64 + t];
  float s = a + b, ss = a * a + b * b;
#pragma unroll
  for (int m = 32; m; m >>= 1) { s += __shfl_xor(s, m); ss += __shfl_xor(ss, m); }
  bool valid = (s != 0.f);
  a = valid ? a : 0.f; b = valid ? b : 0.f;
  hidden2[(size_t)j * H + t] = a;
  hidden2[(size_t)j * H + 64 + t] = b;
  float inv = (valid && ss > 0.f) ? (1.f / sqrtf(ss)) : 1.f;
  h2hat[(size_t)j * H + t] = a * inv;
  h2hat[(size_t)j * H + 64 + t] = b * inv;
  if (t == 0) valid2f[j] = valid ? 1.f : 0.f;
}

__global__ __launch_bounds__(256) void k_recip(const float* __restrict__ in,
                                               float* __restrict__ outv) {
  int i = blockIdx.x * 256 + threadIdx.x;
  outv[i] = 1.f / in[i];
}

__global__ __launch_bounds__(64) void k_final(const float* __restrict__ ai,
                                              const float* __restrict__ Wout,
                                              const float* __restrict__ bout,
                                              float* __restrict__ out) {
  int i = blockIdx.x, t = threadIdx.x;
  float s = ai[(size_t)i * H + t] * Wout[t] + ai[(size_t)i * H + 64 + t] * Wout[64 + t];
  s = wave_reduce_sum(s);
  if (t == 0) out[i] = s + bout[0];
}

// ---------------- bf16x3 MFMA NT GEMM: A[M,128] @ B[Nn,128]^T ----------------
// EPI 0: fp32 store; 2: diag-zeroed fp16 store into sh; 3: E=exp(s-1) masked
// -> bf16 pairs (ehi/elo) + per-row sum atomics into lsum
template <int EPI>
__global__ __launch_bounds__(256) void k_mfma_nt(
    const unsigned short* __restrict__ Ahi, const unsigned short* __restrict__ Alo,
    const unsigned short* __restrict__ Bhi, const unsigned short* __restrict__ Blo,
    const float* __restrict__ validn, float* __restrict__ out,
    unsigned short* __restrict__ ehi, unsigned short* __restrict__ elo,
    float* __restrict__ lsum, int Nn) {
  __shared__ __align__(16) unsigned short sAh[128 * PAD];
  __shared__ __align__(16) unsigned short sAl[128 * PAD];
  __shared__ __align__(16) unsigned short sBh[128 * PAD];
  __shared__ __align__(16) unsigned short sBl[128 * PAD];
  int tid = threadIdx.x;
  int bm = blockIdx.y * 128, bn = blockIdx.x * 128;
  int lane = tid & 63, w = tid >> 6;
  int wm = (w & 1) * 64, wn = (w >> 1) * 64;
  int l15 = lane & 15, quad = lane >> 4;
  f32x4 zero = {0.f, 0.f, 0.f, 0.f};
  f32x4 acc[4][4];
#pragma unroll
  for (int mt = 0; mt < 4; mt++)
#pragma unroll
    for (int nt = 0; nt < 4; nt++) acc[mt][nt] = zero;

  for (int kt = 0; kt < 128; kt += 32) {
#pragma unroll
    for (int q = 0; q < 2; q++) {
      int f = tid * 2 + q;
      int row = f >> 2, ch = f & 3;
      size_t ga = (size_t)(bm + row) * 128 + kt + ch * 8;
      size_t gb = (size_t)(bn + row) * 128 + kt + ch * 8;
      int ls = row * PAD + ch * 8;
      *(uint4*)&sAh[ls] = *(const uint4*)&Ahi[ga];
      *(uint4*)&sAl[ls] = *(const uint4*)&Alo[ga];
      *(uint4*)&sBh[ls] = *(const uint4*)&Bhi[gb];
      *(uint4*)&sBl[ls] = *(const uint4*)&Blo[gb];
    }
    __syncthreads();
    bf16x8 ah[4], al[4], bh[4], bl[4];
#pragma unroll
    for (int t = 0; t < 4; t++) {
      int ar = (wm + t * 16 + l15) * PAD + quad * 8;
      ah[t] = *(const bf16x8*)&sAh[ar];
      al[t] = *(const bf16x8*)&sAl[ar];
      int br = (wn + t * 16 + l15) * PAD + quad * 8;
      bh[t] = *(const bf16x8*)&sBh[br];
      bl[t] = *(const bf16x8*)&sBl[br];
    }
#pragma unroll
    for (int mt = 0; mt < 4; mt++)
#pragma unroll
      for (int nt = 0; nt < 4; nt++) {
        acc[mt][nt] = __builtin_amdgcn_mfma_f32_16x16x32_bf16(ah[mt], bh[nt], acc[mt][nt], 0, 0, 0);
        acc[mt][nt] = __builtin_amdgcn_mfma_f32_16x16x32_bf16(ah[mt], bl[nt], acc[mt][nt], 0, 0, 0);
        acc[mt][nt] = __builtin_amdgcn_mfma_f32_16x16x32_bf16(al[mt], bh[nt], acc[mt][nt], 0, 0, 0);
      }
    __syncthreads();
  }
  if (EPI == 3) {
    float vm[4];
#pragma unroll
    for (int nt = 0; nt < 4; nt++) vm[nt] = validn[bn + wn + nt * 16 + l15];
#pragma unroll
    for (int mt = 0; mt < 4; mt++) {
#pragma unroll
      for (int rg = 0; rg < 4; rg++) {
        int row = bm + wm + mt * 16 + quad * 4 + rg;
        float rsum = 0.f;
#pragma unroll
        for (int nt = 0; nt < 4; nt++) {
          int col = bn + wn + nt * 16 + l15;
          float e = (vm[nt] != 0.f) ? __expf(acc[mt][nt][rg] - 1.f) : 0.f;
          rsum += e;
          unsigned short h = f2bf(e);
          ehi[(size_t)row * N + col] = h;
          elo[(size_t)row * N + col] = f2bf(e - bf2f(h));
        }
#pragma unroll
        for (int d = 1; d < 16; d <<= 1) rsum += __shfl_xor(rsum, d);
        if (l15 == 0) atomicAdd(&lsum[row], rsum);
      }
    }
  } else if (EPI == 2) {
#pragma unroll
    for (int mt = 0; mt < 4; mt++) {
#pragma unroll
      for (int nt = 0; nt < 4; nt++) {
        int col = bn + wn + nt * 16 + l15;
#pragma unroll
        for (int rg = 0; rg < 4; rg++) {
          int row = bm + wm + mt * 16 + quad * 4 + rg;
          float v = (row == col) ? 0.f : acc[mt][nt][rg];
          ehi[(size_t)row * N + col] = __half_as_ushort(__float2half(v));
        }
      }
    }
  } else {
#pragma unroll
    for (int mt = 0; mt < 4; mt++) {
#pragma unroll
      for (int nt = 0; nt < 4; nt++) {
        int col = bn + wn + nt * 16 + l15;
#pragma unroll
        for (int rg = 0; rg < 4; rg++) {
          int row = bm + wm + mt * 16 + quad * 4 + rg;
          out[(size_t)row * Nn + col] = acc[mt][nt][rg];
        }
      }
    }
  }
}

// ---------------- bf16x3 MFMA KN GEMM (split-K): partial[z] = A @ B ----------
// A pairs [4096, lda] row-major; Bt pairs [128, lda] (B transposed)
__global__ __launch_bounds__(256) void k_mfma_kn(
    const unsigned short* __restrict__ Ahi, const unsigned short* __restrict__ Alo,
    const unsigned short* __restrict__ Bthi, const unsigned short* __restrict__ Btlo,
    float* __restrict__ partial, int lda, int KC) {
  __shared__ __align__(16) unsigned short sAh[128 * PAD];
  __shared__ __align__(16) unsigned short sAl[128 * PAD];
  __shared__ __align__(16) unsigned short sBh[128 * PAD];
  __shared__ __align__(16) unsigned short sBl[128 * PAD];
  int tid = threadIdx.x;
  int bm = blockIdx.y * 128;
  int k0 = blockIdx.z * KC;
  int lane = tid & 63, w = tid >> 6;
  int wm = (w & 1) * 64, wn = (w >> 1) * 64;
  int l15 = lane & 15, quad = lane >> 4;
  f32x4 zero = {0.f, 0.f, 0.f, 0.f};
  f32x4 acc[4][4];
#pragma unroll
  for (int mt = 0; mt < 4; mt++)
#pragma unroll
    for (int nt = 0; nt < 4; nt++) acc[mt][nt] = zero;

  for (int kt = 0; kt < KC; kt += 32) {
#pragma unroll
    for (int q = 0; q < 2; q++) {
      int f = tid * 2 + q;
      int row = f >> 2, ch = f & 3;
      size_t ga = (size_t)(bm + row) * lda + k0 + kt + ch * 8;
      size_t gb = (size_t)row * lda + k0 + kt + ch * 8;
      int ls = row * PAD + ch * 8;
      *(uint4*)&sAh[ls] = *(const uint4*)&Ahi[ga];
      *(uint4*)&sAl[ls] = *(const uint4*)&Alo[ga];
      *(uint4*)&sBh[ls] = *(const uint4*)&Bthi[gb];
      *(uint4*)&sBl[ls] = *(const uint4*)&Btlo[gb];
    }
    __syncthreads();
    bf16x8 ah[4], al[4], bh[4], bl[4];
#pragma unroll
    for (int t = 0; t < 4; t++) {
      int ar = (wm + t * 16 + l15) * PAD + quad * 8;
      ah[t] = *(const bf16x8*)&sAh[ar];
      al[t] = *(const bf16x8*)&sAl[ar];
      int br = (wn + t * 16 + l15) * PAD + quad * 8;
      bh[t] = *(const bf16x8*)&sBh[br];
      bl[t] = *(const bf16x8*)&sBl[br];
    }
#pragma unroll
    for (int mt = 0; mt < 4; mt++)
#pragma unroll
      for (int nt = 0; nt < 4; nt++) {
        acc[mt][nt] = __builtin_amdgcn_mfma_f32_16x16x32_bf16(ah[mt], bh[nt], acc[mt][nt], 0, 0, 0);
        acc[mt][nt] = __builtin_amdgcn_mfma_f32_16x16x32_bf16(ah[mt], bl[nt], acc[mt][nt], 0, 0, 0);
        acc[mt][nt] = __builtin_amdgcn_mfma_f32_16x16x32_bf16(al[mt], bh[nt], acc[mt][nt], 0, 0, 0);
      }
    __syncthreads();
  }
  float* pp = partial + (size_t)blockIdx.z * N * 128;
#pragma unroll
  for (int mt = 0; mt < 4; mt++)
#pragma unroll
    for (int nt = 0; nt < 4; nt++) {
      int col = wn + nt * 16 + l15;
#pragma unroll
      for (int rg = 0; rg < 4; rg++) {
        int row = bm + wm + mt * 16 + quad * 4 + rg;
        pp[(size_t)row * 128 + col] = acc[mt][nt][rg];
      }
    }
}

// ---------------- bf16x3 MFMA genA GEMM (split-K): partial[z] = a(k,m) @ x[k,n]
// AMODE1: a = P[k,m]*mv[k] / (col1[m]*P[k,m] + 1)   P=concept_matrix [N,C]
// AMODE2: a = exp(P[k,m]-col1[m]) / col2[m]          P=scores [N,C]
// Bt pairs = x^T [128, 4096]. Output rows m (C dim), cols n (H=128).
template <int AMODE>
__global__ __launch_bounds__(256) void k_mfma_genA(
    const float* __restrict__ P, const float* __restrict__ mv,
    const float* __restrict__ col1, const float* __restrict__ col2,
    const unsigned short* __restrict__ Bthi, const unsigned short* __restrict__ Btlo,
    float* __restrict__ partial, int KC) {
  __shared__ __align__(16) unsigned short sAh[128 * PAD];
  __shared__ __align__(16) unsigned short sAl[128 * PAD];
  __shared__ __align__(16) unsigned short sBh[128 * PAD];
  __shared__ __align__(16) unsigned short sBl[128 * PAD];
  int tid = threadIdx.x;
  int bm = blockIdx.y * 128;          // over C
  int k0 = blockIdx.z * KC;           // over N
  int lane = tid & 63, w = tid >> 6;
  int wm = (w & 1) * 64, wn = (w >> 1) * 64;
  int l15 = lane & 15, quad = lane >> 4;
  f32x4 zero = {0.f, 0.f, 0.f, 0.f};
  f32x4 acc[4][4];
#pragma unroll
  for (int mt = 0; mt < 4; mt++)
#pragma unroll
    for (int nt = 0; nt < 4; nt++) acc[mt][nt] = zero;

  for (int kt = 0; kt < KC; kt += 32) {
    // stage A: generate weights from P[k][m], write transposed [m][k]
    int kr = tid >> 3;            // 32 k-rows
    int mc = (tid & 7) * 16;      // 16 m per thread
    int k = k0 + kt + kr;
    float mvk = (AMODE == 1) ? mv[k] : 0.f;
#pragma unroll
    for (int q = 0; q < 4; q++) {
      int m0 = mc + q * 4;
      float4 pv = *(const float4*)&P[(size_t)k * C + bm + m0];
      float4 c1 = *(const float4*)&col1[bm + m0];
      float wv[4];
      if (AMODE == 1) {
        wv[0] = pv.x * mvk / (c1.x * pv.x + 1.f);
        wv[1] = pv.y * mvk / (c1.y * pv.y + 1.f);
        wv[2] = pv.z * mvk / (c1.z * pv.z + 1.f);
        wv[3] = pv.w * mvk / (c1.w * pv.w + 1.f);
      } else {
        float4 c2 = *(const float4*)&col2[bm + m0];
        wv[0] = __expf(pv.x - c1.x) / c2.x;
        wv[1] = __expf(pv.y - c1.y) / c2.y;
        wv[2] = __expf(pv.z - c1.z) / c2.z;
        wv[3] = __expf(pv.w - c1.w) / c2.w;
      }
#pragma unroll
      for (int j = 0; j < 4; j++) {
        unsigned short hh = f2bf(wv[j]);
        sAh[(m0 + j) * PAD + kr] = hh;
        sAl[(m0 + j) * PAD + kr] = f2bf(wv[j] - bf2f(hh));
      }
    }
    // stage B: xt pairs [128, N]
#pragma unroll
    for (int q = 0; q < 2; q++) {
      int f = q * 256 + tid;
      int row = f >> 2, ch = f & 3;
      size_t gb = (size_t)row * N + k0 + kt + ch * 8;
      int ls = row * PAD + ch * 8;
      *(uint4*)&sBh[ls] = *(const uint4*)&Bthi[gb];
      *(uint4*)&sBl[ls] = *(const uint4*)&Btlo[gb];
    }
    __syncthreads();
    bf16x8 ah[4], al[4], bh[4], bl[4];
#pragma unroll
    for (int t = 0; t < 4; t++) {
      int ar = (wm + t * 16 + l15) * PAD + quad * 8;
      ah[t] = *(const bf16x8*)&sAh[ar];
      al[t] = *(const bf16x8*)&sAl[ar];
      int br = (wn + t * 16 + l15) * PAD + quad * 8;
      bh[t] = *(const bf16x8*)&sBh[br];
      bl[t] = *(const bf16x8*)&sBl[br];
    }
#pragma unroll
    for (int mt = 0; mt < 4; mt++)
#pragma unroll
      for (int nt = 0; nt < 4; nt++) {
        acc[mt][nt] = __builtin_amdgcn_mfma_f32_16x16x32_bf16(ah[mt], bh[nt], acc[mt][nt], 0, 0, 0);
        acc[mt][nt] = __builtin_amdgcn_mfma_f32_16x16x32_bf16(ah[mt], bl[nt], acc[mt][nt], 0, 0, 0);
        acc[mt][nt] = __builtin_amdgcn_mfma_f32_16x16x32_bf16(al[mt], bh[nt], acc[mt][nt], 0, 0, 0);
      }
    __syncthreads();
  }
  float* pp = partial + (size_t)blockIdx.z * C * 128;
#pragma unroll
  for (int mt = 0; mt < 4; mt++)
#pragma unroll
    for (int nt = 0; nt < 4; nt++) {
      int col = wn + nt * 16 + l15;
#pragma unroll
      for (int rg = 0; rg < 4; rg++) {
        int row = bm + wm + mt * 16 + quad * 4 + rg;
        pp[(size_t)row * 128 + col] = acc[mt][nt][rg];
      }
    }
}

// ---------------- bf16x3 MFMA linear, 32-row blocks: out = epi(A @ W^T + b) ---
// grid (1, N/32). EPI: 0 store, 1 lrelu, 2 += lrelu, 3 aux - v
template <int EPI>
__global__ __launch_bounds__(256) void k_mfma_lin(
    const float* __restrict__ A, const float* __restrict__ Wt,
    const float* __restrict__ bias, const float* __restrict__ aux,
    float* __restrict__ out) {
  __shared__ __align__(16) unsigned short sAh[32 * PAD];
  __shared__ __align__(16) unsigned short sAl[32 * PAD];
  __shared__ __align__(16) unsigned short sWh[128 * PAD];
  __shared__ __align__(16) unsigned short sWl[128 * PAD];
  int tid = threadIdx.x;
  int bm = blockIdx.y * 32;
  int lane = tid & 63, w = tid >> 6;
  int rt = (w & 1) * 16, ch2 = (w >> 1) * 64;
  int l15 = lane & 15, quad = lane >> 4;
  f32x4 zero = {0.f, 0.f, 0.f, 0.f};
  f32x4 acc[4];
#pragma unroll
  for (int nt = 0; nt < 4; nt++) acc[nt] = zero;

  for (int kt = 0; kt < 128; kt += 32) {
    // stage A: 32 rows x 32 k (256 threads x 1 float4)
    {
      int arow = tid >> 3, ach = tid & 7;
      float4 av = *(const float4*)&A[(size_t)(bm + arow) * 128 + kt + ach * 4];
      float aa[4] = {av.x, av.y, av.z, av.w};
      int ls = arow * PAD + ach * 4;
#pragma unroll
      for (int c = 0; c < 4; c++) {
        unsigned short hh = f2bf(aa[c]);
        sAh[ls + c] = hh;
        sAl[ls + c] = f2bf(aa[c] - bf2f(hh));
      }
    }
    // stage W: 128 rows x 32 k
#pragma unroll
    for (int q = 0; q < 4; q++) {
      int f = q * 256 + tid;
      int wrow = f >> 3, wch = f & 7;
      float4 wv = *(const float4*)&Wt[(size_t)wrow * 128 + kt + wch * 4];
      float ww[4] = {wv.x, wv.y, wv.z, wv.w};
      int ls = wrow * PAD + wch * 4;
#pragma unroll
      for (int c = 0; c < 4; c++) {
        unsigned short hh = f2bf(ww[c]);
        sWh[ls + c] = hh;
        sWl[ls + c] = f2bf(ww[c] - bf2f(hh));
      }
    }
    __syncthreads();
    bf16x8 ah, al, bh[4], bl[4];
    {
      int ar = (rt + l15) * PAD + quad * 8;
      ah = *(const bf16x8*)&sAh[ar];
      al = *(const bf16x8*)&sAl[ar];
    }
#pragma unroll
    for (int nt = 0; nt < 4; nt++) {
      int br = (ch2 + nt * 16 + l15) * PAD + quad * 8;
      bh[nt] = *(const bf16x8*)&sWh[br];
      bl[nt] = *(const bf16x8*)&sWl[br];
    }
#pragma unroll
    for (int nt = 0; nt < 4; nt++) {
      acc[nt] = __builtin_amdgcn_mfma_f32_16x16x32_bf16(ah, bh[nt], acc[nt], 0, 0, 0);
      acc[nt] = __builtin_amdgcn_mfma_f32_16x16x32_bf16(ah, bl[nt], acc[nt], 0, 0, 0);
      acc[nt] = __builtin_amdgcn_mfma_f32_16x16x32_bf16(al, bh[nt], acc[nt], 0, 0, 0);
    }
    __syncthreads();
  }
#pragma unroll
  for (int nt = 0; nt < 4; nt++) {
    int col = ch2 + nt * 16 + l15;
    float bv = bias[col];
#pragma unroll
    for (int rg = 0; rg < 4; rg++) {
      int row = bm + rt + quad * 4 + rg;
      size_t off = (size_t)row * 128 + col;
      float v = acc[nt][rg] + bv;
      if (EPI == 0) out[off] = v;
      else if (EPI == 1) out[off] = lrelu(v);
      else if (EPI == 2) out[off] += lrelu(v);
      else out[off] = aux[off] - v;
    }
  }
}

// ---------------- row top-k: approx top-5 from fp16 S, exact fp32 rescore -----
__global__ __launch_bounds__(256) void k_rowtop(
    const unsigned short* __restrict__ Sh, const float* __restrict__ hhat,
    float* __restrict__ mtv, int* __restrict__ mtj) {
  int i = blockIdx.x * 4 + (threadIdx.x >> 6);
  int lane = threadIdx.x & 63;
  const unsigned short* row = &Sh[(size_t)i * N];
  float v[5] = {-3e38f, -3e38f, -3e38f, -3e38f, -3e38f};
  int jx[5] = {0x7fffffff, 0x7fffffff, 0x7fffffff, 0x7fffffff, 0x7fffffff};
  for (int t = 0; t < 8; t++) {
    int base = t * 512 + lane * 8;
    uint4 p = *(const uint4*)&row[base];
    unsigned pk[4] = {p.x, p.y, p.z, p.w};
#pragma unroll
    for (int c = 0; c < 4; c++) {
      float e0 = __half2float(__ushort_as_half((unsigned short)(pk[c] & 0xffffu)));
      float e1 = __half2float(__ushort_as_half((unsigned short)(pk[c] >> 16)));
      ins5(e0, base + c * 2, v, jx);
      ins5(e1, base + c * 2 + 1, v, jx);
    }
  }
#pragma unroll
  for (int d = 1; d < 64; d <<= 1) {
    float fv[5]; int fj[5];
#pragma unroll
    for (int c = 0; c < 5; c++) { fv[c] = __shfl_xor(v[c], d); fj[c] = __shfl_xor(jx[c], d); }
#pragma unroll
    for (int c = 0; c < 5; c++) ins5(fv[c], fj[c], v, jx);
  }
  const float* hi = &hhat[(size_t)i * H];
  float b0 = -3e38f, b1 = -3e38f, b2 = -3e38f;
  int q0 = 0, q1 = 0, q2 = 0;
#pragma unroll
  for (int c = 0; c < 5; c++) {
    int j = jx[c];
    float s;
    if (j == i) {
      s = 0.f;
    } else {
      const float* hj = &hhat[(size_t)j * H];
      float p = hi[lane] * hj[lane] + hi[lane + 64] * hj[lane + 64];
      s = wave_reduce_sum(p);
    }
    top3_ins(s, j, b0, q0, b1, q1, b2, q2);
  }
  if (lane == 0) {
    mtv[i * 3 + 0] = b0; mtv[i * 3 + 1] = b1; mtv[i * 3 + 2] = b2;
    mtj[i * 3 + 0] = q0; mtj[i * 3 + 1] = q1; mtj[i * 3 + 2] = q2;
  }
}

__global__ __launch_bounds__(256) void k_scatter(
    const float* __restrict__ mtv, const int* __restrict__ mtj,
    const float* __restrict__ h, float* __restrict__ hidden2,
    float* __restrict__ colsum_m) {
  int i = blockIdx.x * 4 + (threadIdx.x >> 6);
  int lane = threadIdx.x & 63;
  float h0 = h[(size_t)i * H + lane], h1 = h[(size_t)i * H + 64 + lane];
#pragma unroll
  for (int s = 0; s < 3; s++) {
    float v = mtv[i * 3 + s];
    int j = mtj[i * 3 + s];
    atomicAdd(&hidden2[(size_t)j * H + lane], v * h0);
    atomicAdd(&hidden2[(size_t)j * H + 64 + lane], v * h1);
    if (lane == s) atomicAdd(&colsum_m[j], v);
  }
}

// reduce split-K partials; optional per-row (128-wide) scale
__global__ __launch_bounds__(256) void k_reduce(
    const float* __restrict__ partial, float* __restrict__ out, int cnt,
    size_t slot, size_t size4, const float* __restrict__ scalem) {
  size_t idx = (size_t)blockIdx.x * 256 + threadIdx.x;
  if (idx >= size4) return;
  float4 s = {0, 0, 0, 0};
  for (int c = 0; c < cnt; c++) {
    float4 v = *(const float4*)&partial[c * slot + idx * 4];
    s.x += v.x; s.y += v.y; s.z += v.z; s.w += v.w;
  }
  if (scalem) {
    float sc = scalem[idx >> 5];
    s.x *= sc; s.y *= sc; s.z *= sc; s.w *= sc;
  }
  *(float4*)&out[idx * 4] = s;
}

// ---------------- launch ----------------

extern "C" void kernel_launch(void* const* d_in, const int* in_sizes, int n_in,
                              void* d_out, int out_size, void* d_ws, size_t ws_size,
                              hipStream_t stream) {
  (void)in_sizes; (void)n_in; (void)out_size;
  const float* x   = (const float*)d_in[0];
  const float* cm  = (const float*)d_in[1];
  const float* mv  = (const float*)d_in[2];
  const float* W_ps = (const float*)d_in[3],  *b_ps = (const float*)d_in[4];
  const float* W_psf = (const float*)d_in[5], *b_psf = (const float*)d_in[6];
  const float* W_psb = (const float*)d_in[7], *b_psb = (const float*)d_in[8];
  const float* W_hs = (const float*)d_in[9],  *b_hs = (const float*)d_in[10];
  const float* W_hsf = (const float*)d_in[11], *b_hsf = (const float*)d_in[12];
  const float* W_hsb = (const float*)d_in[13], *b_hsb = (const float*)d_in[14];
  const float* W_in = (const float*)d_in[15], *b_in = (const float*)d_in[16];
  const float* W_out = (const float*)d_in[17], *b_out = (const float*)d_in[18];
  float* out = (float*)d_out;

  float* W = (float*)d_ws;
  size_t o = 0;
  auto alloc = [&](size_t n) { float* p = W + o; o += n; return p; };
  float* colsum_c = alloc(C);
  float* colmax   = alloc(C);
  float* colsumexp= alloc(C);
  float* valid1   = alloc(C);
  float* hnorm_ps = alloc(C);
  float* xnorm    = alloc(N);
  float* diagv    = alloc(N);
  float* colsum_m = alloc(N);
  float* valid2f  = alloc(N);
  float* lsum     = alloc(N);
  float* linv     = alloc(N);
  float* mtv      = alloc(3 * N);
  int*   mtj      = (int*)alloc(3 * N);
  float* hidden1  = alloc((size_t)C * H);
  float* hidden_ps= alloc((size_t)C * H);
  float* scores   = alloc((size_t)N * C);
  float* ps_pre   = alloc((size_t)N * H);   // later hs_pre
  float* p_shared = alloc((size_t)N * H);   // later h_shared
  float* all_info = alloc((size_t)N * H);
  float* hbuf     = alloc((size_t)N * H);   // h; later indiv (in-place)
  float* hhat     = alloc((size_t)N * H);
  float* hidden2  = alloc((size_t)N * H);
  float* h2hat    = alloc((size_t)N * H);
  unsigned short* xhi    = (unsigned short*)alloc((size_t)N * H / 2);
  unsigned short* xlo    = (unsigned short*)alloc((size_t)N * H / 2);
  unsigned short* hhathi = (unsigned short*)alloc((size_t)N * H / 2);
  unsigned short* hhatlo = (unsigned short*)alloc((size_t)N * H / 2);
  unsigned short* h2hi   = (unsigned short*)alloc((size_t)N * H / 2);
  unsigned short* h2lo   = (unsigned short*)alloc((size_t)N * H / 2);
  unsigned short* h1hi   = (unsigned short*)alloc((size_t)C * H / 2);
  unsigned short* h1lo   = (unsigned short*)alloc((size_t)C * H / 2);
  unsigned short* hpshi  = (unsigned short*)alloc((size_t)C * H / 2);
  unsigned short* hpslo  = (unsigned short*)alloc((size_t)C * H / 2);
  unsigned short* cshi   = (unsigned short*)alloc((size_t)N * C / 2);
  unsigned short* cslo   = (unsigned short*)alloc((size_t)N * C / 2);
  unsigned short* hpst_hi= (unsigned short*)alloc((size_t)H * C / 2);
  unsigned short* hpst_lo= (unsigned short*)alloc((size_t)H * C / 2);
  unsigned short* h2t_hi = (unsigned short*)alloc((size_t)H * N / 2);
  unsigned short* h2t_lo = (unsigned short*)alloc((size_t)H * N / 2);
  unsigned short* xt_hi  = (unsigned short*)alloc((size_t)H * N / 2);
  unsigned short* xt_lo  = (unsigned short*)alloc((size_t)H * N / 2);
  float* Sbuf     = alloc((size_t)N * N);   // fp16 S (32 MB) then E pairs (64 MB)
  unsigned short* Sh  = (unsigned short*)Sbuf;
  unsigned short* Ehi = (unsigned short*)Sbuf;
  unsigned short* Elo = Ehi + (size_t)N * N;
  float* partial  = W + o;
  size_t rem = ws_size / 4 - o;
  int Z = (rem >= (size_t)16 * N * H) ? 16 : 8;
  int KC = 4096 / Z;

  hipMemsetAsync(colsum_c, 0, C * sizeof(float), stream);
  hipMemsetAsync(colsum_m, 0, N * sizeof(float), stream);
  hipMemsetAsync(lsum, 0, N * sizeof(float), stream);
  hipMemsetAsync(hidden2, 0, (size_t)N * H * sizeof(float), stream);

  dim3 blk(256);
  // --- ps branch ---
  k_split<<<dim3(N * H / 1024), blk, 0, stream>>>(x, xhi, xlo);
  k_tsplit<<<dim3(N / 32), blk, 0, stream>>>(x, xt_hi, xt_lo, N);
  k_colsum_s2c<<<dim3(C / 64, 16), dim3(64), 0, stream>>>(cm, mv, colsum_c);
  k_mfma_genA<1><<<dim3(1, C / 128, 32), blk, 0, stream>>>(
      cm, mv, colsum_c, nullptr, xt_hi, xt_lo, partial, N / 32);
  k_reduce<<<dim3(C * H / 4 / 256), blk, 0, stream>>>(
      partial, hidden1, 32, (size_t)C * H, (size_t)C * H / 4, nullptr);
  k_valid1<<<dim3(C), dim3(64), 0, stream>>>(hidden1, valid1);
  k_split<<<dim3(C * H / 1024), blk, 0, stream>>>(hidden1, h1hi, h1lo);
  k_mfma_nt<0><<<dim3(C / 128, N / 128), blk, 0, stream>>>(
      xhi, xlo, h1hi, h1lo, nullptr, scores, nullptr, nullptr, nullptr, C);
  k_colstats<<<dim3(C), blk, 0, stream>>>(scores, colmax, colsumexp);
  k_mfma_genA<2><<<dim3(1, C / 128, 32), blk, 0, stream>>>(
      scores, nullptr, colmax, colsumexp, xt_hi, xt_lo, partial, N / 32);
  k_reduce<<<dim3(C * H / 4 / 256), blk, 0, stream>>>(
      partial, hidden_ps, 32, (size_t)C * H, (size_t)C * H / 4, valid1);
  k_rownorm128<<<dim3(N), dim3(64), 0, stream>>>(x, xnorm);
  k_rownorm128<<<dim3(C), dim3(64), 0, stream>>>(hidden_ps, hnorm_ps);
  k_split<<<dim3(C * H / 1024), blk, 0, stream>>>(hidden_ps, hpshi, hpslo);
  k_mfma_nt<0><<<dim3(C / 128, N / 128), blk, 0, stream>>>(
      xhi, xlo, hpshi, hpslo, nullptr, scores, nullptr, nullptr, nullptr, C);
  k_cs_softmax<<<dim3(N), blk, 0, stream>>>(scores, xnorm, hnorm_ps, valid1,
                                            cshi, cslo);
  k_tsplit<<<dim3(C / 32), blk, 0, stream>>>(hidden_ps, hpst_hi, hpst_lo, C);
  k_mfma_kn<<<dim3(1, N / 128, 4), blk, 0, stream>>>(
      cshi, cslo, hpst_hi, hpst_lo, partial, C, C / 4);
  k_reduce<<<dim3(N * H / 4 / 256), blk, 0, stream>>>(
      partial, ps_pre, 4, (size_t)N * H, (size_t)N * H / 4, nullptr);
  k_mfma_lin<0><<<dim3(1, N / 32), blk, 0, stream>>>(
      ps_pre, W_ps, b_ps, nullptr, p_shared);
  k_mfma_lin<3><<<dim3(1, N / 32), blk, 0, stream>>>(
      p_shared, W_psb, b_psb, x, hbuf);                      // h = x - p_back
  k_mfma_lin<1><<<dim3(1, N / 32), blk, 0, stream>>>(
      p_shared, W_psf, b_psf, nullptr, all_info);            // out_ps
  // --- hs branch ---
  k_hhat<<<dim3(N), dim3(64), 0, stream>>>(hbuf, hhat, diagv);
  k_split<<<dim3(N * H / 1024), blk, 0, stream>>>(hhat, hhathi, hhatlo);
  k_mfma_nt<2><<<dim3(N / 128, N / 128), blk, 0, stream>>>(
      hhathi, hhatlo, hhathi, hhatlo, nullptr, nullptr, Sh, nullptr, nullptr, N);
  k_rowtop<<<dim3(N / 4), blk, 0, stream>>>(Sh, hhat, mtv, mtj);
  k_scatter<<<dim3(N / 4), blk, 0, stream>>>(mtv, mtj, hbuf, hidden2, colsum_m);
  k_fin_hidden2<<<dim3(N), dim3(64), 0, stream>>>(hbuf, diagv, colsum_m, hidden2,
                                                  h2hat, valid2f);
  k_split<<<dim3(N * H / 1024), blk, 0, stream>>>(h2hat, h2hi, h2lo);
  k_mfma_nt<3><<<dim3(N / 128, N / 128), blk, 0, stream>>>(
      hhathi, hhatlo, h2hi, h2lo, valid2f, nullptr, Ehi, Elo, lsum, N);
  k_recip<<<dim3(N / 256), blk, 0, stream>>>(lsum, linv);
  k_tsplit<<<dim3(N / 32), blk, 0, stream>>>(hidden2, h2t_hi, h2t_lo, N);
  k_mfma_kn<<<dim3(1, N / 128, Z), blk, 0, stream>>>(
      Ehi, Elo, h2t_hi, h2t_lo, partial, N, KC);
  k_reduce<<<dim3(N * H / 4 / 256), blk, 0, stream>>>(
      partial, ps_pre, Z, (size_t)N * H, (size_t)N * H / 4, linv);  // hs_pre
  k_mfma_lin<0><<<dim3(1, N / 32), blk, 0, stream>>>(
      ps_pre, W_hs, b_hs, nullptr, p_shared);                // h_shared
  k_mfma_lin<2><<<dim3(1, N / 32), blk, 0, stream>>>(
      p_shared, W_hsf, b_hsf, nullptr, all_info);            // += out_hs
  k_mfma_lin<3><<<dim3(1, N / 32), blk, 0, stream>>>(
      p_shared, W_hsb, b_hsb, hbuf, hbuf);                   // indiv = h - h_back
  k_mfma_lin<2><<<dim3(1, N / 32), blk, 0, stream>>>(
      hbuf, W_in, b_in, nullptr, all_info);                  // += out_indi
  k_final<<<dim3(N), dim3(64), 0, stream>>>(all_info, W_out, b_out, out);
}